// Round 1
// baseline (517.608 us; speedup 1.0000x reference)
//
#include <hip/hip_runtime.h>
#include <hip/hip_bf16.h>

typedef unsigned short u16;
typedef __attribute__((ext_vector_type(4))) short bf16x4;
typedef __attribute__((ext_vector_type(8))) short bf16x8;
typedef __attribute__((ext_vector_type(4))) float f32x4;

// ---------- helpers ----------
static __device__ __forceinline__ u16 f2b(float f){
  union { float f; unsigned u; } v; v.f = f;
  unsigned r = v.u + 0x7fffu + ((v.u >> 16) & 1u);   // RNE
  return (u16)(r >> 16);
}
static __device__ __forceinline__ float b2f(u16 h){
  union { unsigned u; float f; } v; v.u = ((unsigned)h) << 16; return v.f;
}
static __device__ __forceinline__ void gld_lds16(const void* g, void* l){
  __builtin_amdgcn_global_load_lds((const __attribute__((address_space(1))) void*)g,
                                   (__attribute__((address_space(3))) void*)l, 16, 0, 0);
}

// ---------- f32 -> bf16 row convert (row remap for K compaction) ----------
__global__ __launch_bounds__(256) void cvt_rows_k(const float* __restrict__ in,
                                                  u16* __restrict__ out, int extra){
  int row = blockIdx.x, t = threadIdx.x;
  size_t irow = (size_t)row + (size_t)(row >> 10) * extra;
  const float4 v = *(const float4*)(in + irow * 1024 + t * 4);
  bf16x4 o;
  o[0] = (short)f2b(v.x); o[1] = (short)f2b(v.y);
  o[2] = (short)f2b(v.z); o[3] = (short)f2b(v.w);
  *(bf16x4*)(out + (size_t)row * 1024 + t * 4) = o;
}

// ---------- weight transpose + convert: in [K][N] f32 -> out [N][K] bf16 ----------
__global__ __launch_bounds__(256) void transpose_cvt_k(const float* __restrict__ in,
                                                       u16* __restrict__ out, int K, int N){
  __shared__ float tile[64][65];
  const int k0 = blockIdx.y * 64, n0 = blockIdx.x * 64;
  const int t = threadIdx.x, tr = t >> 4, tc = t & 15;
#pragma unroll
  for (int i = 0; i < 4; i++){
    int r = tr + i * 16;
    float4 v = *(const float4*)(in + (size_t)(k0 + r) * N + n0 + tc * 4);
    tile[r][tc*4+0] = v.x; tile[r][tc*4+1] = v.y; tile[r][tc*4+2] = v.z; tile[r][tc*4+3] = v.w;
  }
  __syncthreads();
#pragma unroll
  for (int i = 0; i < 4; i++){
    int nr = tr + i * 16;
    bf16x4 pk;
#pragma unroll
    for (int j = 0; j < 4; j++) pk[j] = (short)f2b(tile[tc*4+j][nr]);
    *(bf16x4*)(out + (size_t)(n0 + nr) * K + k0 + tc * 4) = pk;
  }
}

// ---------- GEMM: C[M,N] = A[M,K](bf16) @ Bt[N,K](bf16)^T + bias ----------
// EPI: 0 = bias -> bf16 ; 1 = bias + residual(bf16) -> bf16 ;
//      2 = bias + relu -> bf16 ; 3 = bias -> transposed vt[b][n][key] bf16
template<int EPI>
__global__ __launch_bounds__(256) void gemm_bt(const u16* __restrict__ A,
                                               const u16* __restrict__ Bt,
                                               const float* __restrict__ bias,
                                               const u16* __restrict__ res,
                                               u16* __restrict__ out,
                                               int M, int N, int K){
  __shared__ u16 lA[128 * 64];
  __shared__ u16 lB[128 * 64];
  const int t = threadIdx.x, w = t >> 6, l = t & 63;
  const int m0 = blockIdx.y * 128, n0 = blockIdx.x * 128;
  const int wr = w >> 1, wc = w & 1;
  const int lrow = l >> 3, lc8 = l & 7;
  const int c = l & 15, g = l >> 4;

  f32x4 acc[4][4];
#pragma unroll
  for (int i = 0; i < 4; i++)
#pragma unroll
    for (int j = 0; j < 4; j++) acc[i][j] = (f32x4){0.f, 0.f, 0.f, 0.f};

  for (int k0 = 0; k0 < K; k0 += 64){
#pragma unroll
    for (int i = 0; i < 4; i++){
      int ch = w * 4 + i;
      int r  = ch * 8 + lrow;
      gld_lds16(A  + (size_t)(m0 + r) * K + k0 + lc8 * 8, lA + ch * 512);
      gld_lds16(Bt + (size_t)(n0 + r) * K + k0 + lc8 * 8, lB + ch * 512);
    }
    __syncthreads();
#pragma unroll
    for (int ks = 0; ks < 2; ks++){
      bf16x8 af[4], bfr[4];
#pragma unroll
      for (int mi = 0; mi < 4; mi++){
        int row = wr * 64 + mi * 16 + c;
        af[mi] = *(const bf16x8*)((const char*)lA + row * 128 + ks * 64 + g * 16);
      }
#pragma unroll
      for (int ni = 0; ni < 4; ni++){
        int row = wc * 64 + ni * 16 + c;
        bfr[ni] = *(const bf16x8*)((const char*)lB + row * 128 + ks * 64 + g * 16);
      }
#pragma unroll
      for (int mi = 0; mi < 4; mi++)
#pragma unroll
        for (int ni = 0; ni < 4; ni++)
          acc[mi][ni] = __builtin_amdgcn_mfma_f32_16x16x32_bf16(af[mi], bfr[ni], acc[mi][ni], 0, 0, 0);
    }
    __syncthreads();
  }

  // epilogue: C frag mapping (m89): col = lane&15, row = (lane>>4)*4 + r
#pragma unroll
  for (int ni = 0; ni < 4; ni++){
    int n = n0 + wc * 64 + ni * 16 + c;
    float bv = bias[n];
#pragma unroll
    for (int mi = 0; mi < 4; mi++){
      int row0 = m0 + wr * 64 + mi * 16 + 4 * g;
      if (EPI == 3){
        bf16x4 pk;
#pragma unroll
        for (int r = 0; r < 4; r++) pk[r] = (short)f2b(acc[mi][ni][r] + bv);
        int bb = row0 >> 10, key = row0 & 1023;
        *(bf16x4*)(out + ((size_t)bb << 20) + (size_t)n * 1024 + key) = pk;
      } else {
#pragma unroll
        for (int r = 0; r < 4; r++){
          int row = row0 + r;
          float v = acc[mi][ni][r] + bv;
          if (EPI == 1) v += b2f(res[(size_t)row * N + n]);
          if (EPI == 2) v = fmaxf(v, 0.f);
          out[(size_t)row * N + n] = f2b(v);
        }
      }
    }
  }
}

// ---------- fused masked attention (flash-style, swapped-operand) ----------
// qb,kb: [4096][1024] bf16 (token-major, col = h*64+dh); vt: [4][1024 dh][1024 key] bf16
// mask: [64][1024][1024] f32 ; ob: [4096][1024] bf16
__global__ __launch_bounds__(256) void attn_k(const u16* __restrict__ qb,
                                              const u16* __restrict__ kb,
                                              const u16* __restrict__ vt,
                                              const float* __restrict__ mask,
                                              u16* __restrict__ ob){
  const int t = threadIdx.x, w = t >> 6, l = t & 63;
  const int c = l & 15, g = l >> 4;
  const int q0 = blockIdx.x * 64, h = blockIdx.y, b = blockIdx.z;
  const int qrow = q0 + w * 16 + c;                       // q row within batch
  const size_t qoff = ((size_t)(b * 1024 + qrow)) * 1024 + h * 64;
  const bf16x8 bq0 = *(const bf16x8*)(qb + qoff + g * 8);       // B-frag: dh 0..31
  const bf16x8 bq1 = *(const bf16x8*)(qb + qoff + 32 + g * 8);  // B-frag: dh 32..63
  const u16* kbase = kb + ((size_t)b * 1024) * 1024 + h * 64;
  const u16* vbase = vt + ((size_t)b << 20) + (size_t)(h * 64) * 1024;
  const float* mbase = mask + ((size_t)(h * 4 + b) * 1024 + qrow) * 1024;

  float m = -INFINITY, lsum = 0.f;
  f32x4 acc[4];
#pragma unroll
  for (int f = 0; f < 4; f++) acc[f] = (f32x4){0.f, 0.f, 0.f, 0.f};

  for (int kv = 0; kv < 1024; kv += 64){
    f32x4 st[4];
#pragma unroll
    for (int nf = 0; nf < 4; nf++){
      const u16* kr = kbase + (size_t)(kv + nf * 16 + c) * 1024;   // A-frag: row = key
      bf16x8 ak0 = *(const bf16x8*)(kr + g * 8);
      bf16x8 ak1 = *(const bf16x8*)(kr + 32 + g * 8);
      f32x4 z = (f32x4){0.f, 0.f, 0.f, 0.f};
      z = __builtin_amdgcn_mfma_f32_16x16x32_bf16(ak0, bq0, z, 0, 0, 0);
      z = __builtin_amdgcn_mfma_f32_16x16x32_bf16(ak1, bq1, z, 0, 0, 0);
      st[nf] = z;   // S^T frag: key = kv+nf*16+4g+r, qrow = q0+w*16+c (lane-local!)
    }
    float s[16]; float tmax = -INFINITY;
#pragma unroll
    for (int nf = 0; nf < 4; nf++){
      f32x4 mv = *(const f32x4*)(mbase + kv + nf * 16 + g * 4);
#pragma unroll
      for (int r = 0; r < 4; r++){
        float v = st[nf][r] * 0.03125f + mv[r];   // logits/sqrt(1024) + mask
        s[nf * 4 + r] = v; tmax = fmaxf(tmax, v);
      }
    }
    tmax = fmaxf(tmax, __shfl_xor(tmax, 16));
    tmax = fmaxf(tmax, __shfl_xor(tmax, 32));
    float mnew  = fmaxf(m, tmax);
    float alpha = __expf(m - mnew);               // 0 on first iter (m = -inf)
    float rs = 0.f;
    bf16x4 pb[4];
#pragma unroll
    for (int nf = 0; nf < 4; nf++){
#pragma unroll
      for (int r = 0; r < 4; r++){
        float p = __expf(s[nf * 4 + r] - mnew);
        rs += p;
        pb[nf][r] = (short)f2b(p);                // P^T feeds PV B-operand directly
      }
    }
    rs += __shfl_xor(rs, 16); rs += __shfl_xor(rs, 32);
    lsum = lsum * alpha + rs; m = mnew;
#pragma unroll
    for (int f = 0; f < 4; f++){
      acc[f][0] *= alpha; acc[f][1] *= alpha; acc[f][2] *= alpha; acc[f][3] *= alpha;
    }
    // O^T += V^T @ P^T  (16x16x16: k-map 4g+j matches S^T row-map 4g+r)
#pragma unroll
    for (int f = 0; f < 4; f++){
      const u16* vr = vbase + (size_t)(f * 16 + c) * 1024 + kv;   // A-frag: row = dh
#pragma unroll
      for (int nf = 0; nf < 4; nf++){
        bf16x4 av = *(const bf16x4*)(vr + nf * 16 + g * 4);
        acc[f] = __builtin_amdgcn_mfma_f32_16x16x16bf16_1k(av, pb[nf], acc[f], 0, 0, 0);
      }
    }
  }
  const float inv = 1.f / lsum;
#pragma unroll
  for (int f = 0; f < 4; f++){
    bf16x4 pk;
#pragma unroll
    for (int r = 0; r < 4; r++) pk[r] = (short)f2b(acc[f][r] * inv);
    *(bf16x4*)(ob + qoff + f * 16 + g * 4) = pk;   // O^T frag col = qrow = c (lane-local)
  }
}

// ---------- LayerNorm over 1024 cols ----------
template<int F32OUT>
__global__ __launch_bounds__(256) void ln_k(const u16* __restrict__ x,
                                            const float* __restrict__ gw,
                                            const float* __restrict__ bw,
                                            void* __restrict__ outp){
  const int row = blockIdx.x, t = threadIdx.x, w = t >> 6, l = t & 63;
  const u16* xr = x + (size_t)row * 1024;
  bf16x4 xv = *(const bf16x4*)(xr + t * 4);
  float xs[4], s = 0.f, sq = 0.f;
#pragma unroll
  for (int j = 0; j < 4; j++){ xs[j] = b2f((u16)xv[j]); s += xs[j]; sq += xs[j] * xs[j]; }
#pragma unroll
  for (int o = 32; o; o >>= 1){ s += __shfl_xor(s, o); sq += __shfl_xor(sq, o); }
  __shared__ float rs[4], rq[4];
  if (l == 0){ rs[w] = s; rq[w] = sq; }
  __syncthreads();
  s  = rs[0] + rs[1] + rs[2] + rs[3];
  sq = rq[0] + rq[1] + rq[2] + rq[3];
  const float mu   = s * (1.f / 1024.f);
  const float var  = sq * (1.f / 1024.f) - mu * mu;
  const float rstd = rsqrtf(var + 1e-5f);
  if (F32OUT){
    float4 o4;
    o4.x = (xs[0]-mu)*rstd*gw[t*4+0] + bw[t*4+0];
    o4.y = (xs[1]-mu)*rstd*gw[t*4+1] + bw[t*4+1];
    o4.z = (xs[2]-mu)*rstd*gw[t*4+2] + bw[t*4+2];
    o4.w = (xs[3]-mu)*rstd*gw[t*4+3] + bw[t*4+3];
    *((float4*)outp + (size_t)row * 256 + t) = o4;
  } else {
    bf16x4 o;
#pragma unroll
    for (int j = 0; j < 4; j++) o[j] = (short)f2b((xs[j]-mu)*rstd*gw[t*4+j] + bw[t*4+j]);
    *((bf16x4*)outp + (size_t)row * 256 + t) = o;
  }
}

// ---------- launch ----------
extern "C" void kernel_launch(void* const* d_in, const int* in_sizes, int n_in,
                              void* d_out, int out_size, void* d_ws, size_t ws_size,
                              hipStream_t stream){
  const float* Q    = (const float*)d_in[0];
  const float* K    = (const float*)d_in[1];
  const float* mask = (const float*)d_in[2];
  const float* Wq   = (const float*)d_in[4];  const float* bq  = (const float*)d_in[5];
  const float* Wk   = (const float*)d_in[6];  const float* bk  = (const float*)d_in[7];
  const float* Wv   = (const float*)d_in[8];  const float* bv  = (const float*)d_in[9];
  const float* Wo0  = (const float*)d_in[10]; const float* bo0 = (const float*)d_in[11];
  const float* Wo   = (const float*)d_in[12]; const float* bo  = (const float*)d_in[13];
  const float* Wo2  = (const float*)d_in[14]; const float* bo2 = (const float*)d_in[15];
  const float* g0   = (const float*)d_in[16]; const float* be0 = (const float*)d_in[17];
  const float* g1   = (const float*)d_in[18]; const float* be1 = (const float*)d_in[19];

  uint8_t* W = (uint8_t*)d_ws;
  const size_t MB = 1024ull * 1024ull;
  u16* Wq_t  = (u16*)(W + 0);
  u16* Wk_t  = (u16*)(W + 2  * MB);
  u16* Wv_t  = (u16*)(W + 4  * MB);
  u16* Wo0_t = (u16*)(W + 6  * MB);
  u16* Wo_t  = (u16*)(W + 8  * MB);   // [4096][1024]
  u16* Wo2_t = (u16*)(W + 16 * MB);   // [1024][4096]
  u16* Qb    = (u16*)(W + 24 * MB);
  u16* Kb    = (u16*)(W + 32 * MB);
  u16* qb    = (u16*)(W + 40 * MB);
  u16* kbf   = (u16*)(W + 48 * MB);
  u16* vtb   = (u16*)(W + 56 * MB);
  u16* ob    = (u16*)(W + 24 * MB);   // reuse Qb
  u16* x0b   = (u16*)(W + 32 * MB);   // reuse Kb
  u16* x1b   = (u16*)(W + 64 * MB);
  u16* hb    = (u16*)(W + 32 * MB);   // 32MB spanning dead x0b/qb/kbf/vtb
  u16* zb    = (u16*)(W + 24 * MB);   // reuse ob

  // input conversion (K compacted to first 1024 rows per batch)
  cvt_rows_k<<<4096, 256, 0, stream>>>(Q, Qb, 0);
  cvt_rows_k<<<4096, 256, 0, stream>>>(K, Kb, 512);
  transpose_cvt_k<<<dim3(16, 16), 256, 0, stream>>>(Wq,  Wq_t,  1024, 1024);
  transpose_cvt_k<<<dim3(16, 16), 256, 0, stream>>>(Wk,  Wk_t,  1024, 1024);
  transpose_cvt_k<<<dim3(16, 16), 256, 0, stream>>>(Wv,  Wv_t,  1024, 1024);
  transpose_cvt_k<<<dim3(16, 16), 256, 0, stream>>>(Wo0, Wo0_t, 1024, 1024);
  transpose_cvt_k<<<dim3(64, 16), 256, 0, stream>>>(Wo,  Wo_t,  1024, 4096);
  transpose_cvt_k<<<dim3(16, 64), 256, 0, stream>>>(Wo2, Wo2_t, 4096, 1024);

  // projections
  gemm_bt<0><<<dim3(8, 32), 256, 0, stream>>>(Qb, Wq_t, bq, nullptr, qb, 4096, 1024, 1024);
  gemm_bt<0><<<dim3(8, 32), 256, 0, stream>>>(Kb, Wk_t, bk, nullptr, kbf, 4096, 1024, 1024);
  gemm_bt<3><<<dim3(8, 32), 256, 0, stream>>>(Kb, Wv_t, bv, nullptr, vtb, 4096, 1024, 1024);

  // attention
  attn_k<<<dim3(16, 16, 4), 256, 0, stream>>>(qb, kbf, vtb, mask, ob);

  // output proj + residual, LN0
  gemm_bt<1><<<dim3(8, 32), 256, 0, stream>>>(ob, Wo0_t, bo0, qb, x0b, 4096, 1024, 1024);
  ln_k<0><<<4096, 256, 0, stream>>>(x0b, g0, be0, x1b);

  // FFN + residual, LN1
  gemm_bt<2><<<dim3(32, 32), 256, 0, stream>>>(x1b, Wo_t, bo, nullptr, hb, 4096, 4096, 1024);
  gemm_bt<1><<<dim3(8, 32), 256, 0, stream>>>(hb, Wo2_t, bo2, x1b, zb, 4096, 1024, 4096);
  ln_k<1><<<4096, 256, 0, stream>>>(zb, g1, be1, d_out);
}

// Round 2
// 378.555 us; speedup vs baseline: 1.3673x; 1.3673x over previous
//
#include <hip/hip_runtime.h>
#include <hip/hip_bf16.h>

typedef unsigned short u16;
typedef __attribute__((ext_vector_type(4))) short bf16x4;
typedef __attribute__((ext_vector_type(8))) short bf16x8;
typedef __attribute__((ext_vector_type(4))) float f32x4;

// ---------- helpers ----------
static __device__ __forceinline__ u16 f2b(float f){
  union { float f; unsigned u; } v; v.f = f;
  unsigned r = v.u + 0x7fffu + ((v.u >> 16) & 1u);   // RNE
  return (u16)(r >> 16);
}
static __device__ __forceinline__ float b2f(u16 h){
  union { unsigned u; float f; } v; v.u = ((unsigned)h) << 16; return v.f;
}
static __device__ __forceinline__ void gld_lds16(const void* g, void* l){
  __builtin_amdgcn_global_load_lds((const __attribute__((address_space(1))) void*)g,
                                   (__attribute__((address_space(3))) void*)l, 16, 0, 0);
}

// ---------- f32 -> bf16 row convert (row remap for K compaction) ----------
__global__ __launch_bounds__(256) void cvt_rows_k(const float* __restrict__ in,
                                                  u16* __restrict__ out, int extra){
  int row = blockIdx.x, t = threadIdx.x;
  size_t irow = (size_t)row + (size_t)(row >> 10) * extra;
  const float4 v = *(const float4*)(in + irow * 1024 + t * 4);
  bf16x4 o;
  o[0] = (short)f2b(v.x); o[1] = (short)f2b(v.y);
  o[2] = (short)f2b(v.z); o[3] = (short)f2b(v.w);
  *(bf16x4*)(out + (size_t)row * 1024 + t * 4) = o;
}

// ---------- weight transpose + convert: in [K][N] f32 -> out [N][K] bf16 ----------
__global__ __launch_bounds__(256) void transpose_cvt_k(const float* __restrict__ in,
                                                       u16* __restrict__ out, int K, int N){
  __shared__ float tile[64][65];
  const int k0 = blockIdx.y * 64, n0 = blockIdx.x * 64;
  const int t = threadIdx.x, tr = t >> 4, tc = t & 15;
#pragma unroll
  for (int i = 0; i < 4; i++){
    int r = tr + i * 16;
    float4 v = *(const float4*)(in + (size_t)(k0 + r) * N + n0 + tc * 4);
    tile[r][tc*4+0] = v.x; tile[r][tc*4+1] = v.y; tile[r][tc*4+2] = v.z; tile[r][tc*4+3] = v.w;
  }
  __syncthreads();
#pragma unroll
  for (int i = 0; i < 4; i++){
    int nr = tr + i * 16;
    bf16x4 pk;
#pragma unroll
    for (int j = 0; j < 4; j++) pk[j] = (short)f2b(tile[tc*4+j][nr]);
    *(bf16x4*)(out + (size_t)(n0 + nr) * K + k0 + tc * 4) = pk;
  }
}

// ---------- GEMM: C[M,N] = A[M,K](bf16) @ Bt[N,K](bf16)^T + bias ----------
// EPI: 0 = bias -> bf16 ; 1 = bias + residual(bf16) -> bf16 ;
//      2 = bias + relu -> bf16 ; 3 = bias -> transposed vt[b][n][key] bf16
template<int EPI>
__global__ __launch_bounds__(256) void gemm_bt(const u16* __restrict__ A,
                                               const u16* __restrict__ Bt,
                                               const float* __restrict__ bias,
                                               const u16* __restrict__ res,
                                               u16* __restrict__ out,
                                               int M, int N, int K){
  __shared__ u16 lA[128 * 64];
  __shared__ u16 lB[128 * 64];
  const int t = threadIdx.x, w = t >> 6, l = t & 63;
  const int m0 = blockIdx.y * 128, n0 = blockIdx.x * 128;
  const int wr = w >> 1, wc = w & 1;
  const int lrow = l >> 3, lc8 = l & 7;
  const int c = l & 15, g = l >> 4;

  f32x4 acc[4][4];
#pragma unroll
  for (int i = 0; i < 4; i++)
#pragma unroll
    for (int j = 0; j < 4; j++) acc[i][j] = (f32x4){0.f, 0.f, 0.f, 0.f};

  for (int k0 = 0; k0 < K; k0 += 64){
#pragma unroll
    for (int i = 0; i < 4; i++){
      int ch = w * 4 + i;
      int r  = ch * 8 + lrow;
      gld_lds16(A  + (size_t)(m0 + r) * K + k0 + lc8 * 8, lA + ch * 512);
      gld_lds16(Bt + (size_t)(n0 + r) * K + k0 + lc8 * 8, lB + ch * 512);
    }
    __syncthreads();
#pragma unroll
    for (int ks = 0; ks < 2; ks++){
      bf16x8 af[4], bfr[4];
#pragma unroll
      for (int mi = 0; mi < 4; mi++){
        int row = wr * 64 + mi * 16 + c;
        af[mi] = *(const bf16x8*)((const char*)lA + row * 128 + ks * 64 + g * 16);
      }
#pragma unroll
      for (int ni = 0; ni < 4; ni++){
        int row = wc * 64 + ni * 16 + c;
        bfr[ni] = *(const bf16x8*)((const char*)lB + row * 128 + ks * 64 + g * 16);
      }
#pragma unroll
      for (int mi = 0; mi < 4; mi++)
#pragma unroll
        for (int ni = 0; ni < 4; ni++)
          acc[mi][ni] = __builtin_amdgcn_mfma_f32_16x16x32_bf16(af[mi], bfr[ni], acc[mi][ni], 0, 0, 0);
    }
    __syncthreads();
  }

  // epilogue: C frag mapping (m89): col = lane&15, row = (lane>>4)*4 + r
#pragma unroll
  for (int ni = 0; ni < 4; ni++){
    int n = n0 + wc * 64 + ni * 16 + c;
    float bv = bias[n];
#pragma unroll
    for (int mi = 0; mi < 4; mi++){
      int row0 = m0 + wr * 64 + mi * 16 + 4 * g;
      if (EPI == 3){
        bf16x4 pk;
#pragma unroll
        for (int r = 0; r < 4; r++) pk[r] = (short)f2b(acc[mi][ni][r] + bv);
        int bb = row0 >> 10, key = row0 & 1023;
        *(bf16x4*)(out + ((size_t)bb << 20) + (size_t)n * 1024 + key) = pk;
      } else {
#pragma unroll
        for (int r = 0; r < 4; r++){
          int row = row0 + r;
          float v = acc[mi][ni][r] + bv;
          if (EPI == 1) v += b2f(res[(size_t)row * N + n]);
          if (EPI == 2) v = fmaxf(v, 0.f);
          out[(size_t)row * N + n] = f2b(v);
        }
      }
    }
  }
}

// ---------- fused masked attention (flash-style, swapped-operand) ----------
// qb,kb: [4096][1024] bf16 (token-major, col = h*64+dh); vt: [4][1024 dh][1024 key] bf16
// mask: [64][1024][1024] f32 ; ob: [4096][1024] bf16
// K/V tiles double-buffered in LDS via global_load_lds with XOR-swizzle
// (linear LDS dest + inverse-swizzled global source; swizzled ds_read).
__global__ __launch_bounds__(256, 4) void attn_k(const u16* __restrict__ qb,
                                                 const u16* __restrict__ kb,
                                                 const u16* __restrict__ vt,
                                                 const float* __restrict__ mask,
                                                 u16* __restrict__ ob){
  __shared__ u16 sK[2][4096];   // [key 0..63][dh 0..63], row stride 128B, swizzled
  __shared__ u16 sV[2][4096];   // [dh 0..63][key 0..63], row stride 128B, swizzled

  const int t = threadIdx.x, w = t >> 6, l = t & 63;
  const int c = l & 15, g = l >> 4;
  const int q0 = blockIdx.x * 64, h = blockIdx.y, b = blockIdx.z;
  const int qrow = q0 + w * 16 + c;
  const size_t qoff = ((size_t)(b * 1024 + qrow)) * 1024 + h * 64;
  const bf16x8 bq0 = *(const bf16x8*)(qb + qoff + g * 8);       // B-frag: dh 0..31
  const bf16x8 bq1 = *(const bf16x8*)(qb + qoff + 32 + g * 8);  // B-frag: dh 32..63
  const u16* kbase = kb + ((size_t)b * 1024) * 1024 + h * 64;
  const u16* vbase = vt + ((size_t)b << 20) + (size_t)(h * 64) * 1024;
  const float* mbase = mask + ((size_t)(h * 4 + b) * 1024 + qrow) * 1024;

  const int lr3 = l >> 3, lc3 = l & 7;
  const int ch0 = w * 2;                 // this wave's 2 staging chunks (1KB each)

  // stage K+V tile for kv into buf: LDS linear, global source pre-swizzled
  auto stage = [&](int buf, int kv){
#pragma unroll
    for (int i = 0; i < 2; i++){
      int ch  = ch0 + i;
      int row = ch * 8 + lr3;                       // tile row (key for K, dh for V)
      int L   = (lc3 * 16) ^ ((row & 7) << 4);      // logical colbyte this lane fetches
      gld_lds16(kbase + (size_t)(kv + row) * 1024 + (L >> 1), &sK[buf][ch * 512]);
      gld_lds16(vbase + (size_t)row * 1024 + kv + (L >> 1),   &sV[buf][ch * 512]);
    }
  };

  float m = -INFINITY, lsum = 0.f;
  f32x4 acc[4];
#pragma unroll
  for (int f = 0; f < 4; f++) acc[f] = (f32x4){0.f, 0.f, 0.f, 0.f};

  // prologue: stage kv=0, prefetch mask kv=0
  stage(0, 0);
  f32x4 mc[4];
#pragma unroll
  for (int nf = 0; nf < 4; nf++) mc[nf] = *(const f32x4*)(mbase + nf * 16 + g * 4);
  __syncthreads();   // drains vmcnt(0) -> buf0 + mc ready

  const int sw = (c & 7) << 4;
  int cur = 0;
  for (int it = 0; it < 16; ++it){
    const int kv = it * 64;
    f32x4 mn[4];
    if (it < 15){
      stage(cur ^ 1, kv + 64);                                   // next K/V tile
#pragma unroll
      for (int nf = 0; nf < 4; nf++)                             // next mask frags
        mn[nf] = *(const f32x4*)(mbase + kv + 64 + nf * 16 + g * 4);
    }

    // QK^T from LDS (swizzled reads)
    const char* kt = (const char*)sK[cur];
    f32x4 st[4];
#pragma unroll
    for (int nf = 0; nf < 4; nf++){
      const char* kr = kt + (nf * 16 + c) * 128;
      bf16x8 ak0 = *(const bf16x8*)(kr + ((g * 16) ^ sw));
      bf16x8 ak1 = *(const bf16x8*)(kr + ((64 + g * 16) ^ sw));
      f32x4 z = (f32x4){0.f, 0.f, 0.f, 0.f};
      z = __builtin_amdgcn_mfma_f32_16x16x32_bf16(ak0, bq0, z, 0, 0, 0);
      z = __builtin_amdgcn_mfma_f32_16x16x32_bf16(ak1, bq1, z, 0, 0, 0);
      st[nf] = z;   // S^T frag: key = kv+nf*16+4g+r, qrow lane-local
    }

    // online softmax (lane-local rows, 2 shuffles per reduce)
    float tmax = -INFINITY;
#pragma unroll
    for (int nf = 0; nf < 4; nf++)
#pragma unroll
      for (int r = 0; r < 4; r++){
        float v = st[nf][r] * 0.03125f + mc[nf][r];
        st[nf][r] = v; tmax = fmaxf(tmax, v);
      }
    tmax = fmaxf(tmax, __shfl_xor(tmax, 16));
    tmax = fmaxf(tmax, __shfl_xor(tmax, 32));
    float mnew  = fmaxf(m, tmax);
    float alpha = __expf(m - mnew);               // 0 on first iter
    float rs = 0.f;
    bf16x4 pb[4];
#pragma unroll
    for (int nf = 0; nf < 4; nf++)
#pragma unroll
      for (int r = 0; r < 4; r++){
        float p = __expf(st[nf][r] - mnew);
        rs += p;
        pb[nf][r] = (short)f2b(p);
      }
    rs += __shfl_xor(rs, 16); rs += __shfl_xor(rs, 32);
    lsum = lsum * alpha + rs; m = mnew;
#pragma unroll
    for (int f = 0; f < 4; f++){
      acc[f][0] *= alpha; acc[f][1] *= alpha; acc[f][2] *= alpha; acc[f][3] *= alpha;
    }

    // O^T += V^T @ P^T from LDS (swizzled b64 reads)
    const char* vtc = (const char*)sV[cur];
#pragma unroll
    for (int f = 0; f < 4; f++){
      const char* vr = vtc + (f * 16 + c) * 128;
#pragma unroll
      for (int nf = 0; nf < 4; nf++){
        bf16x4 av = *(const bf16x4*)(vr + ((nf * 32 + g * 8) ^ sw));
        acc[f] = __builtin_amdgcn_mfma_f32_16x16x16bf16_1k(av, pb[nf], acc[f], 0, 0, 0);
      }
    }

    __syncthreads();   // vmcnt(0)+lgkmcnt(0)+barrier: next buf ready, cur safe to overwrite
    cur ^= 1;
    if (it < 15){
#pragma unroll
      for (int nf = 0; nf < 4; nf++) mc[nf] = mn[nf];
    }
  }

  const float inv = 1.f / lsum;
#pragma unroll
  for (int f = 0; f < 4; f++){
    bf16x4 pk;
#pragma unroll
    for (int r = 0; r < 4; r++) pk[r] = (short)f2b(acc[f][r] * inv);
    *(bf16x4*)(ob + qoff + f * 16 + g * 4) = pk;   // O^T frag col = qrow (lane-local)
  }
}

// ---------- LayerNorm over 1024 cols ----------
template<int F32OUT>
__global__ __launch_bounds__(256) void ln_k(const u16* __restrict__ x,
                                            const float* __restrict__ gw,
                                            const float* __restrict__ bw,
                                            void* __restrict__ outp){
  const int row = blockIdx.x, t = threadIdx.x, w = t >> 6, l = t & 63;
  const u16* xr = x + (size_t)row * 1024;
  bf16x4 xv = *(const bf16x4*)(xr + t * 4);
  float xs[4], s = 0.f, sq = 0.f;
#pragma unroll
  for (int j = 0; j < 4; j++){ xs[j] = b2f((u16)xv[j]); s += xs[j]; sq += xs[j] * xs[j]; }
#pragma unroll
  for (int o = 32; o; o >>= 1){ s += __shfl_xor(s, o); sq += __shfl_xor(sq, o); }
  __shared__ float rs[4], rq[4];
  if (l == 0){ rs[w] = s; rq[w] = sq; }
  __syncthreads();
  s  = rs[0] + rs[1] + rs[2] + rs[3];
  sq = rq[0] + rq[1] + rq[2] + rq[3];
  const float mu   = s * (1.f / 1024.f);
  const float var  = sq * (1.f / 1024.f) - mu * mu;
  const float rstd = rsqrtf(var + 1e-5f);
  if (F32OUT){
    float4 o4;
    o4.x = (xs[0]-mu)*rstd*gw[t*4+0] + bw[t*4+0];
    o4.y = (xs[1]-mu)*rstd*gw[t*4+1] + bw[t*4+1];
    o4.z = (xs[2]-mu)*rstd*gw[t*4+2] + bw[t*4+2];
    o4.w = (xs[3]-mu)*rstd*gw[t*4+3] + bw[t*4+3];
    *((float4*)outp + (size_t)row * 256 + t) = o4;
  } else {
    bf16x4 o;
#pragma unroll
    for (int j = 0; j < 4; j++) o[j] = (short)f2b((xs[j]-mu)*rstd*gw[t*4+j] + bw[t*4+j]);
    *((bf16x4*)outp + (size_t)row * 256 + t) = o;
  }
}

// ---------- launch ----------
extern "C" void kernel_launch(void* const* d_in, const int* in_sizes, int n_in,
                              void* d_out, int out_size, void* d_ws, size_t ws_size,
                              hipStream_t stream){
  const float* Q    = (const float*)d_in[0];
  const float* K    = (const float*)d_in[1];
  const float* mask = (const float*)d_in[2];
  const float* Wq   = (const float*)d_in[4];  const float* bq  = (const float*)d_in[5];
  const float* Wk   = (const float*)d_in[6];  const float* bk  = (const float*)d_in[7];
  const float* Wv   = (const float*)d_in[8];  const float* bv  = (const float*)d_in[9];
  const float* Wo0  = (const float*)d_in[10]; const float* bo0 = (const float*)d_in[11];
  const float* Wo   = (const float*)d_in[12]; const float* bo  = (const float*)d_in[13];
  const float* Wo2  = (const float*)d_in[14]; const float* bo2 = (const float*)d_in[15];
  const float* g0   = (const float*)d_in[16]; const float* be0 = (const float*)d_in[17];
  const float* g1   = (const float*)d_in[18]; const float* be1 = (const float*)d_in[19];

  uint8_t* W = (uint8_t*)d_ws;
  const size_t MB = 1024ull * 1024ull;
  u16* Wq_t  = (u16*)(W + 0);
  u16* Wk_t  = (u16*)(W + 2  * MB);
  u16* Wv_t  = (u16*)(W + 4  * MB);
  u16* Wo0_t = (u16*)(W + 6  * MB);
  u16* Wo_t  = (u16*)(W + 8  * MB);   // [4096][1024]
  u16* Wo2_t = (u16*)(W + 16 * MB);   // [1024][4096]
  u16* Qb    = (u16*)(W + 24 * MB);
  u16* Kb    = (u16*)(W + 32 * MB);
  u16* qb    = (u16*)(W + 40 * MB);
  u16* kbf   = (u16*)(W + 48 * MB);
  u16* vtb   = (u16*)(W + 56 * MB);
  u16* ob    = (u16*)(W + 24 * MB);   // reuse Qb
  u16* x0b   = (u16*)(W + 32 * MB);   // reuse Kb
  u16* x1b   = (u16*)(W + 64 * MB);
  u16* hb    = (u16*)(W + 32 * MB);   // 32MB spanning dead x0b/qb/kbf/vtb
  u16* zb    = (u16*)(W + 24 * MB);   // reuse ob

  // input conversion (K compacted to first 1024 rows per batch)
  cvt_rows_k<<<4096, 256, 0, stream>>>(Q, Qb, 0);
  cvt_rows_k<<<4096, 256, 0, stream>>>(K, Kb, 512);
  transpose_cvt_k<<<dim3(16, 16), 256, 0, stream>>>(Wq,  Wq_t,  1024, 1024);
  transpose_cvt_k<<<dim3(16, 16), 256, 0, stream>>>(Wk,  Wk_t,  1024, 1024);
  transpose_cvt_k<<<dim3(16, 16), 256, 0, stream>>>(Wv,  Wv_t,  1024, 1024);
  transpose_cvt_k<<<dim3(16, 16), 256, 0, stream>>>(Wo0, Wo0_t, 1024, 1024);
  transpose_cvt_k<<<dim3(64, 16), 256, 0, stream>>>(Wo,  Wo_t,  1024, 4096);
  transpose_cvt_k<<<dim3(16, 64), 256, 0, stream>>>(Wo2, Wo2_t, 4096, 1024);

  // projections
  gemm_bt<0><<<dim3(8, 32), 256, 0, stream>>>(Qb, Wq_t, bq, nullptr, qb, 4096, 1024, 1024);
  gemm_bt<0><<<dim3(8, 32), 256, 0, stream>>>(Kb, Wk_t, bk, nullptr, kbf, 4096, 1024, 1024);
  gemm_bt<3><<<dim3(8, 32), 256, 0, stream>>>(Kb, Wv_t, bv, nullptr, vtb, 4096, 1024, 1024);

  // attention
  attn_k<<<dim3(16, 16, 4), 256, 0, stream>>>(qb, kbf, vtb, mask, ob);

  // output proj + residual, LN0
  gemm_bt<1><<<dim3(8, 32), 256, 0, stream>>>(ob, Wo0_t, bo0, qb, x0b, 4096, 1024, 1024);
  ln_k<0><<<4096, 256, 0, stream>>>(x0b, g0, be0, x1b);

  // FFN + residual, LN1
  gemm_bt<2><<<dim3(32, 32), 256, 0, stream>>>(x1b, Wo_t, bo, nullptr, hb, 4096, 4096, 1024);
  gemm_bt<1><<<dim3(8, 32), 256, 0, stream>>>(hb, Wo2_t, bo2, x1b, zb, 4096, 1024, 4096);
  ln_k<1><<<4096, 256, 0, stream>>>(zb, g1, be1, d_out);
}

// Round 3
// 347.747 us; speedup vs baseline: 1.4885x; 1.0886x over previous
//
#include <hip/hip_runtime.h>
#include <hip/hip_bf16.h>

typedef unsigned short u16;
typedef __attribute__((ext_vector_type(4))) short bf16x4;
typedef __attribute__((ext_vector_type(8))) short bf16x8;
typedef __attribute__((ext_vector_type(4))) float f32x4;

// ---------- helpers ----------
static __device__ __forceinline__ u16 f2b(float f){
  union { float f; unsigned u; } v; v.f = f;
  unsigned r = v.u + 0x7fffu + ((v.u >> 16) & 1u);   // RNE
  return (u16)(r >> 16);
}
static __device__ __forceinline__ float b2f(u16 h){
  union { unsigned u; float f; } v; v.u = ((unsigned)h) << 16; return v.f;
}
static __device__ __forceinline__ void gld_lds16(const void* g, void* l){
  __builtin_amdgcn_global_load_lds((const __attribute__((address_space(1))) void*)g,
                                   (__attribute__((address_space(3))) void*)l, 16, 0, 0);
}

// ---------- f32 -> bf16 convert: Q rows + K rows (compacted) in one grid ----------
__global__ __launch_bounds__(256) void cvt_qk(const float* __restrict__ Q,
                                              const float* __restrict__ K,
                                              u16* __restrict__ Qb,
                                              u16* __restrict__ Kb){
  const int row = blockIdx.x, t = threadIdx.x;
  const float* src; u16* dst;
  if (row < 4096){
    src = Q + (size_t)row * 1024; dst = Qb + (size_t)row * 1024;
  } else {
    int r = row - 4096;
    size_t ir = (size_t)r + (size_t)(r >> 10) * 512;    // skip rows 1024..1535 per batch
    src = K + ir * 1024; dst = Kb + (size_t)r * 1024;
  }
  const float4 v = *(const float4*)(src + t * 4);
  bf16x4 o;
  o[0] = (short)f2b(v.x); o[1] = (short)f2b(v.y);
  o[2] = (short)f2b(v.z); o[3] = (short)f2b(v.w);
  *(bf16x4*)(dst + t * 4) = o;
}

// ---------- weight transpose + convert: in [K][N] f32 -> out [N][K] bf16 ----------
static __device__ __forceinline__ void transpose_body(const float* __restrict__ in,
                                                      u16* __restrict__ out, int K, int N){
  __shared__ float tile[64][65];
  const int k0 = blockIdx.y * 64, n0 = blockIdx.x * 64;
  const int t = threadIdx.x, tr = t >> 4, tc = t & 15;
#pragma unroll
  for (int i = 0; i < 4; i++){
    int r = tr + i * 16;
    float4 v = *(const float4*)(in + (size_t)(k0 + r) * N + n0 + tc * 4);
    tile[r][tc*4+0] = v.x; tile[r][tc*4+1] = v.y; tile[r][tc*4+2] = v.z; tile[r][tc*4+3] = v.w;
  }
  __syncthreads();
#pragma unroll
  for (int i = 0; i < 4; i++){
    int nr = tr + i * 16;
    bf16x4 pk;
#pragma unroll
    for (int j = 0; j < 4; j++) pk[j] = (short)f2b(tile[tc*4+j][nr]);
    *(bf16x4*)(out + (size_t)(n0 + nr) * K + k0 + tc * 4) = pk;
  }
}

__global__ __launch_bounds__(256) void transpose_cvt_k(const float* __restrict__ in,
                                                       u16* __restrict__ out, int K, int N){
  transpose_body(in, out, K, N);
}

// four 1024x1024 transposes in one dispatch (z selects)
__global__ __launch_bounds__(256) void transpose_cvt4(const float* __restrict__ i0, u16* __restrict__ o0,
                                                      const float* __restrict__ i1, u16* __restrict__ o1,
                                                      const float* __restrict__ i2, u16* __restrict__ o2,
                                                      const float* __restrict__ i3, u16* __restrict__ o3){
  const float* in; u16* out;
  switch (blockIdx.z){
    case 0: in = i0; out = o0; break;
    case 1: in = i1; out = o1; break;
    case 2: in = i2; out = o2; break;
    default: in = i3; out = o3; break;
  }
  transpose_body(in, out, 1024, 1024);
}

// ---------- GEMM main loop (m97 structure: 128x128 tile, BK=64) ----------
static __device__ __forceinline__ void gemm_mainloop(const u16* __restrict__ A,
                                                     const u16* __restrict__ Bt,
                                                     int lda, int ldb, int kbeg, int kend,
                                                     int m0, int n0,
                                                     u16* lA, u16* lB, f32x4 acc[4][4]){
  const int t = threadIdx.x, w = t >> 6, l = t & 63;
  const int wr = w >> 1, wc = w & 1;
  const int lrow = l >> 3, lc8 = l & 7;
  const int c = l & 15, g = l >> 4;
  for (int k0 = kbeg; k0 < kend; k0 += 64){
#pragma unroll
    for (int i = 0; i < 4; i++){
      int ch = w * 4 + i;
      int r  = ch * 8 + lrow;
      gld_lds16(A  + (size_t)(m0 + r) * lda + k0 + lc8 * 8, lA + ch * 512);
      gld_lds16(Bt + (size_t)(n0 + r) * ldb + k0 + lc8 * 8, lB + ch * 512);
    }
    __syncthreads();
#pragma unroll
    for (int ks = 0; ks < 2; ks++){
      bf16x8 af[4], bfr[4];
#pragma unroll
      for (int mi = 0; mi < 4; mi++){
        int row = wr * 64 + mi * 16 + c;
        af[mi] = *(const bf16x8*)((const char*)lA + row * 128 + ks * 64 + g * 16);
      }
#pragma unroll
      for (int ni = 0; ni < 4; ni++){
        int row = wc * 64 + ni * 16 + c;
        bfr[ni] = *(const bf16x8*)((const char*)lB + row * 128 + ks * 64 + g * 16);
      }
#pragma unroll
      for (int mi = 0; mi < 4; mi++)
#pragma unroll
        for (int ni = 0; ni < 4; ni++)
          acc[mi][ni] = __builtin_amdgcn_mfma_f32_16x16x32_bf16(af[mi], bfr[ni], acc[mi][ni], 0, 0, 0);
    }
    __syncthreads();
  }
}

// ---------- GEMM: C[M,N] = A[M,K] @ Bt[N,K]^T + bias ----------
// EPI: 0 = bias -> bf16 ; 1 = bias + residual -> bf16 ; 2 = bias + relu -> bf16
template<int EPI>
__global__ __launch_bounds__(256) void gemm_bt(const u16* __restrict__ A,
                                               const u16* __restrict__ Bt,
                                               const float* __restrict__ bias,
                                               const u16* __restrict__ res,
                                               u16* __restrict__ out,
                                               int M, int N, int K){
  __shared__ u16 lA[128 * 64];
  __shared__ u16 lB[128 * 64];
  const int t = threadIdx.x, w = t >> 6, l = t & 63;
  const int m0 = blockIdx.y * 128, n0 = blockIdx.x * 128;
  const int wr = w >> 1, wc = w & 1;
  const int c = l & 15, g = l >> 4;

  f32x4 acc[4][4];
#pragma unroll
  for (int i = 0; i < 4; i++)
#pragma unroll
    for (int j = 0; j < 4; j++) acc[i][j] = (f32x4){0.f, 0.f, 0.f, 0.f};

  gemm_mainloop(A, Bt, K, K, 0, K, m0, n0, lA, lB, acc);

#pragma unroll
  for (int ni = 0; ni < 4; ni++){
    int n = n0 + wc * 64 + ni * 16 + c;
    float bv = bias[n];
#pragma unroll
    for (int mi = 0; mi < 4; mi++){
      int row0 = m0 + wr * 64 + mi * 16 + 4 * g;
#pragma unroll
      for (int r = 0; r < 4; r++){
        int row = row0 + r;
        float v = acc[mi][ni][r] + bv;
        if (EPI == 1) v += b2f(res[(size_t)row * N + n]);
        if (EPI == 2) v = fmaxf(v, 0.f);
        out[(size_t)row * N + n] = f2b(v);
      }
    }
  }
}

// ---------- fused QKV projection: z=0 Q, z=1 K, z=2 V (V writes transposed) ----------
__global__ __launch_bounds__(256) void gemm_qkv(const u16* __restrict__ Qb,
                                                const u16* __restrict__ Kb,
                                                const u16* __restrict__ Wq_t,
                                                const u16* __restrict__ Wk_t,
                                                const u16* __restrict__ Wv_t,
                                                const float* __restrict__ bq,
                                                const float* __restrict__ bk,
                                                const float* __restrict__ bv,
                                                u16* __restrict__ qb,
                                                u16* __restrict__ kbf,
                                                u16* __restrict__ vtb){
  __shared__ u16 lA[128 * 64];
  __shared__ u16 lB[128 * 64];
  const int z = blockIdx.z;
  const u16* A    = (z == 0) ? Qb   : Kb;
  const u16* Bt   = (z == 0) ? Wq_t : (z == 1) ? Wk_t : Wv_t;
  const float* bi = (z == 0) ? bq   : (z == 1) ? bk   : bv;

  const int t = threadIdx.x, w = t >> 6, l = t & 63;
  const int m0 = blockIdx.y * 128, n0 = blockIdx.x * 128;
  const int wr = w >> 1, wc = w & 1;
  const int c = l & 15, g = l >> 4;

  f32x4 acc[4][4];
#pragma unroll
  for (int i = 0; i < 4; i++)
#pragma unroll
    for (int j = 0; j < 4; j++) acc[i][j] = (f32x4){0.f, 0.f, 0.f, 0.f};

  gemm_mainloop(A, Bt, 1024, 1024, 0, 1024, m0, n0, lA, lB, acc);

#pragma unroll
  for (int ni = 0; ni < 4; ni++){
    int n = n0 + wc * 64 + ni * 16 + c;
    float bv_ = bi[n];
#pragma unroll
    for (int mi = 0; mi < 4; mi++){
      int row0 = m0 + wr * 64 + mi * 16 + 4 * g;
      if (z == 2){
        // V: write transposed vt[b][n dh][key] bf16
        bf16x4 pk;
#pragma unroll
        for (int r = 0; r < 4; r++) pk[r] = (short)f2b(acc[mi][ni][r] + bv_);
        int bb = row0 >> 10, key = row0 & 1023;
        *(bf16x4*)(vtb + ((size_t)bb << 20) + (size_t)n * 1024 + key) = pk;
      } else {
        u16* out = (z == 0) ? qb : kbf;
#pragma unroll
        for (int r = 0; r < 4; r++){
          int row = row0 + r;
          out[(size_t)row * 1024 + n] = f2b(acc[mi][ni][r] + bv_);
        }
      }
    }
  }
}

// ---------- split-K GEMM for FF2: f32 partials, z = K-half ----------
__global__ __launch_bounds__(256) void gemm_splitk(const u16* __restrict__ A,
                                                   const u16* __restrict__ Bt,
                                                   float* __restrict__ pout){
  __shared__ u16 lA[128 * 64];
  __shared__ u16 lB[128 * 64];
  const int t = threadIdx.x, w = t >> 6, l = t & 63;
  const int m0 = blockIdx.y * 128, n0 = blockIdx.x * 128;
  const int wr = w >> 1, wc = w & 1;
  const int c = l & 15, g = l >> 4;
  const int kbeg = blockIdx.z * 2048;

  f32x4 acc[4][4];
#pragma unroll
  for (int i = 0; i < 4; i++)
#pragma unroll
    for (int j = 0; j < 4; j++) acc[i][j] = (f32x4){0.f, 0.f, 0.f, 0.f};

  gemm_mainloop(A, Bt, 4096, 4096, kbeg, kbeg + 2048, m0, n0, lA, lB, acc);

  float* po = pout + ((size_t)blockIdx.z << 22);
#pragma unroll
  for (int ni = 0; ni < 4; ni++){
    int n = n0 + wc * 64 + ni * 16 + c;
#pragma unroll
    for (int mi = 0; mi < 4; mi++){
      int row0 = m0 + wr * 64 + mi * 16 + 4 * g;
#pragma unroll
      for (int r = 0; r < 4; r++)
        po[(size_t)(row0 + r) * 1024 + n] = acc[mi][ni][r];
    }
  }
}

// ---------- FF2 combiner: p0 + p1 + bias + residual -> bf16 ----------
__global__ __launch_bounds__(256) void combine_ff2(const float* __restrict__ pp,
                                                   const float* __restrict__ bias,
                                                   const u16* __restrict__ res,
                                                   u16* __restrict__ out){
  const size_t i4 = ((size_t)blockIdx.x * 256 + threadIdx.x) * 4;
  const int col = (int)(i4 & 1023);
  f32x4 a = *(const f32x4*)(pp + i4);
  f32x4 b = *(const f32x4*)(pp + (1ull << 22) + i4);
  bf16x4 rv = *(const bf16x4*)(res + i4);
  bf16x4 o;
#pragma unroll
  for (int j = 0; j < 4; j++)
    o[j] = (short)f2b(a[j] + b[j] + bias[col + j] + b2f((u16)rv[j]));
  *(bf16x4*)(out + i4) = o;
}

// ---------- fused masked attention (flash-style, swapped-operand) ----------
__global__ __launch_bounds__(256, 4) void attn_k(const u16* __restrict__ qb,
                                                 const u16* __restrict__ kb,
                                                 const u16* __restrict__ vt,
                                                 const float* __restrict__ mask,
                                                 u16* __restrict__ ob){
  __shared__ u16 sK[2][4096];   // [key][dh], row stride 128B, XOR-swizzled
  __shared__ u16 sV[2][4096];   // [dh][key], row stride 128B, XOR-swizzled

  const int t = threadIdx.x, w = t >> 6, l = t & 63;
  const int c = l & 15, g = l >> 4;
  const int q0 = blockIdx.x * 64, h = blockIdx.y, b = blockIdx.z;
  const int qrow = q0 + w * 16 + c;
  const size_t qoff = ((size_t)(b * 1024 + qrow)) * 1024 + h * 64;
  const bf16x8 bq0 = *(const bf16x8*)(qb + qoff + g * 8);
  const bf16x8 bq1 = *(const bf16x8*)(qb + qoff + 32 + g * 8);
  const u16* kbase = kb + ((size_t)b * 1024) * 1024 + h * 64;
  const u16* vbase = vt + ((size_t)b << 20) + (size_t)(h * 64) * 1024;
  const float* mbase = mask + ((size_t)(h * 4 + b) * 1024 + qrow) * 1024;

  const int lr3 = l >> 3, lc3 = l & 7;
  const int ch0 = w * 2;

  auto stage = [&](int buf, int kv){
#pragma unroll
    for (int i = 0; i < 2; i++){
      int ch  = ch0 + i;
      int row = ch * 8 + lr3;
      int L   = (lc3 * 16) ^ ((row & 7) << 4);      // inverse-swizzled source colbyte
      gld_lds16(kbase + (size_t)(kv + row) * 1024 + (L >> 1), &sK[buf][ch * 512]);
      gld_lds16(vbase + (size_t)row * 1024 + kv + (L >> 1),   &sV[buf][ch * 512]);
    }
  };

  float m = -INFINITY, lsum = 0.f;
  f32x4 acc[4];
#pragma unroll
  for (int f = 0; f < 4; f++) acc[f] = (f32x4){0.f, 0.f, 0.f, 0.f};

  stage(0, 0);
  f32x4 mc[4];
#pragma unroll
  for (int nf = 0; nf < 4; nf++) mc[nf] = *(const f32x4*)(mbase + nf * 16 + g * 4);
  __syncthreads();

  const int sw = (c & 7) << 4;
  int cur = 0;
  for (int it = 0; it < 16; ++it){
    const int kv = it * 64;
    f32x4 mn[4];
    if (it < 15){
      stage(cur ^ 1, kv + 64);
#pragma unroll
      for (int nf = 0; nf < 4; nf++)
        mn[nf] = *(const f32x4*)(mbase + kv + 64 + nf * 16 + g * 4);
    }

    const char* kt = (const char*)sK[cur];
    f32x4 st[4];
#pragma unroll
    for (int nf = 0; nf < 4; nf++){
      const char* kr = kt + (nf * 16 + c) * 128;
      bf16x8 ak0 = *(const bf16x8*)(kr + ((g * 16) ^ sw));
      bf16x8 ak1 = *(const bf16x8*)(kr + ((64 + g * 16) ^ sw));
      f32x4 z = (f32x4){0.f, 0.f, 0.f, 0.f};
      z = __builtin_amdgcn_mfma_f32_16x16x32_bf16(ak0, bq0, z, 0, 0, 0);
      z = __builtin_amdgcn_mfma_f32_16x16x32_bf16(ak1, bq1, z, 0, 0, 0);
      st[nf] = z;
    }

    float tmax = -INFINITY;
#pragma unroll
    for (int nf = 0; nf < 4; nf++)
#pragma unroll
      for (int r = 0; r < 4; r++){
        float v = st[nf][r] * 0.03125f + mc[nf][r];
        st[nf][r] = v; tmax = fmaxf(tmax, v);
      }
    tmax = fmaxf(tmax, __shfl_xor(tmax, 16));
    tmax = fmaxf(tmax, __shfl_xor(tmax, 32));
    float mnew  = fmaxf(m, tmax);
    float alpha = __expf(m - mnew);
    float rs = 0.f;
    bf16x4 pb[4];
#pragma unroll
    for (int nf = 0; nf < 4; nf++)
#pragma unroll
      for (int r = 0; r < 4; r++){
        float p = __expf(st[nf][r] - mnew);
        rs += p;
        pb[nf][r] = (short)f2b(p);
      }
    rs += __shfl_xor(rs, 16); rs += __shfl_xor(rs, 32);
    lsum = lsum * alpha + rs; m = mnew;
#pragma unroll
    for (int f = 0; f < 4; f++){
      acc[f][0] *= alpha; acc[f][1] *= alpha; acc[f][2] *= alpha; acc[f][3] *= alpha;
    }

    const char* vtc = (const char*)sV[cur];
#pragma unroll
    for (int f = 0; f < 4; f++){
      const char* vr = vtc + (f * 16 + c) * 128;
#pragma unroll
      for (int nf = 0; nf < 4; nf++){
        bf16x4 av = *(const bf16x4*)(vr + ((nf * 32 + g * 8) ^ sw));
        acc[f] = __builtin_amdgcn_mfma_f32_16x16x16bf16_1k(av, pb[nf], acc[f], 0, 0, 0);
      }
    }

    __syncthreads();
    cur ^= 1;
    if (it < 15){
#pragma unroll
      for (int nf = 0; nf < 4; nf++) mc[nf] = mn[nf];
    }
  }

  const float inv = 1.f / lsum;
#pragma unroll
  for (int f = 0; f < 4; f++){
    bf16x4 pk;
#pragma unroll
    for (int r = 0; r < 4; r++) pk[r] = (short)f2b(acc[f][r] * inv);
    *(bf16x4*)(ob + qoff + f * 16 + g * 4) = pk;
  }
}

// ---------- LayerNorm over 1024 cols ----------
template<int F32OUT>
__global__ __launch_bounds__(256) void ln_k(const u16* __restrict__ x,
                                            const float* __restrict__ gw,
                                            const float* __restrict__ bw,
                                            void* __restrict__ outp){
  const int row = blockIdx.x, t = threadIdx.x, w = t >> 6, l = t & 63;
  const u16* xr = x + (size_t)row * 1024;
  bf16x4 xv = *(const bf16x4*)(xr + t * 4);
  float xs[4], s = 0.f, sq = 0.f;
#pragma unroll
  for (int j = 0; j < 4; j++){ xs[j] = b2f((u16)xv[j]); s += xs[j]; sq += xs[j] * xs[j]; }
#pragma unroll
  for (int o = 32; o; o >>= 1){ s += __shfl_xor(s, o); sq += __shfl_xor(sq, o); }
  __shared__ float rs[4], rq[4];
  if (l == 0){ rs[w] = s; rq[w] = sq; }
  __syncthreads();
  s  = rs[0] + rs[1] + rs[2] + rs[3];
  sq = rq[0] + rq[1] + rq[2] + rq[3];
  const float mu   = s * (1.f / 1024.f);
  const float var  = sq * (1.f / 1024.f) - mu * mu;
  const float rstd = rsqrtf(var + 1e-5f);
  if (F32OUT){
    float4 o4;
    o4.x = (xs[0]-mu)*rstd*gw[t*4+0] + bw[t*4+0];
    o4.y = (xs[1]-mu)*rstd*gw[t*4+1] + bw[t*4+1];
    o4.z = (xs[2]-mu)*rstd*gw[t*4+2] + bw[t*4+2];
    o4.w = (xs[3]-mu)*rstd*gw[t*4+3] + bw[t*4+3];
    *((float4*)outp + (size_t)row * 256 + t) = o4;
  } else {
    bf16x4 o;
#pragma unroll
    for (int j = 0; j < 4; j++) o[j] = (short)f2b((xs[j]-mu)*rstd*gw[t*4+j] + bw[t*4+j]);
    *((bf16x4*)outp + (size_t)row * 256 + t) = o;
  }
}

// ---------- launch ----------
extern "C" void kernel_launch(void* const* d_in, const int* in_sizes, int n_in,
                              void* d_out, int out_size, void* d_ws, size_t ws_size,
                              hipStream_t stream){
  const float* Q    = (const float*)d_in[0];
  const float* K    = (const float*)d_in[1];
  const float* mask = (const float*)d_in[2];
  const float* Wq   = (const float*)d_in[4];  const float* bq  = (const float*)d_in[5];
  const float* Wk   = (const float*)d_in[6];  const float* bk  = (const float*)d_in[7];
  const float* Wv   = (const float*)d_in[8];  const float* bv  = (const float*)d_in[9];
  const float* Wo0  = (const float*)d_in[10]; const float* bo0 = (const float*)d_in[11];
  const float* Wo   = (const float*)d_in[12]; const float* bo  = (const float*)d_in[13];
  const float* Wo2  = (const float*)d_in[14]; const float* bo2 = (const float*)d_in[15];
  const float* g0   = (const float*)d_in[16]; const float* be0 = (const float*)d_in[17];
  const float* g1   = (const float*)d_in[18]; const float* be1 = (const float*)d_in[19];

  uint8_t* W = (uint8_t*)d_ws;
  const size_t MB = 1024ull * 1024ull;
  u16* Wq_t  = (u16*)(W + 0);
  u16* Wk_t  = (u16*)(W + 2  * MB);
  u16* Wv_t  = (u16*)(W + 4  * MB);
  u16* Wo0_t = (u16*)(W + 6  * MB);
  u16* Wo_t  = (u16*)(W + 8  * MB);   // [4096][1024]
  u16* Wo2_t = (u16*)(W + 16 * MB);   // [1024][4096]
  u16* Qb    = (u16*)(W + 24 * MB);
  u16* Kb    = (u16*)(W + 32 * MB);
  u16* qb    = (u16*)(W + 40 * MB);
  u16* kbf   = (u16*)(W + 48 * MB);
  u16* vtb   = (u16*)(W + 56 * MB);
  u16* ob    = (u16*)(W + 24 * MB);   // reuse Qb
  u16* x0b   = (u16*)(W + 32 * MB);   // reuse Kb
  u16* x1b   = (u16*)(W + 64 * MB);
  u16* hb    = (u16*)(W + 32 * MB);   // [4096][4096] bf16, spans dead x0b/qb/kbf/vtb
  u16* zb    = (u16*)(W + 24 * MB);   // reuse ob
  float* pp  = (float*)(W + 72 * MB); // 2 x 16MB f32 FF2 partials

  // input conversions (independent -> fused/overlapped)
  cvt_qk<<<8192, 256, 0, stream>>>(Q, K, Qb, Kb);
  transpose_cvt4<<<dim3(16, 16, 4), 256, 0, stream>>>(Wq, Wq_t, Wk, Wk_t, Wv, Wv_t, Wo0, Wo0_t);
  transpose_cvt_k<<<dim3(64, 16), 256, 0, stream>>>(Wo,  Wo_t,  1024, 4096);
  transpose_cvt_k<<<dim3(16, 64), 256, 0, stream>>>(Wo2, Wo2_t, 4096, 1024);

  // fused QKV projections (768 blocks = 3 blocks/CU)
  gemm_qkv<<<dim3(8, 32, 3), 256, 0, stream>>>(Qb, Kb, Wq_t, Wk_t, Wv_t,
                                               bq, bk, bv, qb, kbf, vtb);

  // attention
  attn_k<<<dim3(16, 16, 4), 256, 0, stream>>>(qb, kbf, vtb, mask, ob);

  // output proj + residual, LN0
  gemm_bt<1><<<dim3(8, 32), 256, 0, stream>>>(ob, Wo0_t, bo0, qb, x0b, 4096, 1024, 1024);
  ln_k<0><<<4096, 256, 0, stream>>>(x0b, g0, be0, x1b);

  // FFN: FF1 (relu) -> split-K FF2 -> combine(+bias+residual), LN1
  gemm_bt<2><<<dim3(32, 32), 256, 0, stream>>>(x1b, Wo_t, bo, nullptr, hb, 4096, 4096, 1024);
  gemm_splitk<<<dim3(8, 32, 2), 256, 0, stream>>>(hb, Wo2_t, pp);
  combine_ff2<<<4096, 256, 0, stream>>>(pp, bo2, x1b, zb);
  ln_k<1><<<4096, 256, 0, stream>>>(zb, g1, be1, d_out);
}

// Round 4
// 325.401 us; speedup vs baseline: 1.5907x; 1.0687x over previous
//
#include <hip/hip_runtime.h>
#include <hip/hip_bf16.h>

typedef unsigned short u16;
typedef __attribute__((ext_vector_type(4))) short bf16x4;
typedef __attribute__((ext_vector_type(8))) short bf16x8;
typedef __attribute__((ext_vector_type(4))) float f32x4;

// ---------- helpers ----------
static __device__ __forceinline__ u16 f2b(float f){
  union { float f; unsigned u; } v; v.f = f;
  unsigned r = v.u + 0x7fffu + ((v.u >> 16) & 1u);   // RNE
  return (u16)(r >> 16);
}
static __device__ __forceinline__ float b2f(u16 h){
  union { unsigned u; float f; } v; v.u = ((unsigned)h) << 16; return v.f;
}
static __device__ __forceinline__ void gld_lds16(const void* g, void* l){
  __builtin_amdgcn_global_load_lds((const __attribute__((address_space(1))) void*)g,
                                   (__attribute__((address_space(3))) void*)l, 16, 0, 0);
}

// ---------- f32 -> bf16 convert: Q rows + K rows (compacted) in one grid ----------
__global__ __launch_bounds__(256) void cvt_qk(const float* __restrict__ Q,
                                              const float* __restrict__ K,
                                              u16* __restrict__ Qb,
                                              u16* __restrict__ Kb){
  const int row = blockIdx.x, t = threadIdx.x;
  const float* src; u16* dst;
  if (row < 4096){
    src = Q + (size_t)row * 1024; dst = Qb + (size_t)row * 1024;
  } else {
    int r = row - 4096;
    size_t ir = (size_t)r + (size_t)(r >> 10) * 512;    // skip rows 1024..1535 per batch
    src = K + ir * 1024; dst = Kb + (size_t)r * 1024;
  }
  const float4 v = *(const float4*)(src + t * 4);
  bf16x4 o;
  o[0] = (short)f2b(v.x); o[1] = (short)f2b(v.y);
  o[2] = (short)f2b(v.z); o[3] = (short)f2b(v.w);
  *(bf16x4*)(dst + t * 4) = o;
}

// ---------- weight transpose + convert: in [K][N] f32 -> out [N][K] bf16 ----------
static __device__ __forceinline__ void transpose_body(const float* __restrict__ in,
                                                      u16* __restrict__ out, int K, int N){
  __shared__ float tile[64][65];
  const int k0 = blockIdx.y * 64, n0 = blockIdx.x * 64;
  const int t = threadIdx.x, tr = t >> 4, tc = t & 15;
#pragma unroll
  for (int i = 0; i < 4; i++){
    int r = tr + i * 16;
    float4 v = *(const float4*)(in + (size_t)(k0 + r) * N + n0 + tc * 4);
    tile[r][tc*4+0] = v.x; tile[r][tc*4+1] = v.y; tile[r][tc*4+2] = v.z; tile[r][tc*4+3] = v.w;
  }
  __syncthreads();
#pragma unroll
  for (int i = 0; i < 4; i++){
    int nr = tr + i * 16;
    bf16x4 pk;
#pragma unroll
    for (int j = 0; j < 4; j++) pk[j] = (short)f2b(tile[tc*4+j][nr]);
    *(bf16x4*)(out + (size_t)(n0 + nr) * K + k0 + tc * 4) = pk;
  }
}

__global__ __launch_bounds__(256) void transpose_cvt_k(const float* __restrict__ in,
                                                       u16* __restrict__ out, int K, int N){
  transpose_body(in, out, K, N);
}

__global__ __launch_bounds__(256) void transpose_cvt4(const float* __restrict__ i0, u16* __restrict__ o0,
                                                      const float* __restrict__ i1, u16* __restrict__ o1,
                                                      const float* __restrict__ i2, u16* __restrict__ o2,
                                                      const float* __restrict__ i3, u16* __restrict__ o3){
  const float* in; u16* out;
  switch (blockIdx.z){
    case 0: in = i0; out = o0; break;
    case 1: in = i1; out = o1; break;
    case 2: in = i2; out = o2; break;
    default: in = i3; out = o3; break;
  }
  transpose_body(in, out, 1024, 1024);
}

// ---------- m97-structure GEMM main loop (128x128 tile, BK=64) ----------
static __device__ __forceinline__ void gemm_mainloop(const u16* __restrict__ A,
                                                     const u16* __restrict__ Bt,
                                                     int lda, int ldb, int kbeg, int kend,
                                                     int m0, int n0,
                                                     u16* lA, u16* lB, f32x4 acc[4][4]){
  const int t = threadIdx.x, w = t >> 6, l = t & 63;
  const int wr = w >> 1, wc = w & 1;
  const int lrow = l >> 3, lc8 = l & 7;
  const int c = l & 15, g = l >> 4;
  for (int k0 = kbeg; k0 < kend; k0 += 64){
#pragma unroll
    for (int i = 0; i < 4; i++){
      int ch = w * 4 + i;
      int r  = ch * 8 + lrow;
      gld_lds16(A  + (size_t)(m0 + r) * lda + k0 + lc8 * 8, lA + ch * 512);
      gld_lds16(Bt + (size_t)(n0 + r) * ldb + k0 + lc8 * 8, lB + ch * 512);
    }
    __syncthreads();
#pragma unroll
    for (int ks = 0; ks < 2; ks++){
      bf16x8 af[4], bfr[4];
#pragma unroll
      for (int mi = 0; mi < 4; mi++){
        int row = wr * 64 + mi * 16 + c;
        af[mi] = *(const bf16x8*)((const char*)lA + row * 128 + ks * 64 + g * 16);
      }
#pragma unroll
      for (int ni = 0; ni < 4; ni++){
        int row = wc * 64 + ni * 16 + c;
        bfr[ni] = *(const bf16x8*)((const char*)lB + row * 128 + ks * 64 + g * 16);
      }
#pragma unroll
      for (int mi = 0; mi < 4; mi++)
#pragma unroll
        for (int ni = 0; ni < 4; ni++)
          acc[mi][ni] = __builtin_amdgcn_mfma_f32_16x16x32_bf16(af[mi], bfr[ni], acc[mi][ni], 0, 0, 0);
    }
    __syncthreads();
  }
}

// ---------- m97 GEMM: EPI 1 = bias + residual -> bf16 ----------
__global__ __launch_bounds__(256) void gemm_res(const u16* __restrict__ A,
                                                const u16* __restrict__ Bt,
                                                const float* __restrict__ bias,
                                                const u16* __restrict__ res,
                                                u16* __restrict__ out,
                                                int N, int K){
  __shared__ u16 lA[128 * 64];
  __shared__ u16 lB[128 * 64];
  const int t = threadIdx.x, w = t >> 6, l = t & 63;
  const int m0 = blockIdx.y * 128, n0 = blockIdx.x * 128;
  const int wr = w >> 1, wc = w & 1;
  const int c = l & 15, g = l >> 4;

  f32x4 acc[4][4];
#pragma unroll
  for (int i = 0; i < 4; i++)
#pragma unroll
    for (int j = 0; j < 4; j++) acc[i][j] = (f32x4){0.f, 0.f, 0.f, 0.f};

  gemm_mainloop(A, Bt, K, K, 0, K, m0, n0, lA, lB, acc);

#pragma unroll
  for (int ni = 0; ni < 4; ni++){
    int n = n0 + wc * 64 + ni * 16 + c;
    float bv = bias[n];
#pragma unroll
    for (int mi = 0; mi < 4; mi++){
      int row0 = m0 + wr * 64 + mi * 16 + 4 * g;
#pragma unroll
      for (int r = 0; r < 4; r++){
        int row = row0 + r;
        float v = acc[mi][ni][r] + bv + b2f(res[(size_t)row * N + n]);
        out[(size_t)row * N + n] = f2b(v);
      }
    }
  }
}

// ---------- fused QKV projection (m97 structure): z=0 Q, z=1 K, z=2 V(transposed) ----------
__global__ __launch_bounds__(256) void gemm_qkv(const u16* __restrict__ Qb,
                                                const u16* __restrict__ Kb,
                                                const u16* __restrict__ Wq_t,
                                                const u16* __restrict__ Wk_t,
                                                const u16* __restrict__ Wv_t,
                                                const float* __restrict__ bq,
                                                const float* __restrict__ bk,
                                                const float* __restrict__ bv,
                                                u16* __restrict__ qb,
                                                u16* __restrict__ kbf,
                                                u16* __restrict__ vtb){
  __shared__ u16 lA[128 * 64];
  __shared__ u16 lB[128 * 64];
  const int z = blockIdx.z;
  const u16* A    = (z == 0) ? Qb   : Kb;
  const u16* Bt   = (z == 0) ? Wq_t : (z == 1) ? Wk_t : Wv_t;
  const float* bi = (z == 0) ? bq   : (z == 1) ? bk   : bv;

  const int t = threadIdx.x, w = t >> 6, l = t & 63;
  const int m0 = blockIdx.y * 128, n0 = blockIdx.x * 128;
  const int wr = w >> 1, wc = w & 1;
  const int c = l & 15, g = l >> 4;

  f32x4 acc[4][4];
#pragma unroll
  for (int i = 0; i < 4; i++)
#pragma unroll
    for (int j = 0; j < 4; j++) acc[i][j] = (f32x4){0.f, 0.f, 0.f, 0.f};

  gemm_mainloop(A, Bt, 1024, 1024, 0, 1024, m0, n0, lA, lB, acc);

#pragma unroll
  for (int ni = 0; ni < 4; ni++){
    int n = n0 + wc * 64 + ni * 16 + c;
    float bv_ = bi[n];
#pragma unroll
    for (int mi = 0; mi < 4; mi++){
      int row0 = m0 + wr * 64 + mi * 16 + 4 * g;
      if (z == 2){
        bf16x4 pk;
#pragma unroll
        for (int r = 0; r < 4; r++) pk[r] = (short)f2b(acc[mi][ni][r] + bv_);
        int bb = row0 >> 10, key = row0 & 1023;
        *(bf16x4*)(vtb + ((size_t)bb << 20) + (size_t)n * 1024 + key) = pk;
      } else {
        u16* out = (z == 0) ? qb : kbf;
#pragma unroll
        for (int r = 0; r < 4; r++){
          int row = row0 + r;
          out[(size_t)row * 1024 + n] = f2b(acc[mi][ni][r] + bv_);
        }
      }
    }
  }
}

// ---------- 256x256 8-phase GEMM (T2+T3+T4+T5), BK=64, 8 waves ----------
// LDS: 2 dbuf x (A,B) x 2 halves of [128 rows][64 cols] bf16, XOR-swizzled.
// Wave (wr,wc) of 2x4 owns C[128x64]: reads A-half wr, B-half wc>>1 only.
// Staging: q0->A0(T+1), q1->A1(T+1), q2->B0(T+2), q3->B1(T+2); vmcnt(4) + barrier at q0.
// EPI 0: bias+relu -> bf16 ; EPI 1: f32 partial (split-K, z-indexed)
template<int EPI>
__global__ __launch_bounds__(512, 2) void gemm8p(const u16* __restrict__ A,
                                                 const u16* __restrict__ Bt,
                                                 const float* __restrict__ bias,
                                                 void* __restrict__ outp,
                                                 int lda, int ldb, int ldout,
                                                 int ksz, int NT){
  __shared__ u16 sA[2][2][8192];
  __shared__ u16 sB[2][2][8192];
  const int t = threadIdx.x, w = t >> 6, l = t & 63;
  const int wr = w >> 2, wc = w & 3;
  const int c = l & 15, g = l >> 4;
  const int m0 = blockIdx.y * 256, n0 = blockIdx.x * 256;
  const int kbeg = blockIdx.z * ksz;
  const int sr = t >> 3, scb = (t & 7) << 4;

  f32x4 acc[8][4];
#pragma unroll
  for (int i = 0; i < 8; i++)
#pragma unroll
    for (int j = 0; j < 4; j++) acc[i][j] = (f32x4){0.f, 0.f, 0.f, 0.f};

  // stage one 128x64 half-tile (2 x gld_lds16 per thread); LDS linear dest,
  // inverse-swizzled global source (same involution as the read side).
  auto stA = [&](int d, int h, int T){
#pragma unroll
    for (int i = 0; i < 2; i++){
      int row = i * 64 + sr;
      int Lb  = scb ^ ((row & 7) << 4);
      gld_lds16(A + (size_t)(m0 + h * 128 + row) * lda + kbeg + T * 64 + (Lb >> 1),
                (char*)&sA[d][h][0] + i * 8192 + t * 16);
    }
  };
  auto stB = [&](int d, int h, int T){
#pragma unroll
    for (int i = 0; i < 2; i++){
      int row = i * 64 + sr;
      int Lb  = scb ^ ((row & 7) << 4);
      gld_lds16(Bt + (size_t)(n0 + h * 128 + row) * ldb + kbeg + T * 64 + (Lb >> 1),
                (char*)&sB[d][h][0] + i * 8192 + t * 16);
    }
  };

  // prologue: B0(0),B1(0),A0(0),A1(0),B0(1),B1(1)  (12 vmcnt slots/thread)
  stB(0, 0, 0); stB(0, 1, 0); stA(0, 0, 0); stA(0, 1, 0);
  stB(1, 0, 1); stB(1, 1, 1);

  bf16x8 bfr[4][2];
  for (int T = 0; T < NT; ++T){
    const int d = T & 1;
    const char* pa = (const char*)&sA[d][wr][0];
    const char* pb = (const char*)&sB[d][wc >> 1][0];
#pragma unroll
    for (int q = 0; q < 4; ++q){
      if (q == 0){
        // counted wait: leave the 2 B-half slots of T+1 in flight; then cross-wave barrier
        if (T + 1 < NT) asm volatile("s_waitcnt vmcnt(4)" ::: "memory");
        else            asm volatile("s_waitcnt vmcnt(0)" ::: "memory");
        asm volatile("" ::: "memory");
        __builtin_amdgcn_s_barrier();
        asm volatile("" ::: "memory");
#pragma unroll
        for (int nf = 0; nf < 4; ++nf){
          int lr = (wc & 1) * 64 + nf * 16 + c;
#pragma unroll
          for (int ks = 0; ks < 2; ++ks)
            bfr[nf][ks] = *(const bf16x8*)(pb + lr * 128 + ((ks * 64 + g * 16) ^ ((lr & 7) << 4)));
        }
      }
      bf16x8 af[2][2];
#pragma unroll
      for (int mi = 0; mi < 2; ++mi){
        int lr = (q * 2 + mi) * 16 + c;
#pragma unroll
        for (int ks = 0; ks < 2; ++ks)
          af[mi][ks] = *(const bf16x8*)(pa + lr * 128 + ((ks * 64 + g * 16) ^ ((lr & 7) << 4)));
      }
      if      (q == 0){ if (T + 1 < NT) stA(d ^ 1, 0, T + 1); }
      else if (q == 1){ if (T + 1 < NT) stA(d ^ 1, 1, T + 1); }
      else if (q == 2){ if (T + 2 < NT) stB(d, 0, T + 2); }
      else            { if (T + 2 < NT) stB(d, 1, T + 2); }
      __builtin_amdgcn_s_setprio(1);
#pragma unroll
      for (int mi = 0; mi < 2; ++mi)
#pragma unroll
        for (int nf = 0; nf < 4; ++nf)
#pragma unroll
          for (int ks = 0; ks < 2; ++ks)
            acc[q * 2 + mi][nf] =
              __builtin_amdgcn_mfma_f32_16x16x32_bf16(af[mi][ks], bfr[nf][ks], acc[q * 2 + mi][nf], 0, 0, 0);
      __builtin_amdgcn_s_setprio(0);
      asm volatile("" ::: "memory");
      __builtin_amdgcn_s_barrier();
      asm volatile("" ::: "memory");
    }
  }

  if (EPI == 0){
    u16* out = (u16*)outp;
#pragma unroll
    for (int nf = 0; nf < 4; ++nf){
      int n = n0 + wc * 64 + nf * 16 + c;
      float bv = bias[n];
#pragma unroll
      for (int mf = 0; mf < 8; ++mf){
        int row0 = m0 + wr * 128 + mf * 16 + 4 * g;
#pragma unroll
        for (int r = 0; r < 4; ++r)
          out[(size_t)(row0 + r) * ldout + n] = f2b(fmaxf(acc[mf][nf][r] + bv, 0.f));
      }
    }
  } else {
    float* po = (float*)outp + (size_t)blockIdx.z * (4096ull * 1024ull);
#pragma unroll
    for (int nf = 0; nf < 4; ++nf){
      int n = n0 + wc * 64 + nf * 16 + c;
#pragma unroll
      for (int mf = 0; mf < 8; ++mf){
        int row0 = m0 + wr * 128 + mf * 16 + 4 * g;
#pragma unroll
        for (int r = 0; r < 4; ++r)
          po[(size_t)(row0 + r) * 1024 + n] = acc[mf][nf][r];
      }
    }
  }
}

// ---------- FF2 combiner: sum 4 partials + bias + residual -> bf16 ----------
__global__ __launch_bounds__(256) void combine4(const float* __restrict__ pp,
                                                const float* __restrict__ bias,
                                                const u16* __restrict__ res,
                                                u16* __restrict__ out){
  const size_t i4 = ((size_t)blockIdx.x * 256 + threadIdx.x) * 4;
  const int col = (int)(i4 & 1023);
  f32x4 s = *(const f32x4*)(pp + i4);
#pragma unroll
  for (int z = 1; z < 4; z++){
    f32x4 p = *(const f32x4*)(pp + (size_t)z * (4096ull * 1024ull) + i4);
    s[0] += p[0]; s[1] += p[1]; s[2] += p[2]; s[3] += p[3];
  }
  bf16x4 rv = *(const bf16x4*)(res + i4);
  bf16x4 o;
#pragma unroll
  for (int j = 0; j < 4; j++)
    o[j] = (short)f2b(s[j] + bias[col + j] + b2f((u16)rv[j]));
  *(bf16x4*)(out + i4) = o;
}

// ---------- fused masked attention (flash-style, swapped-operand) ----------
__global__ __launch_bounds__(256, 4) void attn_k(const u16* __restrict__ qb,
                                                 const u16* __restrict__ kb,
                                                 const u16* __restrict__ vt,
                                                 const float* __restrict__ mask,
                                                 u16* __restrict__ ob){
  __shared__ u16 sK[2][4096];   // [key][dh], row stride 128B, XOR-swizzled
  __shared__ u16 sV[2][4096];   // [dh][key], row stride 128B, XOR-swizzled

  const int t = threadIdx.x, w = t >> 6, l = t & 63;
  const int c = l & 15, g = l >> 4;
  const int q0 = blockIdx.x * 64, h = blockIdx.y, b = blockIdx.z;
  const int qrow = q0 + w * 16 + c;
  const size_t qoff = ((size_t)(b * 1024 + qrow)) * 1024 + h * 64;
  const bf16x8 bq0 = *(const bf16x8*)(qb + qoff + g * 8);
  const bf16x8 bq1 = *(const bf16x8*)(qb + qoff + 32 + g * 8);
  const u16* kbase = kb + ((size_t)b * 1024) * 1024 + h * 64;
  const u16* vbase = vt + ((size_t)b << 20) + (size_t)(h * 64) * 1024;
  const float* mbase = mask + ((size_t)(h * 4 + b) * 1024 + qrow) * 1024;

  const int lr3 = l >> 3, lc3 = l & 7;
  const int ch0 = w * 2;

  auto stage = [&](int buf, int kv){
#pragma unroll
    for (int i = 0; i < 2; i++){
      int ch  = ch0 + i;
      int row = ch * 8 + lr3;
      int L   = (lc3 * 16) ^ ((row & 7) << 4);
      gld_lds16(kbase + (size_t)(kv + row) * 1024 + (L >> 1), &sK[buf][ch * 512]);
      gld_lds16(vbase + (size_t)row * 1024 + kv + (L >> 1),   &sV[buf][ch * 512]);
    }
  };

  float m = -INFINITY, lsum = 0.f;
  f32x4 acc[4];
#pragma unroll
  for (int f = 0; f < 4; f++) acc[f] = (f32x4){0.f, 0.f, 0.f, 0.f};

  stage(0, 0);
  f32x4 mc[4];
#pragma unroll
  for (int nf = 0; nf < 4; nf++) mc[nf] = *(const f32x4*)(mbase + nf * 16 + g * 4);
  __syncthreads();

  const int sw = (c & 7) << 4;
  int cur = 0;
  for (int it = 0; it < 16; ++it){
    const int kv = it * 64;
    f32x4 mn[4];
    if (it < 15){
      stage(cur ^ 1, kv + 64);
#pragma unroll
      for (int nf = 0; nf < 4; nf++)
        mn[nf] = *(const f32x4*)(mbase + kv + 64 + nf * 16 + g * 4);
    }

    const char* kt = (const char*)sK[cur];
    f32x4 st[4];
#pragma unroll
    for (int nf = 0; nf < 4; nf++){
      const char* kr = kt + (nf * 16 + c) * 128;
      bf16x8 ak0 = *(const bf16x8*)(kr + ((g * 16) ^ sw));
      bf16x8 ak1 = *(const bf16x8*)(kr + ((64 + g * 16) ^ sw));
      f32x4 z = (f32x4){0.f, 0.f, 0.f, 0.f};
      z = __builtin_amdgcn_mfma_f32_16x16x32_bf16(ak0, bq0, z, 0, 0, 0);
      z = __builtin_amdgcn_mfma_f32_16x16x32_bf16(ak1, bq1, z, 0, 0, 0);
      st[nf] = z;
    }

    float tmax = -INFINITY;
#pragma unroll
    for (int nf = 0; nf < 4; nf++)
#pragma unroll
      for (int r = 0; r < 4; r++){
        float v = st[nf][r] * 0.03125f + mc[nf][r];
        st[nf][r] = v; tmax = fmaxf(tmax, v);
      }
    tmax = fmaxf(tmax, __shfl_xor(tmax, 16));
    tmax = fmaxf(tmax, __shfl_xor(tmax, 32));
    float mnew  = fmaxf(m, tmax);
    float alpha = __expf(m - mnew);
    float rs = 0.f;
    bf16x4 pb[4];
#pragma unroll
    for (int nf = 0; nf < 4; nf++)
#pragma unroll
      for (int r = 0; r < 4; r++){
        float p = __expf(st[nf][r] - mnew);
        rs += p;
        pb[nf][r] = (short)f2b(p);
      }
    rs += __shfl_xor(rs, 16); rs += __shfl_xor(rs, 32);
    lsum = lsum * alpha + rs; m = mnew;
#pragma unroll
    for (int f = 0; f < 4; f++){
      acc[f][0] *= alpha; acc[f][1] *= alpha; acc[f][2] *= alpha; acc[f][3] *= alpha;
    }

    const char* vtc = (const char*)sV[cur];
#pragma unroll
    for (int f = 0; f < 4; f++){
      const char* vr = vtc + (f * 16 + c) * 128;
#pragma unroll
      for (int nf = 0; nf < 4; nf++){
        bf16x4 av = *(const bf16x4*)(vr + ((nf * 32 + g * 8) ^ sw));
        acc[f] = __builtin_amdgcn_mfma_f32_16x16x16bf16_1k(av, pb[nf], acc[f], 0, 0, 0);
      }
    }

    __syncthreads();
    cur ^= 1;
    if (it < 15){
#pragma unroll
      for (int nf = 0; nf < 4; nf++) mc[nf] = mn[nf];
    }
  }

  const float inv = 1.f / lsum;
#pragma unroll
  for (int f = 0; f < 4; f++){
    bf16x4 pk;
#pragma unroll
    for (int r = 0; r < 4; r++) pk[r] = (short)f2b(acc[f][r] * inv);
    *(bf16x4*)(ob + qoff + f * 16 + g * 4) = pk;
  }
}

// ---------- LayerNorm over 1024 cols ----------
template<int F32OUT>
__global__ __launch_bounds__(256) void ln_k(const u16* __restrict__ x,
                                            const float* __restrict__ gw,
                                            const float* __restrict__ bw,
                                            void* __restrict__ outp){
  const int row = blockIdx.x, t = threadIdx.x, w = t >> 6, l = t & 63;
  const u16* xr = x + (size_t)row * 1024;
  bf16x4 xv = *(const bf16x4*)(xr + t * 4);
  float xs[4], s = 0.f, sq = 0.f;
#pragma unroll
  for (int j = 0; j < 4; j++){ xs[j] = b2f((u16)xv[j]); s += xs[j]; sq += xs[j] * xs[j]; }
#pragma unroll
  for (int o = 32; o; o >>= 1){ s += __shfl_xor(s, o); sq += __shfl_xor(sq, o); }
  __shared__ float rs[4], rq[4];
  if (l == 0){ rs[w] = s; rq[w] = sq; }
  __syncthreads();
  s  = rs[0] + rs[1] + rs[2] + rs[3];
  sq = rq[0] + rq[1] + rq[2] + rq[3];
  const float mu   = s * (1.f / 1024.f);
  const float var  = sq * (1.f / 1024.f) - mu * mu;
  const float rstd = rsqrtf(var + 1e-5f);
  if (F32OUT){
    float4 o4;
    o4.x = (xs[0]-mu)*rstd*gw[t*4+0] + bw[t*4+0];
    o4.y = (xs[1]-mu)*rstd*gw[t*4+1] + bw[t*4+1];
    o4.z = (xs[2]-mu)*rstd*gw[t*4+2] + bw[t*4+2];
    o4.w = (xs[3]-mu)*rstd*gw[t*4+3] + bw[t*4+3];
    *((float4*)outp + (size_t)row * 256 + t) = o4;
  } else {
    bf16x4 o;
#pragma unroll
    for (int j = 0; j < 4; j++) o[j] = (short)f2b((xs[j]-mu)*rstd*gw[t*4+j] + bw[t*4+j]);
    *((bf16x4*)outp + (size_t)row * 256 + t) = o;
  }
}

// ---------- launch ----------
extern "C" void kernel_launch(void* const* d_in, const int* in_sizes, int n_in,
                              void* d_out, int out_size, void* d_ws, size_t ws_size,
                              hipStream_t stream){
  const float* Q    = (const float*)d_in[0];
  const float* K    = (const float*)d_in[1];
  const float* mask = (const float*)d_in[2];
  const float* Wq   = (const float*)d_in[4];  const float* bq  = (const float*)d_in[5];
  const float* Wk   = (const float*)d_in[6];  const float* bk  = (const float*)d_in[7];
  const float* Wv   = (const float*)d_in[8];  const float* bv  = (const float*)d_in[9];
  const float* Wo0  = (const float*)d_in[10]; const float* bo0 = (const float*)d_in[11];
  const float* Wo   = (const float*)d_in[12]; const float* bo  = (const float*)d_in[13];
  const float* Wo2  = (const float*)d_in[14]; const float* bo2 = (const float*)d_in[15];
  const float* g0   = (const float*)d_in[16]; const float* be0 = (const float*)d_in[17];
  const float* g1   = (const float*)d_in[18]; const float* be1 = (const float*)d_in[19];

  uint8_t* W = (uint8_t*)d_ws;
  const size_t MB = 1024ull * 1024ull;
  u16* Wq_t  = (u16*)(W + 0);
  u16* Wk_t  = (u16*)(W + 2  * MB);
  u16* Wv_t  = (u16*)(W + 4  * MB);
  u16* Wo0_t = (u16*)(W + 6  * MB);
  u16* Wo_t  = (u16*)(W + 8  * MB);   // [4096][1024]
  u16* Wo2_t = (u16*)(W + 16 * MB);   // [1024][4096]
  u16* Qb    = (u16*)(W + 24 * MB);
  u16* Kb    = (u16*)(W + 32 * MB);
  u16* qb    = (u16*)(W + 40 * MB);
  u16* kbf   = (u16*)(W + 48 * MB);
  u16* vtb   = (u16*)(W + 56 * MB);
  u16* ob    = (u16*)(W + 24 * MB);   // reuse Qb
  u16* x0b   = (u16*)(W + 32 * MB);   // reuse Kb
  u16* x1b   = (u16*)(W + 64 * MB);
  u16* hb    = (u16*)(W + 32 * MB);   // [4096][4096] bf16, spans dead x0b/qb/kbf/vtb
  u16* zb    = (u16*)(W + 24 * MB);   // reuse ob
  float* pp  = (float*)(W + 72 * MB); // 4 x 16MB f32 FF2 partials

  // input conversions
  cvt_qk<<<8192, 256, 0, stream>>>(Q, K, Qb, Kb);
  transpose_cvt4<<<dim3(16, 16, 4), 256, 0, stream>>>(Wq, Wq_t, Wk, Wk_t, Wv, Wv_t, Wo0, Wo0_t);
  transpose_cvt_k<<<dim3(64, 16), 256, 0, stream>>>(Wo,  Wo_t,  1024, 4096);
  transpose_cvt_k<<<dim3(16, 64), 256, 0, stream>>>(Wo2, Wo2_t, 4096, 1024);

  // fused QKV projections
  gemm_qkv<<<dim3(8, 32, 3), 256, 0, stream>>>(Qb, Kb, Wq_t, Wk_t, Wv_t,
                                               bq, bk, bv, qb, kbf, vtb);

  // attention
  attn_k<<<dim3(16, 16, 4), 256, 0, stream>>>(qb, kbf, vtb, mask, ob);

  // output proj + residual, LN0
  gemm_res<<<dim3(8, 32), 256, 0, stream>>>(ob, Wo0_t, bo0, qb, x0b, 1024, 1024);
  ln_k<0><<<4096, 256, 0, stream>>>(x0b, g0, be0, x1b);

  // FFN: FF1 (8-phase 256², relu) -> FF2 (8-phase 256², split-K=4) -> combine, LN1
  gemm8p<0><<<dim3(16, 16), 512, 0, stream>>>(x1b, Wo_t, bo, hb, 1024, 1024, 4096, 0, 16);
  gemm8p<1><<<dim3(4, 16, 4), 512, 0, stream>>>(hb, Wo2_t, nullptr, pp, 4096, 4096, 1024, 1024, 16);
  combine4<<<4096, 256, 0, stream>>>(pp, bo2, x1b, zb);
  ln_k<1><<<4096, 256, 0, stream>>>(zb, g1, be1, d_out);
}

// Round 5
// 306.560 us; speedup vs baseline: 1.6884x; 1.0615x over previous
//
#include <hip/hip_runtime.h>
#include <hip/hip_bf16.h>

typedef unsigned short u16;
typedef __attribute__((ext_vector_type(4))) short bf16x4;
typedef __attribute__((ext_vector_type(8))) short bf16x8;
typedef __attribute__((ext_vector_type(4))) float f32x4;

// ---------- helpers ----------
static __device__ __forceinline__ u16 f2b(float f){
  union { float f; unsigned u; } v; v.f = f;
  unsigned r = v.u + 0x7fffu + ((v.u >> 16) & 1u);   // RNE
  return (u16)(r >> 16);
}
static __device__ __forceinline__ float b2f(u16 h){
  union { unsigned u; float f; } v; v.u = ((unsigned)h) << 16; return v.f;
}
static __device__ __forceinline__ void gld_lds16(const void* g, void* l){
  __builtin_amdgcn_global_load_lds((const __attribute__((address_space(1))) void*)g,
                                   (__attribute__((address_space(3))) void*)l, 16, 0, 0);
}

// ---------- f32 -> bf16 convert: Q rows + K rows (compacted) in one grid ----------
__global__ __launch_bounds__(256) void cvt_qk(const float* __restrict__ Q,
                                              const float* __restrict__ K,
                                              u16* __restrict__ Qb,
                                              u16* __restrict__ Kb){
  const int row = blockIdx.x, t = threadIdx.x;
  const float* src; u16* dst;
  if (row < 4096){
    src = Q + (size_t)row * 1024; dst = Qb + (size_t)row * 1024;
  } else {
    int r = row - 4096;
    size_t ir = (size_t)r + (size_t)(r >> 10) * 512;    // skip rows 1024..1535 per batch
    src = K + ir * 1024; dst = Kb + (size_t)r * 1024;
  }
  const float4 v = *(const float4*)(src + t * 4);
  bf16x4 o;
  o[0] = (short)f2b(v.x); o[1] = (short)f2b(v.y);
  o[2] = (short)f2b(v.z); o[3] = (short)f2b(v.w);
  *(bf16x4*)(dst + t * 4) = o;
}

// ---------- weight transpose + convert: in [K][N] f32 -> out [N][K] bf16 ----------
static __device__ __forceinline__ void transpose_body(const float* __restrict__ in,
                                                      u16* __restrict__ out, int K, int N){
  __shared__ float tile[64][65];
  const int k0 = blockIdx.y * 64, n0 = blockIdx.x * 64;
  const int t = threadIdx.x, tr = t >> 4, tc = t & 15;
#pragma unroll
  for (int i = 0; i < 4; i++){
    int r = tr + i * 16;
    float4 v = *(const float4*)(in + (size_t)(k0 + r) * N + n0 + tc * 4);
    tile[r][tc*4+0] = v.x; tile[r][tc*4+1] = v.y; tile[r][tc*4+2] = v.z; tile[r][tc*4+3] = v.w;
  }
  __syncthreads();
#pragma unroll
  for (int i = 0; i < 4; i++){
    int nr = tr + i * 16;
    bf16x4 pk;
#pragma unroll
    for (int j = 0; j < 4; j++) pk[j] = (short)f2b(tile[tc*4+j][nr]);
    *(bf16x4*)(out + (size_t)(n0 + nr) * K + k0 + tc * 4) = pk;
  }
}

__global__ __launch_bounds__(256) void transpose_cvt_k(const float* __restrict__ in,
                                                       u16* __restrict__ out, int K, int N){
  transpose_body(in, out, K, N);
}

__global__ __launch_bounds__(256) void transpose_cvt4(const float* __restrict__ i0, u16* __restrict__ o0,
                                                      const float* __restrict__ i1, u16* __restrict__ o1,
                                                      const float* __restrict__ i2, u16* __restrict__ o2,
                                                      const float* __restrict__ i3, u16* __restrict__ o3){
  const float* in; u16* out;
  switch (blockIdx.z){
    case 0: in = i0; out = o0; break;
    case 1: in = i1; out = o1; break;
    case 2: in = i2; out = o2; break;
    default: in = i3; out = o3; break;
  }
  transpose_body(in, out, 1024, 1024);
}

// ---------- m97-structure GEMM main loop (128x128 tile, BK=64) ----------
static __device__ __forceinline__ void gemm_mainloop(const u16* __restrict__ A,
                                                     const u16* __restrict__ Bt,
                                                     int lda, int ldb, int kbeg, int kend,
                                                     int m0, int n0,
                                                     u16* lA, u16* lB, f32x4 acc[4][4]){
  const int t = threadIdx.x, w = t >> 6, l = t & 63;
  const int wr = w >> 1, wc = w & 1;
  const int lrow = l >> 3, lc8 = l & 7;
  const int c = l & 15, g = l >> 4;
  for (int k0 = kbeg; k0 < kend; k0 += 64){
#pragma unroll
    for (int i = 0; i < 4; i++){
      int ch = w * 4 + i;
      int r  = ch * 8 + lrow;
      gld_lds16(A  + (size_t)(m0 + r) * lda + k0 + lc8 * 8, lA + ch * 512);
      gld_lds16(Bt + (size_t)(n0 + r) * ldb + k0 + lc8 * 8, lB + ch * 512);
    }
    __syncthreads();
#pragma unroll
    for (int ks = 0; ks < 2; ks++){
      bf16x8 af[4], bfr[4];
#pragma unroll
      for (int mi = 0; mi < 4; mi++){
        int row = wr * 64 + mi * 16 + c;
        af[mi] = *(const bf16x8*)((const char*)lA + row * 128 + ks * 64 + g * 16);
      }
#pragma unroll
      for (int ni = 0; ni < 4; ni++){
        int row = wc * 64 + ni * 16 + c;
        bfr[ni] = *(const bf16x8*)((const char*)lB + row * 128 + ks * 64 + g * 16);
      }
#pragma unroll
      for (int mi = 0; mi < 4; mi++)
#pragma unroll
        for (int ni = 0; ni < 4; ni++)
          acc[mi][ni] = __builtin_amdgcn_mfma_f32_16x16x32_bf16(af[mi], bfr[ni], acc[mi][ni], 0, 0, 0);
    }
    __syncthreads();
  }
}

// ---------- Wo0 split-K=2 (m97 loop, f32 partials) ----------
__global__ __launch_bounds__(256) void gemm_sk2(const u16* __restrict__ A,
                                                const u16* __restrict__ Bt,
                                                float* __restrict__ pout){
  __shared__ u16 lA[128 * 64];
  __shared__ u16 lB[128 * 64];
  const int t = threadIdx.x, w = t >> 6, l = t & 63;
  const int m0 = blockIdx.y * 128, n0 = blockIdx.x * 128;
  const int wr = w >> 1, wc = w & 1;
  const int c = l & 15, g = l >> 4;
  const int kbeg = blockIdx.z * 512;

  f32x4 acc[4][4];
#pragma unroll
  for (int i = 0; i < 4; i++)
#pragma unroll
    for (int j = 0; j < 4; j++) acc[i][j] = (f32x4){0.f, 0.f, 0.f, 0.f};

  gemm_mainloop(A, Bt, 1024, 1024, kbeg, kbeg + 512, m0, n0, lA, lB, acc);

  float* po = pout + ((size_t)blockIdx.z << 22);
#pragma unroll
  for (int ni = 0; ni < 4; ni++){
    int n = n0 + wc * 64 + ni * 16 + c;
#pragma unroll
    for (int mi = 0; mi < 4; mi++){
      int row0 = m0 + wr * 64 + mi * 16 + 4 * g;
#pragma unroll
      for (int r = 0; r < 4; r++)
        po[(size_t)(row0 + r) * 1024 + n] = acc[mi][ni][r];
    }
  }
}

// ---------- 256x256 8-phase main loop (T2+T3+T4+T5), BK=64, 8 waves ----------
static __device__ __forceinline__ void loop8p(const u16* __restrict__ A,
                                              const u16* __restrict__ Bt,
                                              int lda, int ldb, int kbeg, int NT,
                                              int m0, int n0,
                                              u16 (*sA)[2][8192], u16 (*sB)[2][8192],
                                              f32x4 acc[8][4]){
  const int t = threadIdx.x, w = t >> 6, l = t & 63;
  const int wr = w >> 2, wc = w & 3;
  const int c = l & 15, g = l >> 4;
  const int sr = t >> 3, scb = (t & 7) << 4;

  auto stA = [&](int d, int h, int T){
#pragma unroll
    for (int i = 0; i < 2; i++){
      int row = i * 64 + sr;
      int Lb  = scb ^ ((row & 7) << 4);
      gld_lds16(A + (size_t)(m0 + h * 128 + row) * lda + kbeg + T * 64 + (Lb >> 1),
                (char*)&sA[d][h][0] + i * 8192 + t * 16);
    }
  };
  auto stB = [&](int d, int h, int T){
#pragma unroll
    for (int i = 0; i < 2; i++){
      int row = i * 64 + sr;
      int Lb  = scb ^ ((row & 7) << 4);
      gld_lds16(Bt + (size_t)(n0 + h * 128 + row) * ldb + kbeg + T * 64 + (Lb >> 1),
                (char*)&sB[d][h][0] + i * 8192 + t * 16);
    }
  };

  // prologue: B0(0),B1(0),A0(0),A1(0),B0(1),B1(1)
  stB(0, 0, 0); stB(0, 1, 0); stA(0, 0, 0); stA(0, 1, 0);
  stB(1, 0, 1); stB(1, 1, 1);

  bf16x8 bfr[4][2];
  for (int T = 0; T < NT; ++T){
    const int d = T & 1;
    const char* pa = (const char*)&sA[d][wr][0];
    const char* pb = (const char*)&sB[d][wc >> 1][0];
#pragma unroll
    for (int q = 0; q < 4; ++q){
      if (q == 0){
        if (T + 1 < NT) asm volatile("s_waitcnt vmcnt(4)" ::: "memory");
        else            asm volatile("s_waitcnt vmcnt(0)" ::: "memory");
        asm volatile("" ::: "memory");
        __builtin_amdgcn_s_barrier();
        asm volatile("" ::: "memory");
#pragma unroll
        for (int nf = 0; nf < 4; ++nf){
          int lr = (wc & 1) * 64 + nf * 16 + c;
#pragma unroll
          for (int ks = 0; ks < 2; ++ks)
            bfr[nf][ks] = *(const bf16x8*)(pb + lr * 128 + ((ks * 64 + g * 16) ^ ((lr & 7) << 4)));
        }
      }
      bf16x8 af[2][2];
#pragma unroll
      for (int mi = 0; mi < 2; ++mi){
        int lr = (q * 2 + mi) * 16 + c;
#pragma unroll
        for (int ks = 0; ks < 2; ++ks)
          af[mi][ks] = *(const bf16x8*)(pa + lr * 128 + ((ks * 64 + g * 16) ^ ((lr & 7) << 4)));
      }
      if      (q == 0){ if (T + 1 < NT) stA(d ^ 1, 0, T + 1); }
      else if (q == 1){ if (T + 1 < NT) stA(d ^ 1, 1, T + 1); }
      else if (q == 2){ if (T + 2 < NT) stB(d, 0, T + 2); }
      else            { if (T + 2 < NT) stB(d, 1, T + 2); }
      __builtin_amdgcn_s_setprio(1);
#pragma unroll
      for (int mi = 0; mi < 2; ++mi)
#pragma unroll
        for (int nf = 0; nf < 4; ++nf)
#pragma unroll
          for (int ks = 0; ks < 2; ++ks)
            acc[q * 2 + mi][nf] =
              __builtin_amdgcn_mfma_f32_16x16x32_bf16(af[mi][ks], bfr[nf][ks], acc[q * 2 + mi][nf], 0, 0, 0);
      __builtin_amdgcn_s_setprio(0);
      asm volatile("" ::: "memory");
      __builtin_amdgcn_s_barrier();
      asm volatile("" ::: "memory");
    }
  }
}

// ---------- 8-phase GEMM: EPI 0 = bias+relu -> bf16 ; EPI 1 = f32 split-K partial ----------
template<int EPI>
__global__ __launch_bounds__(512, 2) void gemm8p(const u16* __restrict__ A,
                                                 const u16* __restrict__ Bt,
                                                 const float* __restrict__ bias,
                                                 void* __restrict__ outp,
                                                 int lda, int ldb, int ldout,
                                                 int ksz, int NT){
  __shared__ u16 sA[2][2][8192];
  __shared__ u16 sB[2][2][8192];
  const int t = threadIdx.x, w = t >> 6, l = t & 63;
  const int wr = w >> 2, wc = w & 3;
  const int c = l & 15, g = l >> 4;
  const int m0 = blockIdx.y * 256, n0 = blockIdx.x * 256;

  f32x4 acc[8][4];
#pragma unroll
  for (int i = 0; i < 8; i++)
#pragma unroll
    for (int j = 0; j < 4; j++) acc[i][j] = (f32x4){0.f, 0.f, 0.f, 0.f};

  loop8p(A, Bt, lda, ldb, blockIdx.z * ksz, NT, m0, n0, sA, sB, acc);

  if (EPI == 0){
    u16* out = (u16*)outp;
#pragma unroll
    for (int nf = 0; nf < 4; ++nf){
      int n = n0 + wc * 64 + nf * 16 + c;
      float bv = bias[n];
#pragma unroll
      for (int mf = 0; mf < 8; ++mf){
        int row0 = m0 + wr * 128 + mf * 16 + 4 * g;
#pragma unroll
        for (int r = 0; r < 4; ++r)
          out[(size_t)(row0 + r) * ldout + n] = f2b(fmaxf(acc[mf][nf][r] + bv, 0.f));
      }
    }
  } else {
    float* po = (float*)outp + ((size_t)blockIdx.z << 22);
#pragma unroll
    for (int nf = 0; nf < 4; ++nf){
      int n = n0 + wc * 64 + nf * 16 + c;
#pragma unroll
      for (int mf = 0; mf < 8; ++mf){
        int row0 = m0 + wr * 128 + mf * 16 + 4 * g;
#pragma unroll
        for (int r = 0; r < 4; ++r)
          po[(size_t)(row0 + r) * 1024 + n] = acc[mf][nf][r];
      }
    }
  }
}

// ---------- fused QKV (8-phase 256²): bx>>2 selects Q/K/V; V writes transposed ----------
__global__ __launch_bounds__(512, 2) void gemm8p_qkv(const u16* __restrict__ Qb,
                                                     const u16* __restrict__ Kb,
                                                     const u16* __restrict__ Wq_t,
                                                     const u16* __restrict__ Wk_t,
                                                     const u16* __restrict__ Wv_t,
                                                     const float* __restrict__ bq,
                                                     const float* __restrict__ bk,
                                                     const float* __restrict__ bv,
                                                     u16* __restrict__ qb,
                                                     u16* __restrict__ kbf,
                                                     u16* __restrict__ vtb){
  __shared__ u16 sA[2][2][8192];
  __shared__ u16 sB[2][2][8192];
  const int bx = blockIdx.x, sel = bx >> 2;
  const u16* A    = sel ? Kb : Qb;
  const u16* Bt   = (sel == 0) ? Wq_t : (sel == 1) ? Wk_t : Wv_t;
  const float* bi = (sel == 0) ? bq   : (sel == 1) ? bk   : bv;
  const int t = threadIdx.x, w = t >> 6, l = t & 63;
  const int wr = w >> 2, wc = w & 3;
  const int c = l & 15, g = l >> 4;
  const int m0 = blockIdx.y * 256, n0 = (bx & 3) * 256;

  f32x4 acc[8][4];
#pragma unroll
  for (int i = 0; i < 8; i++)
#pragma unroll
    for (int j = 0; j < 4; j++) acc[i][j] = (f32x4){0.f, 0.f, 0.f, 0.f};

  loop8p(A, Bt, 1024, 1024, 0, 16, m0, n0, sA, sB, acc);

#pragma unroll
  for (int nf = 0; nf < 4; ++nf){
    int n = n0 + wc * 64 + nf * 16 + c;
    float bv_ = bi[n];
#pragma unroll
    for (int mf = 0; mf < 8; ++mf){
      int row0 = m0 + wr * 128 + mf * 16 + 4 * g;
      if (sel == 2){
        bf16x4 pk;
#pragma unroll
        for (int r = 0; r < 4; ++r) pk[r] = (short)f2b(acc[mf][nf][r] + bv_);
        int bb = row0 >> 10, key = row0 & 1023;
        *(bf16x4*)(vtb + ((size_t)bb << 20) + (size_t)n * 1024 + key) = pk;
      } else {
        u16* out = sel ? kbf : qb;
#pragma unroll
        for (int r = 0; r < 4; ++r)
          out[(size_t)(row0 + r) * 1024 + n] = f2b(acc[mf][nf][r] + bv_);
      }
    }
  }
}

// ---------- combine 2 partials + bias + residual, then LayerNorm -> bf16 ----------
__global__ __launch_bounds__(256) void comb_ln0(const float* __restrict__ pp,
                                                const float* __restrict__ bias,
                                                const u16* __restrict__ res,
                                                const float* __restrict__ gw,
                                                const float* __restrict__ bw,
                                                u16* __restrict__ out){
  const int row = blockIdx.x, t = threadIdx.x, w = t >> 6, l = t & 63;
  const size_t i4 = (size_t)row * 1024 + t * 4;
  f32x4 a = *(const f32x4*)(pp + i4);
  f32x4 b = *(const f32x4*)(pp + (1ull << 22) + i4);
  bf16x4 rv = *(const bf16x4*)(res + i4);
  float xs[4], s = 0.f, sq = 0.f;
#pragma unroll
  for (int j = 0; j < 4; j++){
    xs[j] = a[j] + b[j] + bias[t * 4 + j] + b2f((u16)rv[j]);
    s += xs[j]; sq += xs[j] * xs[j];
  }
#pragma unroll
  for (int o = 32; o; o >>= 1){ s += __shfl_xor(s, o); sq += __shfl_xor(sq, o); }
  __shared__ float rs[4], rq[4];
  if (l == 0){ rs[w] = s; rq[w] = sq; }
  __syncthreads();
  s  = rs[0] + rs[1] + rs[2] + rs[3];
  sq = rq[0] + rq[1] + rq[2] + rq[3];
  const float mu   = s * (1.f / 1024.f);
  const float var  = sq * (1.f / 1024.f) - mu * mu;
  const float rstd = rsqrtf(var + 1e-5f);
  bf16x4 o;
#pragma unroll
  for (int j = 0; j < 4; j++) o[j] = (short)f2b((xs[j]-mu)*rstd*gw[t*4+j] + bw[t*4+j]);
  *(bf16x4*)(out + i4) = o;
}

// ---------- combine 4 partials + bias + residual, then LayerNorm -> f32 (d_out) ----------
__global__ __launch_bounds__(256) void comb_ln1(const float* __restrict__ pp,
                                                const float* __restrict__ bias,
                                                const u16* __restrict__ res,
                                                const float* __restrict__ gw,
                                                const float* __restrict__ bw,
                                                float* __restrict__ out){
  const int row = blockIdx.x, t = threadIdx.x, w = t >> 6, l = t & 63;
  const size_t i4 = (size_t)row * 1024 + t * 4;
  f32x4 a = *(const f32x4*)(pp + i4);
#pragma unroll
  for (int z = 1; z < 4; z++){
    f32x4 p = *(const f32x4*)(pp + ((size_t)z << 22) + i4);
    a[0] += p[0]; a[1] += p[1]; a[2] += p[2]; a[3] += p[3];
  }
  bf16x4 rv = *(const bf16x4*)(res + i4);
  float xs[4], s = 0.f, sq = 0.f;
#pragma unroll
  for (int j = 0; j < 4; j++){
    xs[j] = a[j] + bias[t * 4 + j] + b2f((u16)rv[j]);
    s += xs[j]; sq += xs[j] * xs[j];
  }
#pragma unroll
  for (int o = 32; o; o >>= 1){ s += __shfl_xor(s, o); sq += __shfl_xor(sq, o); }
  __shared__ float rs[4], rq[4];
  if (l == 0){ rs[w] = s; rq[w] = sq; }
  __syncthreads();
  s  = rs[0] + rs[1] + rs[2] + rs[3];
  sq = rq[0] + rq[1] + rq[2] + rq[3];
  const float mu   = s * (1.f / 1024.f);
  const float var  = sq * (1.f / 1024.f) - mu * mu;
  const float rstd = rsqrtf(var + 1e-5f);
  float4 o4;
  o4.x = (xs[0]-mu)*rstd*gw[t*4+0] + bw[t*4+0];
  o4.y = (xs[1]-mu)*rstd*gw[t*4+1] + bw[t*4+1];
  o4.z = (xs[2]-mu)*rstd*gw[t*4+2] + bw[t*4+2];
  o4.w = (xs[3]-mu)*rstd*gw[t*4+3] + bw[t*4+3];
  *((float4*)out + (size_t)row * 256 + t) = o4;
}

// ---------- fused masked attention: counted-vmcnt 2-phase pipeline ----------
__global__ __launch_bounds__(256, 4) void attn_k(const u16* __restrict__ qb,
                                                 const u16* __restrict__ kb,
                                                 const u16* __restrict__ vt,
                                                 const float* __restrict__ mask,
                                                 u16* __restrict__ ob){
  __shared__ u16 sK[2][4096];   // [key][dh], row stride 128B, XOR-swizzled
  __shared__ u16 sV[2][4096];   // [dh][key], row stride 128B, XOR-swizzled

  const int t = threadIdx.x, w = t >> 6, l = t & 63;
  const int c = l & 15, g = l >> 4;
  const int q0 = blockIdx.x * 64, h = blockIdx.y, b = blockIdx.z;
  const int qrow = q0 + w * 16 + c;
  const size_t qoff = ((size_t)(b * 1024 + qrow)) * 1024 + h * 64;
  const bf16x8 bq0 = *(const bf16x8*)(qb + qoff + g * 8);
  const bf16x8 bq1 = *(const bf16x8*)(qb + qoff + 32 + g * 8);
  const u16* kbase = kb + ((size_t)b * 1024) * 1024 + h * 64;
  const u16* vbase = vt + ((size_t)b << 20) + (size_t)(h * 64) * 1024;
  const float* mbase = mask + ((size_t)(h * 4 + b) * 1024 + qrow) * 1024;

  const int lr3 = l >> 3, lc3 = l & 7;
  const int ch0 = w * 2;

  // 4 global_load_lds per lane, K then V, fixed issue order
  auto stage = [&](int buf, int kv){
#pragma unroll
    for (int i = 0; i < 2; i++){
      int ch  = ch0 + i;
      int row = ch * 8 + lr3;
      int L   = (lc3 * 16) ^ ((row & 7) << 4);
      gld_lds16(kbase + (size_t)(kv + row) * 1024 + (L >> 1), &sK[buf][ch * 512]);
      gld_lds16(vbase + (size_t)row * 1024 + kv + (L >> 1),   &sV[buf][ch * 512]);
    }
  };

  float m = -INFINITY, lsum = 0.f;
  f32x4 acc[4];
#pragma unroll
  for (int f = 0; f < 4; f++) acc[f] = (f32x4){0.f, 0.f, 0.f, 0.f};

  // prologue: stage tile 0 (4 loads), then mask tile 0 (4 loads)
  stage(0, 0);
  asm volatile("" ::: "memory");
  f32x4 mc[4], mn[4];
#pragma unroll
  for (int nf = 0; nf < 4; nf++) mc[nf] = *(const f32x4*)(mbase + nf * 16 + g * 4);

  const int sw = (c & 7) << 4;
  int cur = 0;
  for (int it = 0; it < 16; ++it){
    const int kv = it * 64;
    // counted wait: newest 4 (this tile's mask loads) may stay in flight;
    // everything older — including all waves' stage(cur) — must have landed.
    asm volatile("s_waitcnt vmcnt(4)" ::: "memory");
    __builtin_amdgcn_s_barrier();
    asm volatile("" ::: "memory");

    if (it < 15){
      stage(cur ^ 1, kv + 64);                  // 4 loads into the idle buffer
      asm volatile("" ::: "memory");            // pin issue order: stage before mask
#pragma unroll
      for (int nf = 0; nf < 4; nf++)
        mn[nf] = *(const f32x4*)(mbase + kv + 64 + nf * 16 + g * 4);
    }

    // QK^T from LDS (swizzled reads)
    const char* kt = (const char*)sK[cur];
    f32x4 st[4];
#pragma unroll
    for (int nf = 0; nf < 4; nf++){
      const char* kr = kt + (nf * 16 + c) * 128;
      bf16x8 ak0 = *(const bf16x8*)(kr + ((g * 16) ^ sw));
      bf16x8 ak1 = *(const bf16x8*)(kr + ((64 + g * 16) ^ sw));
      f32x4 z = (f32x4){0.f, 0.f, 0.f, 0.f};
      z = __builtin_amdgcn_mfma_f32_16x16x32_bf16(ak0, bq0, z, 0, 0, 0);
      z = __builtin_amdgcn_mfma_f32_16x16x32_bf16(ak1, bq1, z, 0, 0, 0);
      st[nf] = z;
    }

    // online softmax (lane-local q-rows)
    float tmax = -INFINITY;
#pragma unroll
    for (int nf = 0; nf < 4; nf++)
#pragma unroll
      for (int r = 0; r < 4; r++){
        float v = st[nf][r] * 0.03125f + mc[nf][r];
        st[nf][r] = v; tmax = fmaxf(tmax, v);
      }
    tmax = fmaxf(tmax, __shfl_xor(tmax, 16));
    tmax = fmaxf(tmax, __shfl_xor(tmax, 32));
    float mnew  = fmaxf(m, tmax);
    float alpha = __expf(m - mnew);
    float rsum = 0.f;
    bf16x4 pb[4];
#pragma unroll
    for (int nf = 0; nf < 4; nf++)
#pragma unroll
      for (int r = 0; r < 4; r++){
        float p = __expf(st[nf][r] - mnew);
        rsum += p;
        pb[nf][r] = (short)f2b(p);
      }
    rsum += __shfl_xor(rsum, 16); rsum += __shfl_xor(rsum, 32);
    lsum = lsum * alpha + rsum; m = mnew;
#pragma unroll
    for (int f = 0; f < 4; f++){
      acc[f][0] *= alpha; acc[f][1] *= alpha; acc[f][2] *= alpha; acc[f][3] *= alpha;
    }

    // O^T += V^T @ P^T
    const char* vtc = (const char*)sV[cur];
#pragma unroll
    for (int f = 0; f < 4; f++){
      const char* vr = vtc + (f * 16 + c) * 128;
#pragma unroll
      for (int nf = 0; nf < 4; nf++){
        bf16x4 av = *(const bf16x4*)(vr + ((nf * 32 + g * 8) ^ sw));
        acc[f] = __builtin_amdgcn_mfma_f32_16x16x16bf16_1k(av, pb[nf], acc[f], 0, 0, 0);
      }
    }

    if (it < 15){
#pragma unroll
      for (int nf = 0; nf < 4; nf++) mc[nf] = mn[nf];
    }
    cur ^= 1;
  }

  const float inv = 1.f / lsum;
#pragma unroll
  for (int f = 0; f < 4; f++){
    bf16x4 pk;
#pragma unroll
    for (int r = 0; r < 4; r++) pk[r] = (short)f2b(acc[f][r] * inv);
    *(bf16x4*)(ob + qoff + f * 16 + g * 4) = pk;
  }
}

// ---------- launch ----------
extern "C" void kernel_launch(void* const* d_in, const int* in_sizes, int n_in,
                              void* d_out, int out_size, void* d_ws, size_t ws_size,
                              hipStream_t stream){
  const float* Q    = (const float*)d_in[0];
  const float* K    = (const float*)d_in[1];
  const float* mask = (const float*)d_in[2];
  const float* Wq   = (const float*)d_in[4];  const float* bq  = (const float*)d_in[5];
  const float* Wk   = (const float*)d_in[6];  const float* bk  = (const float*)d_in[7];
  const float* Wv   = (const float*)d_in[8];  const float* bv  = (const float*)d_in[9];
  const float* Wo0  = (const float*)d_in[10]; const float* bo0 = (const float*)d_in[11];
  const float* Wo   = (const float*)d_in[12]; const float* bo  = (const float*)d_in[13];
  const float* Wo2  = (const float*)d_in[14]; const float* bo2 = (const float*)d_in[15];
  const float* g0   = (const float*)d_in[16]; const float* be0 = (const float*)d_in[17];
  const float* g1   = (const float*)d_in[18]; const float* be1 = (const float*)d_in[19];

  uint8_t* W = (uint8_t*)d_ws;
  const size_t MB = 1024ull * 1024ull;
  u16* Wq_t  = (u16*)(W + 0);
  u16* Wk_t  = (u16*)(W + 2  * MB);
  u16* Wv_t  = (u16*)(W + 4  * MB);
  u16* Wo0_t = (u16*)(W + 6  * MB);
  u16* Wo_t  = (u16*)(W + 8  * MB);   // [4096][1024]
  u16* Wo2_t = (u16*)(W + 16 * MB);   // [1024][4096]
  u16* Qb    = (u16*)(W + 24 * MB);
  u16* Kb    = (u16*)(W + 32 * MB);
  u16* qb    = (u16*)(W + 40 * MB);
  u16* kbf   = (u16*)(W + 48 * MB);
  u16* vtb   = (u16*)(W + 56 * MB);
  u16* ob    = (u16*)(W + 24 * MB);   // reuse Qb
  u16* x1b   = (u16*)(W + 64 * MB);
  u16* hb    = (u16*)(W + 32 * MB);   // [4096][4096] bf16, spans dead Kb/qb/kbf/vtb
  float* pp  = (float*)(W + 72 * MB); // up to 4 x 16MB f32 partials (Wo0 uses 2, FF2 uses 4)

  // input conversions
  cvt_qk<<<8192, 256, 0, stream>>>(Q, K, Qb, Kb);
  transpose_cvt4<<<dim3(16, 16, 4), 256, 0, stream>>>(Wq, Wq_t, Wk, Wk_t, Wv, Wv_t, Wo0, Wo0_t);
  transpose_cvt_k<<<dim3(64, 16), 256, 0, stream>>>(Wo,  Wo_t,  1024, 4096);
  transpose_cvt_k<<<dim3(16, 64), 256, 0, stream>>>(Wo2, Wo2_t, 4096, 1024);

  // fused QKV projections (8-phase 256², 192 blocks)
  gemm8p_qkv<<<dim3(12, 16), 512, 0, stream>>>(Qb, Kb, Wq_t, Wk_t, Wv_t,
                                               bq, bk, bv, qb, kbf, vtb);

  // attention
  attn_k<<<dim3(16, 16, 4), 256, 0, stream>>>(qb, kbf, vtb, mask, ob);

  // output proj (split-K=2) + fused combine+residual+LN0 -> x1b
  gemm_sk2<<<dim3(8, 32, 2), 256, 0, stream>>>(ob, Wo0_t, pp);
  comb_ln0<<<4096, 256, 0, stream>>>(pp, bo0, qb, g0, be0, x1b);

  // FFN: FF1 (8-phase, relu) -> FF2 (8-phase, split-K=4) -> fused combine+residual+LN1
  gemm8p<0><<<dim3(16, 16), 512, 0, stream>>>(x1b, Wo_t, bo, hb, 1024, 1024, 4096, 0, 16);
  gemm8p<1><<<dim3(4, 16, 4), 512, 0, stream>>>(hb, Wo2_t, nullptr, pp, 4096, 4096, 1024, 1024, 16);
  comb_ln1<<<4096, 256, 0, stream>>>(pp, bo2, x1b, g1, be1, (float*)d_out);
}

// Round 6
// 302.528 us; speedup vs baseline: 1.7109x; 1.0133x over previous
//
#include <hip/hip_runtime.h>
#include <hip/hip_bf16.h>

typedef unsigned short u16;
typedef __attribute__((ext_vector_type(4))) short bf16x4;
typedef __attribute__((ext_vector_type(8))) short bf16x8;
typedef __attribute__((ext_vector_type(4))) float f32x4;

// ---------- helpers ----------
static __device__ __forceinline__ u16 f2b(float f){
  union { float f; unsigned u; } v; v.f = f;
  unsigned r = v.u + 0x7fffu + ((v.u >> 16) & 1u);   // RNE
  return (u16)(r >> 16);
}
static __device__ __forceinline__ float b2f(u16 h){
  union { unsigned u; float f; } v; v.u = ((unsigned)h) << 16; return v.f;
}
static __device__ __forceinline__ void gld_lds16(const void* g, void* l){
  __builtin_amdgcn_global_load_lds((const __attribute__((address_space(1))) void*)g,
                                   (__attribute__((address_space(3))) void*)l, 16, 0, 0);
}

// ---------- fused prep: Q/K bf16 convert (compacted) + all 6 weight transposes ----------
// blocks 0..8191: row convert; 8192..9215: 4x 1024² transposes; 9216..10239: Wo; 10240..11263: Wo2
__global__ __launch_bounds__(256) void prep(const float* __restrict__ Q,
                                            const float* __restrict__ K,
                                            u16* __restrict__ Qb, u16* __restrict__ Kb,
                                            const float* __restrict__ Wq, u16* __restrict__ Wq_t,
                                            const float* __restrict__ Wk, u16* __restrict__ Wk_t,
                                            const float* __restrict__ Wv, u16* __restrict__ Wv_t,
                                            const float* __restrict__ Wo0, u16* __restrict__ Wo0_t,
                                            const float* __restrict__ Wo, u16* __restrict__ Wo_t,
                                            const float* __restrict__ Wo2, u16* __restrict__ Wo2_t){
  __shared__ float tile[64][65];
  const int id = blockIdx.x, t = threadIdx.x;
  if (id < 8192){
    const float* src; u16* dst;
    if (id < 4096){
      src = Q + (size_t)id * 1024; dst = Qb + (size_t)id * 1024;
    } else {
      int r = id - 4096;
      size_t ir = (size_t)r + (size_t)(r >> 10) * 512;   // skip rows 1024..1535 per batch
      src = K + ir * 1024; dst = Kb + (size_t)r * 1024;
    }
    const float4 v = *(const float4*)(src + t * 4);
    bf16x4 o;
    o[0] = (short)f2b(v.x); o[1] = (short)f2b(v.y);
    o[2] = (short)f2b(v.z); o[3] = (short)f2b(v.w);
    *(bf16x4*)(dst + t * 4) = o;
    return;
  }
  int wid = id - 8192;
  const float* in; u16* out; int Kd, N, bx, by;
  if (wid < 1024){
    int sel = wid >> 8, local = wid & 255;
    bx = local & 15; by = local >> 4; Kd = 1024; N = 1024;
    in  = (sel == 0) ? Wq   : (sel == 1) ? Wk   : (sel == 2) ? Wv   : Wo0;
    out = (sel == 0) ? Wq_t : (sel == 1) ? Wk_t : (sel == 2) ? Wv_t : Wo0_t;
  } else if (wid < 2048){
    int local = wid - 1024; bx = local & 63; by = local >> 6; Kd = 1024; N = 4096;
    in = Wo; out = Wo_t;
  } else {
    int local = wid - 2048; bx = local & 15; by = local >> 4; Kd = 4096; N = 1024;
    in = Wo2; out = Wo2_t;
  }
  const int k0 = by * 64, n0 = bx * 64;
  const int tr = t >> 4, tc = t & 15;
#pragma unroll
  for (int i = 0; i < 4; i++){
    int r = tr + i * 16;
    float4 v = *(const float4*)(in + (size_t)(k0 + r) * N + n0 + tc * 4);
    tile[r][tc*4+0] = v.x; tile[r][tc*4+1] = v.y; tile[r][tc*4+2] = v.z; tile[r][tc*4+3] = v.w;
  }
  __syncthreads();
#pragma unroll
  for (int i = 0; i < 4; i++){
    int nr = tr + i * 16;
    bf16x4 pk;
#pragma unroll
    for (int j = 0; j < 4; j++) pk[j] = (short)f2b(tile[tc*4+j][nr]);
    *(bf16x4*)(out + (size_t)(n0 + nr) * Kd + k0 + tc * 4) = pk;
  }
}

// ---------- m97-structure GEMM main loop (128x128 tile, BK=64) ----------
static __device__ __forceinline__ void gemm_mainloop(const u16* __restrict__ A,
                                                     const u16* __restrict__ Bt,
                                                     int lda, int ldb, int kbeg, int kend,
                                                     int m0, int n0,
                                                     u16* lA, u16* lB, f32x4 acc[4][4]){
  const int t = threadIdx.x, w = t >> 6, l = t & 63;
  const int wr = w >> 1, wc = w & 1;
  const int lrow = l >> 3, lc8 = l & 7;
  const int c = l & 15, g = l >> 4;
  for (int k0 = kbeg; k0 < kend; k0 += 64){
#pragma unroll
    for (int i = 0; i < 4; i++){
      int ch = w * 4 + i;
      int r  = ch * 8 + lrow;
      gld_lds16(A  + (size_t)(m0 + r) * lda + k0 + lc8 * 8, lA + ch * 512);
      gld_lds16(Bt + (size_t)(n0 + r) * ldb + k0 + lc8 * 8, lB + ch * 512);
    }
    __syncthreads();
#pragma unroll
    for (int ks = 0; ks < 2; ks++){
      bf16x8 af[4], bfr[4];
#pragma unroll
      for (int mi = 0; mi < 4; mi++){
        int row = wr * 64 + mi * 16 + c;
        af[mi] = *(const bf16x8*)((const char*)lA + row * 128 + ks * 64 + g * 16);
      }
#pragma unroll
      for (int ni = 0; ni < 4; ni++){
        int row = wc * 64 + ni * 16 + c;
        bfr[ni] = *(const bf16x8*)((const char*)lB + row * 128 + ks * 64 + g * 16);
      }
#pragma unroll
      for (int mi = 0; mi < 4; mi++)
#pragma unroll
        for (int ni = 0; ni < 4; ni++)
          acc[mi][ni] = __builtin_amdgcn_mfma_f32_16x16x32_bf16(af[mi], bfr[ni], acc[mi][ni], 0, 0, 0);
    }
    __syncthreads();
  }
}

// ---------- Wo0 split-K=2 (m97 loop, f32 partials) ----------
__global__ __launch_bounds__(256) void gemm_sk2(const u16* __restrict__ A,
                                                const u16* __restrict__ Bt,
                                                float* __restrict__ pout){
  __shared__ u16 lA[128 * 64];
  __shared__ u16 lB[128 * 64];
  const int t = threadIdx.x, w = t >> 6, l = t & 63;
  const int m0 = blockIdx.y * 128, n0 = blockIdx.x * 128;
  const int wr = w >> 1, wc = w & 1;
  const int c = l & 15, g = l >> 4;
  const int kbeg = blockIdx.z * 512;

  f32x4 acc[4][4];
#pragma unroll
  for (int i = 0; i < 4; i++)
#pragma unroll
    for (int j = 0; j < 4; j++) acc[i][j] = (f32x4){0.f, 0.f, 0.f, 0.f};

  gemm_mainloop(A, Bt, 1024, 1024, kbeg, kbeg + 512, m0, n0, lA, lB, acc);

  float* po = pout + ((size_t)blockIdx.z << 22);
#pragma unroll
  for (int ni = 0; ni < 4; ni++){
    int n = n0 + wc * 64 + ni * 16 + c;
#pragma unroll
    for (int mi = 0; mi < 4; mi++){
      int row0 = m0 + wr * 64 + mi * 16 + 4 * g;
#pragma unroll
      for (int r = 0; r < 4; r++)
        po[(size_t)(row0 + r) * 1024 + n] = acc[mi][ni][r];
    }
  }
}

// ---------- 256x256 8-phase main loop (T2+T3+T4+T5), BK=64, 8 waves ----------
static __device__ __forceinline__ void loop8p(const u16* __restrict__ A,
                                              const u16* __restrict__ Bt,
                                              int lda, int ldb, int kbeg, int NT,
                                              int m0, int n0,
                                              u16 (*sA)[2][8192], u16 (*sB)[2][8192],
                                              f32x4 acc[8][4]){
  const int t = threadIdx.x, w = t >> 6, l = t & 63;
  const int wr = w >> 2, wc = w & 3;
  const int c = l & 15, g = l >> 4;
  const int sr = t >> 3, scb = (t & 7) << 4;

  auto stA = [&](int d, int h, int T){
#pragma unroll
    for (int i = 0; i < 2; i++){
      int row = i * 64 + sr;
      int Lb  = scb ^ ((row & 7) << 4);
      gld_lds16(A + (size_t)(m0 + h * 128 + row) * lda + kbeg + T * 64 + (Lb >> 1),
                (char*)&sA[d][h][0] + i * 8192 + t * 16);
    }
  };
  auto stB = [&](int d, int h, int T){
#pragma unroll
    for (int i = 0; i < 2; i++){
      int row = i * 64 + sr;
      int Lb  = scb ^ ((row & 7) << 4);
      gld_lds16(Bt + (size_t)(n0 + h * 128 + row) * ldb + kbeg + T * 64 + (Lb >> 1),
                (char*)&sB[d][h][0] + i * 8192 + t * 16);
    }
  };

  // prologue: B0(0),B1(0),A0(0),A1(0),B0(1),B1(1)
  stB(0, 0, 0); stB(0, 1, 0); stA(0, 0, 0); stA(0, 1, 0);
  stB(1, 0, 1); stB(1, 1, 1);

  bf16x8 bfr[4][2];
  for (int T = 0; T < NT; ++T){
    const int d = T & 1;
    const char* pa = (const char*)&sA[d][wr][0];
    const char* pb = (const char*)&sB[d][wc >> 1][0];
#pragma unroll
    for (int q = 0; q < 4; ++q){
      if (q == 0){
        if (T + 1 < NT) asm volatile("s_waitcnt vmcnt(4)" ::: "memory");
        else            asm volatile("s_waitcnt vmcnt(0)" ::: "memory");
        asm volatile("" ::: "memory");
        __builtin_amdgcn_s_barrier();
        asm volatile("" ::: "memory");
#pragma unroll
        for (int nf = 0; nf < 4; ++nf){
          int lr = (wc & 1) * 64 + nf * 16 + c;
#pragma unroll
          for (int ks = 0; ks < 2; ++ks)
            bfr[nf][ks] = *(const bf16x8*)(pb + lr * 128 + ((ks * 64 + g * 16) ^ ((lr & 7) << 4)));
        }
      }
      bf16x8 af[2][2];
#pragma unroll
      for (int mi = 0; mi < 2; ++mi){
        int lr = (q * 2 + mi) * 16 + c;
#pragma unroll
        for (int ks = 0; ks < 2; ++ks)
          af[mi][ks] = *(const bf16x8*)(pa + lr * 128 + ((ks * 64 + g * 16) ^ ((lr & 7) << 4)));
      }
      if      (q == 0){ if (T + 1 < NT) stA(d ^ 1, 0, T + 1); }
      else if (q == 1){ if (T + 1 < NT) stA(d ^ 1, 1, T + 1); }
      else if (q == 2){ if (T + 2 < NT) stB(d, 0, T + 2); }
      else            { if (T + 2 < NT) stB(d, 1, T + 2); }
      __builtin_amdgcn_s_setprio(1);
#pragma unroll
      for (int mi = 0; mi < 2; ++mi)
#pragma unroll
        for (int nf = 0; nf < 4; ++nf)
#pragma unroll
          for (int ks = 0; ks < 2; ++ks)
            acc[q * 2 + mi][nf] =
              __builtin_amdgcn_mfma_f32_16x16x32_bf16(af[mi][ks], bfr[nf][ks], acc[q * 2 + mi][nf], 0, 0, 0);
      __builtin_amdgcn_s_setprio(0);
      asm volatile("" ::: "memory");
      __builtin_amdgcn_s_barrier();
      asm volatile("" ::: "memory");
    }
  }
}

// ---------- 8-phase GEMM: EPI 0 = bias+relu -> bf16 ; EPI 1 = f32 split-K partial ----------
template<int EPI>
__global__ __launch_bounds__(512, 2) void gemm8p(const u16* __restrict__ A,
                                                 const u16* __restrict__ Bt,
                                                 const float* __restrict__ bias,
                                                 void* __restrict__ outp,
                                                 int lda, int ldb, int ldout,
                                                 int ksz, int NT){
  __shared__ u16 sA[2][2][8192];
  __shared__ u16 sB[2][2][8192];
  const int t = threadIdx.x, w = t >> 6, l = t & 63;
  const int wr = w >> 2, wc = w & 3;
  const int c = l & 15, g = l >> 4;
  const int m0 = blockIdx.y * 256, n0 = blockIdx.x * 256;

  f32x4 acc[8][4];
#pragma unroll
  for (int i = 0; i < 8; i++)
#pragma unroll
    for (int j = 0; j < 4; j++) acc[i][j] = (f32x4){0.f, 0.f, 0.f, 0.f};

  loop8p(A, Bt, lda, ldb, blockIdx.z * ksz, NT, m0, n0, sA, sB, acc);

  if (EPI == 0){
    u16* out = (u16*)outp;
#pragma unroll
    for (int nf = 0; nf < 4; ++nf){
      int n = n0 + wc * 64 + nf * 16 + c;
      float bv = bias[n];
#pragma unroll
      for (int mf = 0; mf < 8; ++mf){
        int row0 = m0 + wr * 128 + mf * 16 + 4 * g;
#pragma unroll
        for (int r = 0; r < 4; ++r)
          out[(size_t)(row0 + r) * ldout + n] = f2b(fmaxf(acc[mf][nf][r] + bv, 0.f));
      }
    }
  } else {
    float* po = (float*)outp + ((size_t)blockIdx.z << 22);
#pragma unroll
    for (int nf = 0; nf < 4; ++nf){
      int n = n0 + wc * 64 + nf * 16 + c;
#pragma unroll
      for (int mf = 0; mf < 8; ++mf){
        int row0 = m0 + wr * 128 + mf * 16 + 4 * g;
#pragma unroll
        for (int r = 0; r < 4; ++r)
          po[(size_t)(row0 + r) * 1024 + n] = acc[mf][nf][r];
      }
    }
  }
}

// ---------- fused QKV (8-phase 256²): bx>>2 selects Q/K/V; V writes transposed ----------
__global__ __launch_bounds__(512, 2) void gemm8p_qkv(const u16* __restrict__ Qb,
                                                     const u16* __restrict__ Kb,
                                                     const u16* __restrict__ Wq_t,
                                                     const u16* __restrict__ Wk_t,
                                                     const u16* __restrict__ Wv_t,
                                                     const float* __restrict__ bq,
                                                     const float* __restrict__ bk,
                                                     const float* __restrict__ bv,
                                                     u16* __restrict__ qb,
                                                     u16* __restrict__ kbf,
                                                     u16* __restrict__ vtb){
  __shared__ u16 sA[2][2][8192];
  __shared__ u16 sB[2][2][8192];
  const int bx = blockIdx.x, sel = bx >> 2;
  const u16* A    = sel ? Kb : Qb;
  const u16* Bt   = (sel == 0) ? Wq_t : (sel == 1) ? Wk_t : Wv_t;
  const float* bi = (sel == 0) ? bq   : (sel == 1) ? bk   : bv;
  const int t = threadIdx.x, w = t >> 6, l = t & 63;
  const int wr = w >> 2, wc = w & 3;
  const int c = l & 15, g = l >> 4;
  const int m0 = blockIdx.y * 256, n0 = (bx & 3) * 256;

  f32x4 acc[8][4];
#pragma unroll
  for (int i = 0; i < 8; i++)
#pragma unroll
    for (int j = 0; j < 4; j++) acc[i][j] = (f32x4){0.f, 0.f, 0.f, 0.f};

  loop8p(A, Bt, 1024, 1024, 0, 16, m0, n0, sA, sB, acc);

#pragma unroll
  for (int nf = 0; nf < 4; ++nf){
    int n = n0 + wc * 64 + nf * 16 + c;
    float bv_ = bi[n];
#pragma unroll
    for (int mf = 0; mf < 8; ++mf){
      int row0 = m0 + wr * 128 + mf * 16 + 4 * g;
      if (sel == 2){
        bf16x4 pk;
#pragma unroll
        for (int r = 0; r < 4; ++r) pk[r] = (short)f2b(acc[mf][nf][r] + bv_);
        int bb = row0 >> 10, key = row0 & 1023;
        *(bf16x4*)(vtb + ((size_t)bb << 20) + (size_t)n * 1024 + key) = pk;
      } else {
        u16* out = sel ? kbf : qb;
#pragma unroll
        for (int r = 0; r < 4; ++r)
          out[(size_t)(row0 + r) * 1024 + n] = f2b(acc[mf][nf][r] + bv_);
      }
    }
  }
}

// ---------- combine 2 partials + bias + residual, then LayerNorm -> bf16 ----------
__global__ __launch_bounds__(256) void comb_ln0(const float* __restrict__ pp,
                                                const float* __restrict__ bias,
                                                const u16* __restrict__ res,
                                                const float* __restrict__ gw,
                                                const float* __restrict__ bw,
                                                u16* __restrict__ out){
  const int row = blockIdx.x, t = threadIdx.x, w = t >> 6, l = t & 63;
  const size_t i4 = (size_t)row * 1024 + t * 4;
  f32x4 a = *(const f32x4*)(pp + i4);
  f32x4 b = *(const f32x4*)(pp + (1ull << 22) + i4);
  bf16x4 rv = *(const bf16x4*)(res + i4);
  float xs[4], s = 0.f, sq = 0.f;
#pragma unroll
  for (int j = 0; j < 4; j++){
    xs[j] = a[j] + b[j] + bias[t * 4 + j] + b2f((u16)rv[j]);
    s += xs[j]; sq += xs[j] * xs[j];
  }
#pragma unroll
  for (int o = 32; o; o >>= 1){ s += __shfl_xor(s, o); sq += __shfl_xor(sq, o); }
  __shared__ float rs[4], rq[4];
  if (l == 0){ rs[w] = s; rq[w] = sq; }
  __syncthreads();
  s  = rs[0] + rs[1] + rs[2] + rs[3];
  sq = rq[0] + rq[1] + rq[2] + rq[3];
  const float mu   = s * (1.f / 1024.f);
  const float var  = sq * (1.f / 1024.f) - mu * mu;
  const float rstd = rsqrtf(var + 1e-5f);
  bf16x4 o;
#pragma unroll
  for (int j = 0; j < 4; j++) o[j] = (short)f2b((xs[j]-mu)*rstd*gw[t*4+j] + bw[t*4+j]);
  *(bf16x4*)(out + i4) = o;
}

// ---------- combine 4 partials + bias + residual, then LayerNorm -> f32 (d_out) ----------
__global__ __launch_bounds__(256) void comb_ln1(const float* __restrict__ pp,
                                                const float* __restrict__ bias,
                                                const u16* __restrict__ res,
                                                const float* __restrict__ gw,
                                                const float* __restrict__ bw,
                                                float* __restrict__ out){
  const int row = blockIdx.x, t = threadIdx.x, w = t >> 6, l = t & 63;
  const size_t i4 = (size_t)row * 1024 + t * 4;
  f32x4 a = *(const f32x4*)(pp + i4);
#pragma unroll
  for (int z = 1; z < 4; z++){
    f32x4 p = *(const f32x4*)(pp + ((size_t)z << 22) + i4);
    a[0] += p[0]; a[1] += p[1]; a[2] += p[2]; a[3] += p[3];
  }
  bf16x4 rv = *(const bf16x4*)(res + i4);
  float xs[4], s = 0.f, sq = 0.f;
#pragma unroll
  for (int j = 0; j < 4; j++){
    xs[j] = a[j] + bias[t * 4 + j] + b2f((u16)rv[j]);
    s += xs[j]; sq += xs[j] * xs[j];
  }
#pragma unroll
  for (int o = 32; o; o >>= 1){ s += __shfl_xor(s, o); sq += __shfl_xor(sq, o); }
  __shared__ float rs[4], rq[4];
  if (l == 0){ rs[w] = s; rq[w] = sq; }
  __syncthreads();
  s  = rs[0] + rs[1] + rs[2] + rs[3];
  sq = rq[0] + rq[1] + rq[2] + rq[3];
  const float mu   = s * (1.f / 1024.f);
  const float var  = sq * (1.f / 1024.f) - mu * mu;
  const float rstd = rsqrtf(var + 1e-5f);
  float4 o4;
  o4.x = (xs[0]-mu)*rstd*gw[t*4+0] + bw[t*4+0];
  o4.y = (xs[1]-mu)*rstd*gw[t*4+1] + bw[t*4+1];
  o4.z = (xs[2]-mu)*rstd*gw[t*4+2] + bw[t*4+2];
  o4.w = (xs[3]-mu)*rstd*gw[t*4+3] + bw[t*4+3];
  *((float4*)out + (size_t)row * 256 + t) = o4;
}

// ---------- fused masked attention: counted-vmcnt + depth-2 mask prefetch ----------
// Per iter: vmcnt(4) drains stage(it)+mask(it) (issued 2 iters ago), leaves mask(it+1)
// in flight; mask(it+2) is issued mid-iter after mask(it)'s consumption. No vmcnt(0)
// in the main loop. Static mA/mB register sets via macro (rule #20).
#define ATTN_STEP(IT, CUR, MC) do{                                              \
  if ((IT) < 15) asm volatile("s_waitcnt vmcnt(4)" ::: "memory");               \
  else           asm volatile("s_waitcnt vmcnt(0)" ::: "memory");               \
  __builtin_amdgcn_s_barrier();                                                 \
  asm volatile("" ::: "memory");                                                \
  if ((IT) < 15) stage((CUR) ^ 1, ((IT) + 1) * 64);                             \
  asm volatile("" ::: "memory");                                                \
  const char* kt = (const char*)sK[(CUR)];                                      \
  f32x4 st[4];                                                                  \
  _Pragma("unroll")                                                             \
  for (int nf = 0; nf < 4; nf++){                                               \
    const char* kr = kt + (nf * 16 + c) * 128;                                  \
    bf16x8 ak0 = *(const bf16x8*)(kr + ((g * 16) ^ sw));                        \
    bf16x8 ak1 = *(const bf16x8*)(kr + ((64 + g * 16) ^ sw));                   \
    f32x4 z = (f32x4){0.f, 0.f, 0.f, 0.f};                                      \
    z = __builtin_amdgcn_mfma_f32_16x16x32_bf16(ak0, bq0, z, 0, 0, 0);          \
    z = __builtin_amdgcn_mfma_f32_16x16x32_bf16(ak1, bq1, z, 0, 0, 0);          \
    st[nf] = z;                                                                 \
  }                                                                             \
  float tmax = -INFINITY;                                                       \
  _Pragma("unroll")                                                             \
  for (int nf = 0; nf < 4; nf++)                                                \
    _Pragma("unroll")                                                           \
    for (int r = 0; r < 4; r++){                                                \
      float v = st[nf][r] * 0.03125f + MC[nf][r];                               \
      st[nf][r] = v; tmax = fmaxf(tmax, v);                                     \
    }                                                                           \
  if ((IT) < 14){                                                               \
    _Pragma("unroll")                                                           \
    for (int nf = 0; nf < 4; nf++)                                              \
      MC[nf] = *(const f32x4*)(mbase + ((IT) + 2) * 64 + nf * 16 + g * 4);      \
  }                                                                             \
  tmax = fmaxf(tmax, __shfl_xor(tmax, 16));                                     \
  tmax = fmaxf(tmax, __shfl_xor(tmax, 32));                                     \
  float mnew  = fmaxf(m, tmax);                                                 \
  float alpha = __expf(m - mnew);                                               \
  float rsum = 0.f;                                                             \
  bf16x4 pb[4];                                                                 \
  _Pragma("unroll")                                                             \
  for (int nf = 0; nf < 4; nf++)                                                \
    _Pragma("unroll")                                                           \
    for (int r = 0; r < 4; r++){                                                \
      float p = __expf(st[nf][r] - mnew);                                       \
      rsum += p;                                                                \
      pb[nf][r] = (short)f2b(p);                                                \
    }                                                                           \
  rsum += __shfl_xor(rsum, 16); rsum += __shfl_xor(rsum, 32);                   \
  lsum = lsum * alpha + rsum; m = mnew;                                         \
  _Pragma("unroll")                                                             \
  for (int f = 0; f < 4; f++){                                                  \
    acc[f][0] *= alpha; acc[f][1] *= alpha;                                     \
    acc[f][2] *= alpha; acc[f][3] *= alpha;                                     \
  }                                                                             \
  const char* vtc = (const char*)sV[(CUR)];                                     \
  __builtin_amdgcn_s_setprio(1);                                                \
  _Pragma("unroll")                                                             \
  for (int f = 0; f < 4; f++){                                                  \
    const char* vr = vtc + (f * 16 + c) * 128;                                  \
    _Pragma("unroll")                                                           \
    for (int nf = 0; nf < 4; nf++){                                             \
      bf16x4 av = *(const bf16x4*)(vr + ((nf * 32 + g * 8) ^ sw));              \
      acc[f] = __builtin_amdgcn_mfma_f32_16x16x16bf16_1k(av, pb[nf], acc[f], 0, 0, 0); \
    }                                                                           \
  }                                                                             \
  __builtin_amdgcn_s_setprio(0);                                                \
}while(0)

__global__ __launch_bounds__(256, 4) void attn_k(const u16* __restrict__ qb,
                                                 const u16* __restrict__ kb,
                                                 const u16* __restrict__ vt,
                                                 const float* __restrict__ mask,
                                                 u16* __restrict__ ob){
  __shared__ u16 sK[2][4096];   // [key][dh], row stride 128B, XOR-swizzled
  __shared__ u16 sV[2][4096];   // [dh][key], row stride 128B, XOR-swizzled

  const int t = threadIdx.x, w = t >> 6, l = t & 63;
  const int c = l & 15, g = l >> 4;
  const int q0 = blockIdx.x * 64, h = blockIdx.y, b = blockIdx.z;
  const int qrow = q0 + w * 16 + c;
  const size_t qoff = ((size_t)(b * 1024 + qrow)) * 1024 + h * 64;
  const bf16x8 bq0 = *(const bf16x8*)(qb + qoff + g * 8);
  const bf16x8 bq1 = *(const bf16x8*)(qb + qoff + 32 + g * 8);
  const u16* kbase = kb + ((size_t)b * 1024) * 1024 + h * 64;
  const u16* vbase = vt + ((size_t)b << 20) + (size_t)(h * 64) * 1024;
  const float* mbase = mask + ((size_t)(h * 4 + b) * 1024 + qrow) * 1024;

  const int lr3 = l >> 3, lc3 = l & 7;
  const int ch0 = w * 2;

  auto stage = [&](int buf, int kv){
#pragma unroll
    for (int i = 0; i < 2; i++){
      int ch  = ch0 + i;
      int row = ch * 8 + lr3;
      int L   = (lc3 * 16) ^ ((row & 7) << 4);
      gld_lds16(kbase + (size_t)(kv + row) * 1024 + (L >> 1), &sK[buf][ch * 512]);
      gld_lds16(vbase + (size_t)row * 1024 + kv + (L >> 1),   &sV[buf][ch * 512]);
    }
  };

  float m = -INFINITY, lsum = 0.f;
  f32x4 acc[4];
#pragma unroll
  for (int f = 0; f < 4; f++) acc[f] = (f32x4){0.f, 0.f, 0.f, 0.f};

  // prologue: stage(0) first (oldest), then mask(0)->mA, mask(1)->mB
  stage(0, 0);
  asm volatile("" ::: "memory");
  f32x4 mA[4], mB[4];
#pragma unroll
  for (int nf = 0; nf < 4; nf++) mA[nf] = *(const f32x4*)(mbase + nf * 16 + g * 4);
  asm volatile("" ::: "memory");
#pragma unroll
  for (int nf = 0; nf < 4; nf++) mB[nf] = *(const f32x4*)(mbase + 64 + nf * 16 + g * 4);

  const int sw = (c & 7) << 4;
  for (int ii = 0; ii < 8; ++ii){
    ATTN_STEP(2 * ii,     0, mA);
    ATTN_STEP(2 * ii + 1, 1, mB);
  }

  const float inv = 1.f / lsum;
#pragma unroll
  for (int f = 0; f < 4; f++){
    bf16x4 pk;
#pragma unroll
    for (int r = 0; r < 4; r++) pk[r] = (short)f2b(acc[f][r] * inv);
    *(bf16x4*)(ob + qoff + f * 16 + g * 4) = pk;
  }
}

// ---------- launch ----------
extern "C" void kernel_launch(void* const* d_in, const int* in_sizes, int n_in,
                              void* d_out, int out_size, void* d_ws, size_t ws_size,
                              hipStream_t stream){
  const float* Q    = (const float*)d_in[0];
  const float* K    = (const float*)d_in[1];
  const float* mask = (const float*)d_in[2];
  const float* Wq   = (const float*)d_in[4];  const float* bq  = (const float*)d_in[5];
  const float* Wk   = (const float*)d_in[6];  const float* bk  = (const float*)d_in[7];
  const float* Wv   = (const float*)d_in[8];  const float* bv  = (const float*)d_in[9];
  const float* Wo0  = (const float*)d_in[10]; const float* bo0 = (const float*)d_in[11];
  const float* Wo   = (const float*)d_in[12]; const float* bo  = (const float*)d_in[13];
  const float* Wo2  = (const float*)d_in[14]; const float* bo2 = (const float*)d_in[15];
  const float* g0   = (const float*)d_in[16]; const float* be0 = (const float*)d_in[17];
  const float* g1   = (const float*)d_in[18]; const float* be1 = (const float*)d_in[19];

  uint8_t* W = (uint8_t*)d_ws;
  const size_t MB = 1024ull * 1024ull;
  u16* Wq_t  = (u16*)(W + 0);
  u16* Wk_t  = (u16*)(W + 2  * MB);
  u16* Wv_t  = (u16*)(W + 4  * MB);
  u16* Wo0_t = (u16*)(W + 6  * MB);
  u16* Wo_t  = (u16*)(W + 8  * MB);   // [4096][1024]
  u16* Wo2_t = (u16*)(W + 16 * MB);   // [1024][4096]
  u16* Qb    = (u16*)(W + 24 * MB);
  u16* Kb    = (u16*)(W + 32 * MB);
  u16* qb    = (u16*)(W + 40 * MB);
  u16* kbf   = (u16*)(W + 48 * MB);
  u16* vtb   = (u16*)(W + 56 * MB);
  u16* ob    = (u16*)(W + 24 * MB);   // reuse Qb
  u16* x1b   = (u16*)(W + 64 * MB);
  u16* hb    = (u16*)(W + 32 * MB);   // [4096][4096] bf16, spans dead Kb/qb/kbf/vtb
  float* pp  = (float*)(W + 72 * MB); // up to 4 x 16MB f32 partials (Wo0 uses 2, FF2 uses 4)

  // fused input conversions + weight transposes (one dispatch)
  prep<<<11264, 256, 0, stream>>>(Q, K, Qb, Kb, Wq, Wq_t, Wk, Wk_t, Wv, Wv_t,
                                  Wo0, Wo0_t, Wo, Wo_t, Wo2, Wo2_t);

  // fused QKV projections (8-phase 256², 192 blocks)
  gemm8p_qkv<<<dim3(12, 16), 512, 0, stream>>>(Qb, Kb, Wq_t, Wk_t, Wv_t,
                                               bq, bk, bv, qb, kbf, vtb);

  // attention
  attn_k<<<dim3(16, 16, 4), 256, 0, stream>>>(qb, kbf, vtb, mask, ob);

  // output proj (split-K=2) + fused combine+residual+LN0 -> x1b
  gemm_sk2<<<dim3(8, 32, 2), 256, 0, stream>>>(ob, Wo0_t, pp);
  comb_ln0<<<4096, 256, 0, stream>>>(pp, bo0, qb, g0, be0, x1b);

  // FFN: FF1 (8-phase, relu) -> FF2 (8-phase, split-K=4) -> fused combine+residual+LN1
  gemm8p<0><<<dim3(16, 16), 512, 0, stream>>>(x1b, Wo_t, bo, hb, 1024, 1024, 4096, 0, 16);
  gemm8p<1><<<dim3(4, 16, 4), 512, 0, stream>>>(hb, Wo2_t, nullptr, pp, 4096, 4096, 1024, 1024, 16);
  comb_ln1<<<4096, 256, 0, stream>>>(pp, bo2, x1b, g1, be1, (float*)d_out);
}

// Round 7
// 301.463 us; speedup vs baseline: 1.7170x; 1.0035x over previous
//
#include <hip/hip_runtime.h>
#include <hip/hip_bf16.h>

typedef unsigned short u16;
typedef __attribute__((ext_vector_type(4))) short bf16x4;
typedef __attribute__((ext_vector_type(8))) short bf16x8;
typedef __attribute__((ext_vector_type(4))) float f32x4;

// ---------- helpers ----------
static __device__ __forceinline__ u16 f2b(float f){
  union { float f; unsigned u; } v; v.f = f;
  unsigned r = v.u + 0x7fffu + ((v.u >> 16) & 1u);   // RNE
  return (u16)(r >> 16);
}
static __device__ __forceinline__ float b2f(u16 h){
  union { unsigned u; float f; } v; v.u = ((unsigned)h) << 16; return v.f;
}
static __device__ __forceinline__ void gld_lds16(const void* g, void* l){
  __builtin_amdgcn_global_load_lds((const __attribute__((address_space(1))) void*)g,
                                   (__attribute__((address_space(3))) void*)l, 16, 0, 0);
}

// ---------- fused prep: Q/K bf16 convert (compacted) + all 6 weight transposes ----------
__global__ __launch_bounds__(256) void prep(const float* __restrict__ Q,
                                            const float* __restrict__ K,
                                            u16* __restrict__ Qb, u16* __restrict__ Kb,
                                            const float* __restrict__ Wq, u16* __restrict__ Wq_t,
                                            const float* __restrict__ Wk, u16* __restrict__ Wk_t,
                                            const float* __restrict__ Wv, u16* __restrict__ Wv_t,
                                            const float* __restrict__ Wo0, u16* __restrict__ Wo0_t,
                                            const float* __restrict__ Wo, u16* __restrict__ Wo_t,
                                            const float* __restrict__ Wo2, u16* __restrict__ Wo2_t){
  __shared__ float tile[64][65];
  const int id = blockIdx.x, t = threadIdx.x;
  if (id < 8192){
    const float* src; u16* dst;
    if (id < 4096){
      src = Q + (size_t)id * 1024; dst = Qb + (size_t)id * 1024;
    } else {
      int r = id - 4096;
      size_t ir = (size_t)r + (size_t)(r >> 10) * 512;   // skip rows 1024..1535 per batch
      src = K + ir * 1024; dst = Kb + (size_t)r * 1024;
    }
    const float4 v = *(const float4*)(src + t * 4);
    bf16x4 o;
    o[0] = (short)f2b(v.x); o[1] = (short)f2b(v.y);
    o[2] = (short)f2b(v.z); o[3] = (short)f2b(v.w);
    *(bf16x4*)(dst + t * 4) = o;
    return;
  }
  int wid = id - 8192;
  const float* in; u16* out; int Kd, N, bx, by;
  if (wid < 1024){
    int sel = wid >> 8, local = wid & 255;
    bx = local & 15; by = local >> 4; Kd = 1024; N = 1024;
    in  = (sel == 0) ? Wq   : (sel == 1) ? Wk   : (sel == 2) ? Wv   : Wo0;
    out = (sel == 0) ? Wq_t : (sel == 1) ? Wk_t : (sel == 2) ? Wv_t : Wo0_t;
  } else if (wid < 2048){
    int local = wid - 1024; bx = local & 63; by = local >> 6; Kd = 1024; N = 4096;
    in = Wo; out = Wo_t;
  } else {
    int local = wid - 2048; bx = local & 15; by = local >> 4; Kd = 4096; N = 1024;
    in = Wo2; out = Wo2_t;
  }
  const int k0 = by * 64, n0 = bx * 64;
  const int tr = t >> 4, tc = t & 15;
#pragma unroll
  for (int i = 0; i < 4; i++){
    int r = tr + i * 16;
    float4 v = *(const float4*)(in + (size_t)(k0 + r) * N + n0 + tc * 4);
    tile[r][tc*4+0] = v.x; tile[r][tc*4+1] = v.y; tile[r][tc*4+2] = v.z; tile[r][tc*4+3] = v.w;
  }
  __syncthreads();
#pragma unroll
  for (int i = 0; i < 4; i++){
    int nr = tr + i * 16;
    bf16x4 pk;
#pragma unroll
    for (int j = 0; j < 4; j++) pk[j] = (short)f2b(tile[tc*4+j][nr]);
    *(bf16x4*)(out + (size_t)(n0 + nr) * Kd + k0 + tc * 4) = pk;
  }
}

// ---------- m97-structure GEMM main loop (128x128 tile, BK=64) ----------
static __device__ __forceinline__ void gemm_mainloop(const u16* __restrict__ A,
                                                     const u16* __restrict__ Bt,
                                                     int lda, int ldb, int kbeg, int kend,
                                                     int m0, int n0,
                                                     u16* lA, u16* lB, f32x4 acc[4][4]){
  const int t = threadIdx.x, w = t >> 6, l = t & 63;
  const int wr = w >> 1, wc = w & 1;
  const int lrow = l >> 3, lc8 = l & 7;
  const int c = l & 15, g = l >> 4;
  for (int k0 = kbeg; k0 < kend; k0 += 64){
#pragma unroll
    for (int i = 0; i < 4; i++){
      int ch = w * 4 + i;
      int r  = ch * 8 + lrow;
      gld_lds16(A  + (size_t)(m0 + r) * lda + k0 + lc8 * 8, lA + ch * 512);
      gld_lds16(Bt + (size_t)(n0 + r) * ldb + k0 + lc8 * 8, lB + ch * 512);
    }
    __syncthreads();
#pragma unroll
    for (int ks = 0; ks < 2; ks++){
      bf16x8 af[4], bfr[4];
#pragma unroll
      for (int mi = 0; mi < 4; mi++){
        int row = wr * 64 + mi * 16 + c;
        af[mi] = *(const bf16x8*)((const char*)lA + row * 128 + ks * 64 + g * 16);
      }
#pragma unroll
      for (int ni = 0; ni < 4; ni++){
        int row = wc * 64 + ni * 16 + c;
        bfr[ni] = *(const bf16x8*)((const char*)lB + row * 128 + ks * 64 + g * 16);
      }
#pragma unroll
      for (int mi = 0; mi < 4; mi++)
#pragma unroll
        for (int ni = 0; ni < 4; ni++)
          acc[mi][ni] = __builtin_amdgcn_mfma_f32_16x16x32_bf16(af[mi], bfr[ni], acc[mi][ni], 0, 0, 0);
    }
    __syncthreads();
  }
}

// ---------- Wo0 split-K=2 (m97 loop, f32 partials) ----------
__global__ __launch_bounds__(256) void gemm_sk2(const u16* __restrict__ A,
                                                const u16* __restrict__ Bt,
                                                float* __restrict__ pout){
  __shared__ u16 lA[128 * 64];
  __shared__ u16 lB[128 * 64];
  const int t = threadIdx.x, w = t >> 6, l = t & 63;
  const int m0 = blockIdx.y * 128, n0 = blockIdx.x * 128;
  const int wr = w >> 1, wc = w & 1;
  const int c = l & 15, g = l >> 4;
  const int kbeg = blockIdx.z * 512;

  f32x4 acc[4][4];
#pragma unroll
  for (int i = 0; i < 4; i++)
#pragma unroll
    for (int j = 0; j < 4; j++) acc[i][j] = (f32x4){0.f, 0.f, 0.f, 0.f};

  gemm_mainloop(A, Bt, 1024, 1024, kbeg, kbeg + 512, m0, n0, lA, lB, acc);

  float* po = pout + ((size_t)blockIdx.z << 22);
#pragma unroll
  for (int ni = 0; ni < 4; ni++){
    int n = n0 + wc * 64 + ni * 16 + c;
#pragma unroll
    for (int mi = 0; mi < 4; mi++){
      int row0 = m0 + wr * 64 + mi * 16 + 4 * g;
#pragma unroll
      for (int r = 0; r < 4; r++)
        po[(size_t)(row0 + r) * 1024 + n] = acc[mi][ni][r];
    }
  }
}

// ---------- 256x256 8-phase main loop (T2+T3+T4+T5), BK=64, 8 waves ----------
static __device__ __forceinline__ void loop8p(const u16* __restrict__ A,
                                              const u16* __restrict__ Bt,
                                              int lda, int ldb, int kbeg, int NT,
                                              int m0, int n0,
                                              u16 (*sA)[2][8192], u16 (*sB)[2][8192],
                                              f32x4 acc[8][4]){
  const int t = threadIdx.x, w = t >> 6, l = t & 63;
  const int wr = w >> 2, wc = w & 3;
  const int c = l & 15, g = l >> 4;
  const int sr = t >> 3, scb = (t & 7) << 4;

  auto stA = [&](int d, int h, int T){
#pragma unroll
    for (int i = 0; i < 2; i++){
      int row = i * 64 + sr;
      int Lb  = scb ^ ((row & 7) << 4);
      gld_lds16(A + (size_t)(m0 + h * 128 + row) * lda + kbeg + T * 64 + (Lb >> 1),
                (char*)&sA[d][h][0] + i * 8192 + t * 16);
    }
  };
  auto stB = [&](int d, int h, int T){
#pragma unroll
    for (int i = 0; i < 2; i++){
      int row = i * 64 + sr;
      int Lb  = scb ^ ((row & 7) << 4);
      gld_lds16(Bt + (size_t)(n0 + h * 128 + row) * ldb + kbeg + T * 64 + (Lb >> 1),
                (char*)&sB[d][h][0] + i * 8192 + t * 16);
    }
  };

  // prologue: B0(0),B1(0),A0(0),A1(0),B0(1),B1(1)
  stB(0, 0, 0); stB(0, 1, 0); stA(0, 0, 0); stA(0, 1, 0);
  stB(1, 0, 1); stB(1, 1, 1);

  bf16x8 bfr[4][2];
  for (int T = 0; T < NT; ++T){
    const int d = T & 1;
    const char* pa = (const char*)&sA[d][wr][0];
    const char* pb = (const char*)&sB[d][wc >> 1][0];
#pragma unroll
    for (int q = 0; q < 4; ++q){
      if (q == 0){
        if (T + 1 < NT) asm volatile("s_waitcnt vmcnt(4)" ::: "memory");
        else            asm volatile("s_waitcnt vmcnt(0)" ::: "memory");
        asm volatile("" ::: "memory");
        __builtin_amdgcn_s_barrier();
        asm volatile("" ::: "memory");
#pragma unroll
        for (int nf = 0; nf < 4; ++nf){
          int lr = (wc & 1) * 64 + nf * 16 + c;
#pragma unroll
          for (int ks = 0; ks < 2; ++ks)
            bfr[nf][ks] = *(const bf16x8*)(pb + lr * 128 + ((ks * 64 + g * 16) ^ ((lr & 7) << 4)));
        }
      }
      bf16x8 af[2][2];
#pragma unroll
      for (int mi = 0; mi < 2; ++mi){
        int lr = (q * 2 + mi) * 16 + c;
#pragma unroll
        for (int ks = 0; ks < 2; ++ks)
          af[mi][ks] = *(const bf16x8*)(pa + lr * 128 + ((ks * 64 + g * 16) ^ ((lr & 7) << 4)));
      }
      if      (q == 0){ if (T + 1 < NT) stA(d ^ 1, 0, T + 1); }
      else if (q == 1){ if (T + 1 < NT) stA(d ^ 1, 1, T + 1); }
      else if (q == 2){ if (T + 2 < NT) stB(d, 0, T + 2); }
      else            { if (T + 2 < NT) stB(d, 1, T + 2); }
      __builtin_amdgcn_s_setprio(1);
#pragma unroll
      for (int mi = 0; mi < 2; ++mi)
#pragma unroll
        for (int nf = 0; nf < 4; ++nf)
#pragma unroll
          for (int ks = 0; ks < 2; ++ks)
            acc[q * 2 + mi][nf] =
              __builtin_amdgcn_mfma_f32_16x16x32_bf16(af[mi][ks], bfr[nf][ks], acc[q * 2 + mi][nf], 0, 0, 0);
      __builtin_amdgcn_s_setprio(0);
      asm volatile("" ::: "memory");
      __builtin_amdgcn_s_barrier();
      asm volatile("" ::: "memory");
    }
  }
}

// ---------- 8-phase GEMM with XCD-rect swizzle ----------
// EPI 0 (FF1, grid 16x16): per-XCD 8x4 rect. EPI 1 (FF2, grid 4x16x4): per-XCD (4bx,2by,4bz).
template<int EPI>
__global__ __launch_bounds__(512, 2) void gemm8p(const u16* __restrict__ A,
                                                 const u16* __restrict__ Bt,
                                                 const float* __restrict__ bias,
                                                 void* __restrict__ outp,
                                                 int lda, int ldb, int ldout,
                                                 int ksz, int NT){
  __shared__ u16 sA[2][2][8192];
  __shared__ u16 sB[2][2][8192];
  const int t = threadIdx.x, w = t >> 6, l = t & 63;
  const int wr = w >> 2, wc = w & 3;
  const int c = l & 15, g = l >> 4;

  int m0, n0, zidx;
  if (EPI == 0){
    // grid (16,16): lid -> xcd rect of 8 cols x 4 rows
    int lid = blockIdx.x + (blockIdx.y << 4);
    int xcd = lid & 7, slot = lid >> 3;               // slot 0..31
    int bx = ((xcd & 1) << 3) + (slot & 7);
    int by = ((xcd >> 1) << 2) + (slot >> 3);
    m0 = by * 256; n0 = bx * 256; zidx = 0;
  } else {
    // grid (4,16,4): lid -> xcd rect (4 bx, 2 by, 4 bz)
    int lid = blockIdx.x + (blockIdx.y << 2) + (blockIdx.z << 6);
    int xcd = lid & 7, slot = lid >> 3;               // slot 0..31
    int bx = slot & 3, rest = slot >> 2;              // rest 0..7
    int by = (xcd << 1) + (rest & 1);
    zidx = rest >> 1;                                 // 0..3
    m0 = by * 256; n0 = bx * 256;
  }

  f32x4 acc[8][4];
#pragma unroll
  for (int i = 0; i < 8; i++)
#pragma unroll
    for (int j = 0; j < 4; j++) acc[i][j] = (f32x4){0.f, 0.f, 0.f, 0.f};

  loop8p(A, Bt, lda, ldb, zidx * ksz, NT, m0, n0, sA, sB, acc);

  if (EPI == 0){
    u16* out = (u16*)outp;
#pragma unroll
    for (int nf = 0; nf < 4; ++nf){
      int n = n0 + wc * 64 + nf * 16 + c;
      float bv = bias[n];
#pragma unroll
      for (int mf = 0; mf < 8; ++mf){
        int row0 = m0 + wr * 128 + mf * 16 + 4 * g;
#pragma unroll
        for (int r = 0; r < 4; ++r)
          out[(size_t)(row0 + r) * ldout + n] = f2b(fmaxf(acc[mf][nf][r] + bv, 0.f));
      }
    }
  } else {
    float* po = (float*)outp + ((size_t)zidx << 22);
#pragma unroll
    for (int nf = 0; nf < 4; ++nf){
      int n = n0 + wc * 64 + nf * 16 + c;
#pragma unroll
      for (int mf = 0; mf < 8; ++mf){
        int row0 = m0 + wr * 128 + mf * 16 + 4 * g;
#pragma unroll
        for (int r = 0; r < 4; ++r)
          po[(size_t)(row0 + r) * 1024 + n] = acc[mf][nf][r];
      }
    }
  }
}

// ---------- fused QKV (8-phase 256², grid 12x16, XCD 3x8 rect); V writes transposed ----------
__global__ __launch_bounds__(512, 2) void gemm8p_qkv(const u16* __restrict__ Qb,
                                                     const u16* __restrict__ Kb,
                                                     const u16* __restrict__ Wq_t,
                                                     const u16* __restrict__ Wk_t,
                                                     const u16* __restrict__ Wv_t,
                                                     const float* __restrict__ bq,
                                                     const float* __restrict__ bk,
                                                     const float* __restrict__ bv,
                                                     u16* __restrict__ qb,
                                                     u16* __restrict__ kbf,
                                                     u16* __restrict__ vtb){
  __shared__ u16 sA[2][2][8192];
  __shared__ u16 sB[2][2][8192];
  // swizzle: lid -> per-XCD rect of 3 cols x 8 rows
  int lid = blockIdx.x + blockIdx.y * 12;
  int xcd = lid & 7, slot = lid >> 3;                 // slot 0..23
  int bx = (xcd & 3) * 3 + slot % 3;                  // 0..11
  int by = ((xcd >> 2) << 3) + slot / 3;              // 0..15
  const int sel = bx >> 2;
  const u16* A    = sel ? Kb : Qb;
  const u16* Bt   = (sel == 0) ? Wq_t : (sel == 1) ? Wk_t : Wv_t;
  const float* bi = (sel == 0) ? bq   : (sel == 1) ? bk   : bv;
  const int t = threadIdx.x, w = t >> 6, l = t & 63;
  const int wr = w >> 2, wc = w & 3;
  const int c = l & 15, g = l >> 4;
  const int m0 = by * 256, n0 = (bx & 3) * 256;

  f32x4 acc[8][4];
#pragma unroll
  for (int i = 0; i < 8; i++)
#pragma unroll
    for (int j = 0; j < 4; j++) acc[i][j] = (f32x4){0.f, 0.f, 0.f, 0.f};

  loop8p(A, Bt, 1024, 1024, 0, 16, m0, n0, sA, sB, acc);

#pragma unroll
  for (int nf = 0; nf < 4; ++nf){
    int n = n0 + wc * 64 + nf * 16 + c;
    float bv_ = bi[n];
#pragma unroll
    for (int mf = 0; mf < 8; ++mf){
      int row0 = m0 + wr * 128 + mf * 16 + 4 * g;
      if (sel == 2){
        bf16x4 pk;
#pragma unroll
        for (int r = 0; r < 4; ++r) pk[r] = (short)f2b(acc[mf][nf][r] + bv_);
        int bb = row0 >> 10, key = row0 & 1023;
        *(bf16x4*)(vtb + ((size_t)bb << 20) + (size_t)n * 1024 + key) = pk;
      } else {
        u16* out = sel ? kbf : qb;
#pragma unroll
        for (int r = 0; r < 4; ++r)
          out[(size_t)(row0 + r) * 1024 + n] = f2b(acc[mf][nf][r] + bv_);
      }
    }
  }
}

// ---------- combine 2 partials + bias + residual, then LayerNorm -> bf16 ----------
__global__ __launch_bounds__(256) void comb_ln0(const float* __restrict__ pp,
                                                const float* __restrict__ bias,
                                                const u16* __restrict__ res,
                                                const float* __restrict__ gw,
                                                const float* __restrict__ bw,
                                                u16* __restrict__ out){
  const int row = blockIdx.x, t = threadIdx.x, w = t >> 6, l = t & 63;
  const size_t i4 = (size_t)row * 1024 + t * 4;
  f32x4 a = *(const f32x4*)(pp + i4);
  f32x4 b = *(const f32x4*)(pp + (1ull << 22) + i4);
  bf16x4 rv = *(const bf16x4*)(res + i4);
  float xs[4], s = 0.f, sq = 0.f;
#pragma unroll
  for (int j = 0; j < 4; j++){
    xs[j] = a[j] + b[j] + bias[t * 4 + j] + b2f((u16)rv[j]);
    s += xs[j]; sq += xs[j] * xs[j];
  }
#pragma unroll
  for (int o = 32; o; o >>= 1){ s += __shfl_xor(s, o); sq += __shfl_xor(sq, o); }
  __shared__ float rs[4], rq[4];
  if (l == 0){ rs[w] = s; rq[w] = sq; }
  __syncthreads();
  s  = rs[0] + rs[1] + rs[2] + rs[3];
  sq = rq[0] + rq[1] + rq[2] + rq[3];
  const float mu   = s * (1.f / 1024.f);
  const float var  = sq * (1.f / 1024.f) - mu * mu;
  const float rstd = rsqrtf(var + 1e-5f);
  bf16x4 o;
#pragma unroll
  for (int j = 0; j < 4; j++) o[j] = (short)f2b((xs[j]-mu)*rstd*gw[t*4+j] + bw[t*4+j]);
  *(bf16x4*)(out + i4) = o;
}

// ---------- combine 4 partials + bias + residual, then LayerNorm -> f32 (d_out) ----------
__global__ __launch_bounds__(256) void comb_ln1(const float* __restrict__ pp,
                                                const float* __restrict__ bias,
                                                const u16* __restrict__ res,
                                                const float* __restrict__ gw,
                                                const float* __restrict__ bw,
                                                float* __restrict__ out){
  const int row = blockIdx.x, t = threadIdx.x, w = t >> 6, l = t & 63;
  const size_t i4 = (size_t)row * 1024 + t * 4;
  f32x4 a = *(const f32x4*)(pp + i4);
#pragma unroll
  for (int z = 1; z < 4; z++){
    f32x4 p = *(const f32x4*)(pp + ((size_t)z << 22) + i4);
    a[0] += p[0]; a[1] += p[1]; a[2] += p[2]; a[3] += p[3];
  }
  bf16x4 rv = *(const bf16x4*)(res + i4);
  float xs[4], s = 0.f, sq = 0.f;
#pragma unroll
  for (int j = 0; j < 4; j++){
    xs[j] = a[j] + bias[t * 4 + j] + b2f((u16)rv[j]);
    s += xs[j]; sq += xs[j] * xs[j];
  }
#pragma unroll
  for (int o = 32; o; o >>= 1){ s += __shfl_xor(s, o); sq += __shfl_xor(sq, o); }
  __shared__ float rs[4], rq[4];
  if (l == 0){ rs[w] = s; rq[w] = sq; }
  __syncthreads();
  s  = rs[0] + rs[1] + rs[2] + rs[3];
  sq = rq[0] + rq[1] + rq[2] + rq[3];
  const float mu   = s * (1.f / 1024.f);
  const float var  = sq * (1.f / 1024.f) - mu * mu;
  const float rstd = rsqrtf(var + 1e-5f);
  float4 o4;
  o4.x = (xs[0]-mu)*rstd*gw[t*4+0] + bw[t*4+0];
  o4.y = (xs[1]-mu)*rstd*gw[t*4+1] + bw[t*4+1];
  o4.z = (xs[2]-mu)*rstd*gw[t*4+2] + bw[t*4+2];
  o4.w = (xs[3]-mu)*rstd*gw[t*4+3] + bw[t*4+3];
  *((float4*)out + (size_t)row * 256 + t) = o4;
}

// ---------- fused masked attention: counted-vmcnt + depth-2 mask prefetch + XCD cluster ----------
#define ATTN_STEP(IT, CUR, MC) do{                                              \
  if ((IT) < 15) asm volatile("s_waitcnt vmcnt(4)" ::: "memory");               \
  else           asm volatile("s_waitcnt vmcnt(0)" ::: "memory");               \
  __builtin_amdgcn_s_barrier();                                                 \
  asm volatile("" ::: "memory");                                                \
  if ((IT) < 15) stage((CUR) ^ 1, ((IT) + 1) * 64);                             \
  asm volatile("" ::: "memory");                                                \
  const char* kt = (const char*)sK[(CUR)];                                      \
  f32x4 st[4];                                                                  \
  _Pragma("unroll")                                                             \
  for (int nf = 0; nf < 4; nf++){                                               \
    const char* kr = kt + (nf * 16 + c) * 128;                                  \
    bf16x8 ak0 = *(const bf16x8*)(kr + ((g * 16) ^ sw));                        \
    bf16x8 ak1 = *(const bf16x8*)(kr + ((64 + g * 16) ^ sw));                   \
    f32x4 z = (f32x4){0.f, 0.f, 0.f, 0.f};                                      \
    z = __builtin_amdgcn_mfma_f32_16x16x32_bf16(ak0, bq0, z, 0, 0, 0);          \
    z = __builtin_amdgcn_mfma_f32_16x16x32_bf16(ak1, bq1, z, 0, 0, 0);          \
    st[nf] = z;                                                                 \
  }                                                                             \
  float tmax = -INFINITY;                                                       \
  _Pragma("unroll")                                                             \
  for (int nf = 0; nf < 4; nf++)                                                \
    _Pragma("unroll")                                                           \
    for (int r = 0; r < 4; r++){                                                \
      float v = st[nf][r] * 0.03125f + MC[nf][r];                               \
      st[nf][r] = v; tmax = fmaxf(tmax, v);                                     \
    }                                                                           \
  if ((IT) < 14){                                                               \
    _Pragma("unroll")                                                           \
    for (int nf = 0; nf < 4; nf++)                                              \
      MC[nf] = *(const f32x4*)(mbase + ((IT) + 2) * 64 + nf * 16 + g * 4);      \
  }                                                                             \
  tmax = fmaxf(tmax, __shfl_xor(tmax, 16));                                     \
  tmax = fmaxf(tmax, __shfl_xor(tmax, 32));                                     \
  float mnew  = fmaxf(m, tmax);                                                 \
  float alpha = __expf(m - mnew);                                               \
  float rsum = 0.f;                                                             \
  bf16x4 pb[4];                                                                 \
  _Pragma("unroll")                                                             \
  for (int nf = 0; nf < 4; nf++)                                                \
    _Pragma("unroll")                                                           \
    for (int r = 0; r < 4; r++){                                                \
      float p = __expf(st[nf][r] - mnew);                                       \
      rsum += p;                                                                \
      pb[nf][r] = (short)f2b(p);                                                \
    }                                                                           \
  rsum += __shfl_xor(rsum, 16); rsum += __shfl_xor(rsum, 32);                   \
  lsum = lsum * alpha + rsum; m = mnew;                                         \
  _Pragma("unroll")                                                             \
  for (int f = 0; f < 4; f++){                                                  \
    acc[f][0] *= alpha; acc[f][1] *= alpha;                                     \
    acc[f][2] *= alpha; acc[f][3] *= alpha;                                     \
  }                                                                             \
  const char* vtc = (const char*)sV[(CUR)];                                     \
  __builtin_amdgcn_s_setprio(1);                                                \
  _Pragma("unroll")                                                             \
  for (int f = 0; f < 4; f++){                                                  \
    const char* vr = vtc + (f * 16 + c) * 128;                                  \
    _Pragma("unroll")                                                           \
    for (int nf = 0; nf < 4; nf++){                                             \
      bf16x4 av = *(const bf16x4*)(vr + ((nf * 32 + g * 8) ^ sw));              \
      acc[f] = __builtin_amdgcn_mfma_f32_16x16x16bf16_1k(av, pb[nf], acc[f], 0, 0, 0); \
    }                                                                           \
  }                                                                             \
  __builtin_amdgcn_s_setprio(0);                                                \
}while(0)

__global__ __launch_bounds__(256, 4) void attn_k(const u16* __restrict__ qb,
                                                 const u16* __restrict__ kb,
                                                 const u16* __restrict__ vt,
                                                 const float* __restrict__ mask,
                                                 u16* __restrict__ ob){
  __shared__ u16 sK[2][4096];   // [key][dh], row stride 128B, XOR-swizzled
  __shared__ u16 sV[2][4096];   // [dh][key], row stride 128B, XOR-swizzled

  const int t = threadIdx.x, w = t >> 6, l = t & 63;
  const int c = l & 15, g = l >> 4;
  // XCD cluster: the 16 q-tiles sharing one (h,b)'s K/V get bids == const (mod 8)
  // under round-robin bid->XCD, so each K/V tile is HBM-fetched by one XCD only.
  const int lid  = blockIdx.x + (blockIdx.y << 4) + (blockIdx.z << 8);
  const int xcd  = lid & 7, slot = lid >> 3;           // slot 0..127
  const int grp  = xcd + ((slot >> 4) << 3);           // group (h,b) 0..63
  const int q0   = (slot & 15) * 64;
  const int h    = grp & 15, b = grp >> 4;
  const int qrow = q0 + w * 16 + c;
  const size_t qoff = ((size_t)(b * 1024 + qrow)) * 1024 + h * 64;
  const bf16x8 bq0 = *(const bf16x8*)(qb + qoff + g * 8);
  const bf16x8 bq1 = *(const bf16x8*)(qb + qoff + 32 + g * 8);
  const u16* kbase = kb + ((size_t)b * 1024) * 1024 + h * 64;
  const u16* vbase = vt + ((size_t)b << 20) + (size_t)(h * 64) * 1024;
  const float* mbase = mask + ((size_t)(h * 4 + b) * 1024 + qrow) * 1024;

  const int lr3 = l >> 3, lc3 = l & 7;
  const int ch0 = w * 2;

  auto stage = [&](int buf, int kv){
#pragma unroll
    for (int i = 0; i < 2; i++){
      int ch  = ch0 + i;
      int row = ch * 8 + lr3;
      int L   = (lc3 * 16) ^ ((row & 7) << 4);
      gld_lds16(kbase + (size_t)(kv + row) * 1024 + (L >> 1), &sK[buf][ch * 512]);
      gld_lds16(vbase + (size_t)row * 1024 + kv + (L >> 1),   &sV[buf][ch * 512]);
    }
  };

  float m = -INFINITY, lsum = 0.f;
  f32x4 acc[4];
#pragma unroll
  for (int f = 0; f < 4; f++) acc[f] = (f32x4){0.f, 0.f, 0.f, 0.f};

  // prologue: stage(0) first (oldest), then mask(0)->mA, mask(1)->mB
  stage(0, 0);
  asm volatile("" ::: "memory");
  f32x4 mA[4], mB[4];
#pragma unroll
  for (int nf = 0; nf < 4; nf++) mA[nf] = *(const f32x4*)(mbase + nf * 16 + g * 4);
  asm volatile("" ::: "memory");
#pragma unroll
  for (int nf = 0; nf < 4; nf++) mB[nf] = *(const f32x4*)(mbase + 64 + nf * 16 + g * 4);

  const int sw = (c & 7) << 4;
  for (int ii = 0; ii < 8; ++ii){
    ATTN_STEP(2 * ii,     0, mA);
    ATTN_STEP(2 * ii + 1, 1, mB);
  }

  const float inv = 1.f / lsum;
#pragma unroll
  for (int f = 0; f < 4; f++){
    bf16x4 pk;
#pragma unroll
    for (int r = 0; r < 4; r++) pk[r] = (short)f2b(acc[f][r] * inv);
    *(bf16x4*)(ob + qoff + f * 16 + g * 4) = pk;
  }
}

// ---------- launch ----------
extern "C" void kernel_launch(void* const* d_in, const int* in_sizes, int n_in,
                              void* d_out, int out_size, void* d_ws, size_t ws_size,
                              hipStream_t stream){
  const float* Q    = (const float*)d_in[0];
  const float* K    = (const float*)d_in[1];
  const float* mask = (const float*)d_in[2];
  const float* Wq   = (const float*)d_in[4];  const float* bq  = (const float*)d_in[5];
  const float* Wk   = (const float*)d_in[6];  const float* bk  = (const float*)d_in[7];
  const float* Wv   = (const float*)d_in[8];  const float* bv  = (const float*)d_in[9];
  const float* Wo0  = (const float*)d_in[10]; const float* bo0 = (const float*)d_in[11];
  const float* Wo   = (const float*)d_in[12]; const float* bo  = (const float*)d_in[13];
  const float* Wo2  = (const float*)d_in[14]; const float* bo2 = (const float*)d_in[15];
  const float* g0   = (const float*)d_in[16]; const float* be0 = (const float*)d_in[17];
  const float* g1   = (const float*)d_in[18]; const float* be1 = (const float*)d_in[19];

  uint8_t* W = (uint8_t*)d_ws;
  const size_t MB = 1024ull * 1024ull;
  u16* Wq_t  = (u16*)(W + 0);
  u16* Wk_t  = (u16*)(W + 2  * MB);
  u16* Wv_t  = (u16*)(W + 4  * MB);
  u16* Wo0_t = (u16*)(W + 6  * MB);
  u16* Wo_t  = (u16*)(W + 8  * MB);   // [4096][1024]
  u16* Wo2_t = (u16*)(W + 16 * MB);   // [1024][4096]
  u16* Qb    = (u16*)(W + 24 * MB);
  u16* Kb    = (u16*)(W + 32 * MB);
  u16* qb    = (u16*)(W + 40 * MB);
  u16* kbf   = (u16*)(W + 48 * MB);
  u16* vtb   = (u16*)(W + 56 * MB);
  u16* ob    = (u16*)(W + 24 * MB);   // reuse Qb
  u16* x1b   = (u16*)(W + 64 * MB);
  u16* hb    = (u16*)(W + 32 * MB);   // [4096][4096] bf16, spans dead Kb/qb/kbf/vtb
  float* pp  = (float*)(W + 72 * MB); // up to 4 x 16MB f32 partials (Wo0 uses 2, FF2 uses 4)

  // fused input conversions + weight transposes (one dispatch)
  prep<<<11264, 256, 0, stream>>>(Q, K, Qb, Kb, Wq, Wq_t, Wk, Wk_t, Wv, Wv_t,
                                  Wo0, Wo0_t, Wo, Wo_t, Wo2, Wo2_t);

  // fused QKV projections (8-phase 256², 192 blocks, XCD rect)
  gemm8p_qkv<<<dim3(12, 16), 512, 0, stream>>>(Qb, Kb, Wq_t, Wk_t, Wv_t,
                                               bq, bk, bv, qb, kbf, vtb);

  // attention (XCD-clustered K/V sharing)
  attn_k<<<dim3(16, 16, 4), 256, 0, stream>>>(qb, kbf, vtb, mask, ob);

  // output proj (split-K=2) + fused combine+residual+LN0 -> x1b
  gemm_sk2<<<dim3(8, 32, 2), 256, 0, stream>>>(ob, Wo0_t, pp);
  comb_ln0<<<4096, 256, 0, stream>>>(pp, bo0, qb, g0, be0, x1b);

  // FFN: FF1 (8-phase, relu, XCD rect) -> FF2 (8-phase, split-K=4, XCD rect) -> combine+LN1
  gemm8p<0><<<dim3(16, 16), 512, 0, stream>>>(x1b, Wo_t, bo, hb, 1024, 1024, 4096, 0, 16);
  gemm8p<1><<<dim3(4, 16, 4), 512, 0, stream>>>(hb, Wo2_t, nullptr, pp, 4096, 4096, 1024, 1024, 16);
  comb_ln1<<<4096, 256, 0, stream>>>(pp, bo2, x1b, g1, be1, (float*)d_out);
}

// Round 8
// 299.023 us; speedup vs baseline: 1.7310x; 1.0082x over previous
//
#include <hip/hip_runtime.h>
#include <hip/hip_bf16.h>

typedef unsigned short u16;
typedef __attribute__((ext_vector_type(4))) short bf16x4;
typedef __attribute__((ext_vector_type(8))) short bf16x8;
typedef __attribute__((ext_vector_type(4))) float f32x4;

// ---------- helpers ----------
static __device__ __forceinline__ u16 f2b(float f){
  union { float f; unsigned u; } v; v.f = f;
  unsigned r = v.u + 0x7fffu + ((v.u >> 16) & 1u);   // RNE
  return (u16)(r >> 16);
}
static __device__ __forceinline__ float b2f(u16 h){
  union { unsigned u; float f; } v; v.u = ((unsigned)h) << 16; return v.f;
}
static __device__ __forceinline__ void gld_lds16(const void* g, void* l){
  __builtin_amdgcn_global_load_lds((const __attribute__((address_space(1))) void*)g,
                                   (__attribute__((address_space(3))) void*)l, 16, 0, 0);
}

// ---------- fused prep: Q/K bf16 convert (compacted) + all 6 weight transposes ----------
__global__ __launch_bounds__(256) void prep(const float* __restrict__ Q,
                                            const float* __restrict__ K,
                                            u16* __restrict__ Qb, u16* __restrict__ Kb,
                                            const float* __restrict__ Wq, u16* __restrict__ Wq_t,
                                            const float* __restrict__ Wk, u16* __restrict__ Wk_t,
                                            const float* __restrict__ Wv, u16* __restrict__ Wv_t,
                                            const float* __restrict__ Wo0, u16* __restrict__ Wo0_t,
                                            const float* __restrict__ Wo, u16* __restrict__ Wo_t,
                                            const float* __restrict__ Wo2, u16* __restrict__ Wo2_t){
  __shared__ float tile[64][65];
  const int id = blockIdx.x, t = threadIdx.x;
  if (id < 8192){
    const float* src; u16* dst;
    if (id < 4096){
      src = Q + (size_t)id * 1024; dst = Qb + (size_t)id * 1024;
    } else {
      int r = id - 4096;
      size_t ir = (size_t)r + (size_t)(r >> 10) * 512;   // skip rows 1024..1535 per batch
      src = K + ir * 1024; dst = Kb + (size_t)r * 1024;
    }
    const float4 v = *(const float4*)(src + t * 4);
    bf16x4 o;
    o[0] = (short)f2b(v.x); o[1] = (short)f2b(v.y);
    o[2] = (short)f2b(v.z); o[3] = (short)f2b(v.w);
    *(bf16x4*)(dst + t * 4) = o;
    return;
  }
  int wid = id - 8192;
  const float* in; u16* out; int Kd, N, bx, by;
  if (wid < 1024){
    int sel = wid >> 8, local = wid & 255;
    bx = local & 15; by = local >> 4; Kd = 1024; N = 1024;
    in  = (sel == 0) ? Wq   : (sel == 1) ? Wk   : (sel == 2) ? Wv   : Wo0;
    out = (sel == 0) ? Wq_t : (sel == 1) ? Wk_t : (sel == 2) ? Wv_t : Wo0_t;
  } else if (wid < 2048){
    int local = wid - 1024; bx = local & 63; by = local >> 6; Kd = 1024; N = 4096;
    in = Wo; out = Wo_t;
  } else {
    int local = wid - 2048; bx = local & 15; by = local >> 4; Kd = 4096; N = 1024;
    in = Wo2; out = Wo2_t;
  }
  const int k0 = by * 64, n0 = bx * 64;
  const int tr = t >> 4, tc = t & 15;
#pragma unroll
  for (int i = 0; i < 4; i++){
    int r = tr + i * 16;
    float4 v = *(const float4*)(in + (size_t)(k0 + r) * N + n0 + tc * 4);
    tile[r][tc*4+0] = v.x; tile[r][tc*4+1] = v.y; tile[r][tc*4+2] = v.z; tile[r][tc*4+3] = v.w;
  }
  __syncthreads();
#pragma unroll
  for (int i = 0; i < 4; i++){
    int nr = tr + i * 16;
    bf16x4 pk;
#pragma unroll
    for (int j = 0; j < 4; j++) pk[j] = (short)f2b(tile[tc*4+j][nr]);
    *(bf16x4*)(out + (size_t)(n0 + nr) * Kd + k0 + tc * 4) = pk;
  }
}

// ---------- m97-structure GEMM main loop (128x128 tile, BK=64) ----------
static __device__ __forceinline__ void gemm_mainloop(const u16* __restrict__ A,
                                                     const u16* __restrict__ Bt,
                                                     int lda, int ldb, int kbeg, int kend,
                                                     int m0, int n0,
                                                     u16* lA, u16* lB, f32x4 acc[4][4]){
  const int t = threadIdx.x, w = t >> 6, l = t & 63;
  const int wr = w >> 1, wc = w & 1;
  const int lrow = l >> 3, lc8 = l & 7;
  const int c = l & 15, g = l >> 4;
  for (int k0 = kbeg; k0 < kend; k0 += 64){
#pragma unroll
    for (int i = 0; i < 4; i++){
      int ch = w * 4 + i;
      int r  = ch * 8 + lrow;
      gld_lds16(A  + (size_t)(m0 + r) * lda + k0 + lc8 * 8, lA + ch * 512);
      gld_lds16(Bt + (size_t)(n0 + r) * ldb + k0 + lc8 * 8, lB + ch * 512);
    }
    __syncthreads();
#pragma unroll
    for (int ks = 0; ks < 2; ks++){
      bf16x8 af[4], bfr[4];
#pragma unroll
      for (int mi = 0; mi < 4; mi++){
        int row = wr * 64 + mi * 16 + c;
        af[mi] = *(const bf16x8*)((const char*)lA + row * 128 + ks * 64 + g * 16);
      }
#pragma unroll
      for (int ni = 0; ni < 4; ni++){
        int row = wc * 64 + ni * 16 + c;
        bfr[ni] = *(const bf16x8*)((const char*)lB + row * 128 + ks * 64 + g * 16);
      }
#pragma unroll
      for (int mi = 0; mi < 4; mi++)
#pragma unroll
        for (int ni = 0; ni < 4; ni++)
          acc[mi][ni] = __builtin_amdgcn_mfma_f32_16x16x32_bf16(af[mi], bfr[ni], acc[mi][ni], 0, 0, 0);
    }
    __syncthreads();
  }
}

// ---------- Wo0 split-K=2 (m97 loop, f32 partials) ----------
__global__ __launch_bounds__(256) void gemm_sk2(const u16* __restrict__ A,
                                                const u16* __restrict__ Bt,
                                                float* __restrict__ pout){
  __shared__ u16 lA[128 * 64];
  __shared__ u16 lB[128 * 64];
  const int t = threadIdx.x, w = t >> 6, l = t & 63;
  const int m0 = blockIdx.y * 128, n0 = blockIdx.x * 128;
  const int wr = w >> 1, wc = w & 1;
  const int c = l & 15, g = l >> 4;
  const int kbeg = blockIdx.z * 512;

  f32x4 acc[4][4];
#pragma unroll
  for (int i = 0; i < 4; i++)
#pragma unroll
    for (int j = 0; j < 4; j++) acc[i][j] = (f32x4){0.f, 0.f, 0.f, 0.f};

  gemm_mainloop(A, Bt, 1024, 1024, kbeg, kbeg + 512, m0, n0, lA, lB, acc);

  float* po = pout + ((size_t)blockIdx.z << 22);
#pragma unroll
  for (int ni = 0; ni < 4; ni++){
    int n = n0 + wc * 64 + ni * 16 + c;
#pragma unroll
    for (int mi = 0; mi < 4; mi++){
      int row0 = m0 + wr * 64 + mi * 16 + 4 * g;
#pragma unroll
      for (int r = 0; r < 4; r++)
        po[(size_t)(row0 + r) * 1024 + n] = acc[mi][ni][r];
    }
  }
}

// ---------- 256x256 8-phase main loop (T2+T3+T4+T5), BK=64, 8 waves ----------
static __device__ __forceinline__ void loop8p(const u16* __restrict__ A,
                                              const u16* __restrict__ Bt,
                                              int lda, int ldb, int kbeg, int NT,
                                              int m0, int n0,
                                              u16 (*sA)[2][8192], u16 (*sB)[2][8192],
                                              f32x4 acc[8][4]){
  const int t = threadIdx.x, w = t >> 6, l = t & 63;
  const int wr = w >> 2, wc = w & 3;
  const int c = l & 15, g = l >> 4;
  const int sr = t >> 3, scb = (t & 7) << 4;

  auto stA = [&](int d, int h, int T){
#pragma unroll
    for (int i = 0; i < 2; i++){
      int row = i * 64 + sr;
      int Lb  = scb ^ ((row & 7) << 4);
      gld_lds16(A + (size_t)(m0 + h * 128 + row) * lda + kbeg + T * 64 + (Lb >> 1),
                (char*)&sA[d][h][0] + i * 8192 + t * 16);
    }
  };
  auto stB = [&](int d, int h, int T){
#pragma unroll
    for (int i = 0; i < 2; i++){
      int row = i * 64 + sr;
      int Lb  = scb ^ ((row & 7) << 4);
      gld_lds16(Bt + (size_t)(n0 + h * 128 + row) * ldb + kbeg + T * 64 + (Lb >> 1),
                (char*)&sB[d][h][0] + i * 8192 + t * 16);
    }
  };

  // prologue: B0(0),B1(0),A0(0),A1(0),B0(1),B1(1)
  stB(0, 0, 0); stB(0, 1, 0); stA(0, 0, 0); stA(0, 1, 0);
  stB(1, 0, 1); stB(1, 1, 1);

  bf16x8 bfr[4][2];
  for (int T = 0; T < NT; ++T){
    const int d = T & 1;
    const char* pa = (const char*)&sA[d][wr][0];
    const char* pb = (const char*)&sB[d][wc >> 1][0];
#pragma unroll
    for (int q = 0; q < 4; ++q){
      if (q == 0){
        if (T + 1 < NT) asm volatile("s_waitcnt vmcnt(4)" ::: "memory");
        else            asm volatile("s_waitcnt vmcnt(0)" ::: "memory");
        asm volatile("" ::: "memory");
        __builtin_amdgcn_s_barrier();
        asm volatile("" ::: "memory");
#pragma unroll
        for (int nf = 0; nf < 4; ++nf){
          int lr = (wc & 1) * 64 + nf * 16 + c;
#pragma unroll
          for (int ks = 0; ks < 2; ++ks)
            bfr[nf][ks] = *(const bf16x8*)(pb + lr * 128 + ((ks * 64 + g * 16) ^ ((lr & 7) << 4)));
        }
      }
      bf16x8 af[2][2];
#pragma unroll
      for (int mi = 0; mi < 2; ++mi){
        int lr = (q * 2 + mi) * 16 + c;
#pragma unroll
        for (int ks = 0; ks < 2; ++ks)
          af[mi][ks] = *(const bf16x8*)(pa + lr * 128 + ((ks * 64 + g * 16) ^ ((lr & 7) << 4)));
      }
      if      (q == 0){ if (T + 1 < NT) stA(d ^ 1, 0, T + 1); }
      else if (q == 1){ if (T + 1 < NT) stA(d ^ 1, 1, T + 1); }
      else if (q == 2){ if (T + 2 < NT) stB(d, 0, T + 2); }
      else            { if (T + 2 < NT) stB(d, 1, T + 2); }
      __builtin_amdgcn_s_setprio(1);
#pragma unroll
      for (int mi = 0; mi < 2; ++mi)
#pragma unroll
        for (int nf = 0; nf < 4; ++nf)
#pragma unroll
          for (int ks = 0; ks < 2; ++ks)
            acc[q * 2 + mi][nf] =
              __builtin_amdgcn_mfma_f32_16x16x32_bf16(af[mi][ks], bfr[nf][ks], acc[q * 2 + mi][nf], 0, 0, 0);
      __builtin_amdgcn_s_setprio(0);
      asm volatile("" ::: "memory");
      __builtin_amdgcn_s_barrier();
      asm volatile("" ::: "memory");
    }
  }
}

// ---------- 8-phase GEMM with XCD-rect swizzle ----------
template<int EPI>
__global__ __launch_bounds__(512, 2) void gemm8p(const u16* __restrict__ A,
                                                 const u16* __restrict__ Bt,
                                                 const float* __restrict__ bias,
                                                 void* __restrict__ outp,
                                                 int lda, int ldb, int ldout,
                                                 int ksz, int NT){
  __shared__ u16 sA[2][2][8192];
  __shared__ u16 sB[2][2][8192];
  const int t = threadIdx.x, w = t >> 6, l = t & 63;
  const int wr = w >> 2, wc = w & 3;
  const int c = l & 15, g = l >> 4;

  int m0, n0, zidx;
  if (EPI == 0){
    int lid = blockIdx.x + (blockIdx.y << 4);
    int xcd = lid & 7, slot = lid >> 3;
    int bx = ((xcd & 1) << 3) + (slot & 7);
    int by = ((xcd >> 1) << 2) + (slot >> 3);
    m0 = by * 256; n0 = bx * 256; zidx = 0;
  } else {
    int lid = blockIdx.x + (blockIdx.y << 2) + (blockIdx.z << 6);
    int xcd = lid & 7, slot = lid >> 3;
    int bx = slot & 3, rest = slot >> 2;
    int by = (xcd << 1) + (rest & 1);
    zidx = rest >> 1;
    m0 = by * 256; n0 = bx * 256;
  }

  f32x4 acc[8][4];
#pragma unroll
  for (int i = 0; i < 8; i++)
#pragma unroll
    for (int j = 0; j < 4; j++) acc[i][j] = (f32x4){0.f, 0.f, 0.f, 0.f};

  loop8p(A, Bt, lda, ldb, zidx * ksz, NT, m0, n0, sA, sB, acc);

  if (EPI == 0){
    u16* out = (u16*)outp;
#pragma unroll
    for (int nf = 0; nf < 4; ++nf){
      int n = n0 + wc * 64 + nf * 16 + c;
      float bv = bias[n];
#pragma unroll
      for (int mf = 0; mf < 8; ++mf){
        int row0 = m0 + wr * 128 + mf * 16 + 4 * g;
#pragma unroll
        for (int r = 0; r < 4; ++r)
          out[(size_t)(row0 + r) * ldout + n] = f2b(fmaxf(acc[mf][nf][r] + bv, 0.f));
      }
    }
  } else {
    float* po = (float*)outp + ((size_t)zidx << 22);
#pragma unroll
    for (int nf = 0; nf < 4; ++nf){
      int n = n0 + wc * 64 + nf * 16 + c;
#pragma unroll
      for (int mf = 0; mf < 8; ++mf){
        int row0 = m0 + wr * 128 + mf * 16 + 4 * g;
#pragma unroll
        for (int r = 0; r < 4; ++r)
          po[(size_t)(row0 + r) * 1024 + n] = acc[mf][nf][r];
      }
    }
  }
}

// ---------- fused QKV (8-phase 256², grid 12x16, XCD 3x8 rect); V via LDS-transposed stores ----------
__global__ __launch_bounds__(512, 2) void gemm8p_qkv(const u16* __restrict__ Qb,
                                                     const u16* __restrict__ Kb,
                                                     const u16* __restrict__ Wq_t,
                                                     const u16* __restrict__ Wk_t,
                                                     const u16* __restrict__ Wv_t,
                                                     const float* __restrict__ bq,
                                                     const float* __restrict__ bk,
                                                     const float* __restrict__ bv,
                                                     u16* __restrict__ qb,
                                                     u16* __restrict__ kbf,
                                                     u16* __restrict__ vtb){
  __shared__ u16 sA[2][2][8192];
  __shared__ u16 sB[2][2][8192];
  int lid = blockIdx.x + blockIdx.y * 12;
  int xcd = lid & 7, slot = lid >> 3;
  int bx = (xcd & 3) * 3 + slot % 3;
  int by = ((xcd >> 2) << 3) + slot / 3;
  const int sel = bx >> 2;
  const u16* A    = sel ? Kb : Qb;
  const u16* Bt   = (sel == 0) ? Wq_t : (sel == 1) ? Wk_t : Wv_t;
  const float* bi = (sel == 0) ? bq   : (sel == 1) ? bk   : bv;
  const int t = threadIdx.x, w = t >> 6, l = t & 63;
  const int wr = w >> 2, wc = w & 3;
  const int c = l & 15, g = l >> 4;
  const int m0 = by * 256, n0 = (bx & 3) * 256;

  f32x4 acc[8][4];
#pragma unroll
  for (int i = 0; i < 8; i++)
#pragma unroll
    for (int j = 0; j < 4; j++) acc[i][j] = (f32x4){0.f, 0.f, 0.f, 0.f};

  loop8p(A, Bt, 1024, 1024, 0, 16, m0, n0, sA, sB, acc);

  if (sel == 2){
    // V: per-wave LDS transpose (sA/sB dead after final barrier), then coalesced
    // 16B stores of vt[b][dh][key] row chunks (256B contiguous per row).
    u16* sl = (w < 4) ? (&sA[0][0][0] + w * 8192) : (&sB[0][0][0] + (w - 4) * 8192);
#pragma unroll
    for (int nf = 0; nf < 4; ++nf){
      int n = n0 + wc * 64 + nf * 16 + c;
      float bv_ = bi[n];
#pragma unroll
      for (int mf = 0; mf < 8; ++mf){
        bf16x4 pk;
#pragma unroll
        for (int r = 0; r < 4; ++r) pk[r] = (short)f2b(acc[mf][nf][r] + bv_);
        *(bf16x4*)(sl + (nf * 16 + c) * 128 + mf * 16 + 4 * g) = pk;   // [n-local][key-local]
      }
    }
    asm volatile("s_waitcnt lgkmcnt(0)" ::: "memory");
    __builtin_amdgcn_sched_barrier(0);
    const int mg = m0 + wr * 128;               // 128-aligned -> single 1024-block
    const int bb = mg >> 10, kb0 = mg & 1023;
    u16* vbase = vtb + ((size_t)bb << 20) + kb0;
#pragma unroll
    for (int j = 0; j < 16; ++j){
      int nl  = (l >> 4) + j * 4;               // 0..63
      int kl  = (l & 15) * 8;                   // 0..120
      bf16x8 v = *(const bf16x8*)(sl + nl * 128 + kl);
      *(bf16x8*)(vbase + (size_t)(n0 + wc * 64 + nl) * 1024 + kl) = v;
    }
  } else {
    u16* out = sel ? kbf : qb;
#pragma unroll
    for (int nf = 0; nf < 4; ++nf){
      int n = n0 + wc * 64 + nf * 16 + c;
      float bv_ = bi[n];
#pragma unroll
      for (int mf = 0; mf < 8; ++mf){
        int row0 = m0 + wr * 128 + mf * 16 + 4 * g;
#pragma unroll
        for (int r = 0; r < 4; ++r)
          out[(size_t)(row0 + r) * 1024 + n] = f2b(acc[mf][nf][r] + bv_);
      }
    }
  }
}

// ---------- combine 2 partials + bias + residual, then LayerNorm -> bf16 ----------
__global__ __launch_bounds__(256) void comb_ln0(const float* __restrict__ pp,
                                                const float* __restrict__ bias,
                                                const u16* __restrict__ res,
                                                const float* __restrict__ gw,
                                                const float* __restrict__ bw,
                                                u16* __restrict__ out){
  const int row = blockIdx.x, t = threadIdx.x, w = t >> 6, l = t & 63;
  const size_t i4 = (size_t)row * 1024 + t * 4;
  f32x4 a = *(const f32x4*)(pp + i4);
  f32x4 b = *(const f32x4*)(pp + (1ull << 22) + i4);
  bf16x4 rv = *(const bf16x4*)(res + i4);
  float xs[4], s = 0.f, sq = 0.f;
#pragma unroll
  for (int j = 0; j < 4; j++){
    xs[j] = a[j] + b[j] + bias[t * 4 + j] + b2f((u16)rv[j]);
    s += xs[j]; sq += xs[j] * xs[j];
  }
#pragma unroll
  for (int o = 32; o; o >>= 1){ s += __shfl_xor(s, o); sq += __shfl_xor(sq, o); }
  __shared__ float rs[4], rq[4];
  if (l == 0){ rs[w] = s; rq[w] = sq; }
  __syncthreads();
  s  = rs[0] + rs[1] + rs[2] + rs[3];
  sq = rq[0] + rq[1] + rq[2] + rq[3];
  const float mu   = s * (1.f / 1024.f);
  const float var  = sq * (1.f / 1024.f) - mu * mu;
  const float rstd = rsqrtf(var + 1e-5f);
  bf16x4 o;
#pragma unroll
  for (int j = 0; j < 4; j++) o[j] = (short)f2b((xs[j]-mu)*rstd*gw[t*4+j] + bw[t*4+j]);
  *(bf16x4*)(out + i4) = o;
}

// ---------- combine 4 partials + bias + residual, then LayerNorm -> f32 (d_out) ----------
__global__ __launch_bounds__(256) void comb_ln1(const float* __restrict__ pp,
                                                const float* __restrict__ bias,
                                                const u16* __restrict__ res,
                                                const float* __restrict__ gw,
                                                const float* __restrict__ bw,
                                                float* __restrict__ out){
  const int row = blockIdx.x, t = threadIdx.x, w = t >> 6, l = t & 63;
  const size_t i4 = (size_t)row * 1024 + t * 4;
  f32x4 a = *(const f32x4*)(pp + i4);
#pragma unroll
  for (int z = 1; z < 4; z++){
    f32x4 p = *(const f32x4*)(pp + ((size_t)z << 22) + i4);
    a[0] += p[0]; a[1] += p[1]; a[2] += p[2]; a[3] += p[3];
  }
  bf16x4 rv = *(const bf16x4*)(res + i4);
  float xs[4], s = 0.f, sq = 0.f;
#pragma unroll
  for (int j = 0; j < 4; j++){
    xs[j] = a[j] + bias[t * 4 + j] + b2f((u16)rv[j]);
    s += xs[j]; sq += xs[j] * xs[j];
  }
#pragma unroll
  for (int o = 32; o; o >>= 1){ s += __shfl_xor(s, o); sq += __shfl_xor(sq, o); }
  __shared__ float rs[4], rq[4];
  if (l == 0){ rs[w] = s; rq[w] = sq; }
  __syncthreads();
  s  = rs[0] + rs[1] + rs[2] + rs[3];
  sq = rq[0] + rq[1] + rq[2] + rq[3];
  const float mu   = s * (1.f / 1024.f);
  const float var  = sq * (1.f / 1024.f) - mu * mu;
  const float rstd = rsqrtf(var + 1e-5f);
  float4 o4;
  o4.x = (xs[0]-mu)*rstd*gw[t*4+0] + bw[t*4+0];
  o4.y = (xs[1]-mu)*rstd*gw[t*4+1] + bw[t*4+1];
  o4.z = (xs[2]-mu)*rstd*gw[t*4+2] + bw[t*4+2];
  o4.w = (xs[3]-mu)*rstd*gw[t*4+3] + bw[t*4+3];
  *((float4*)out + (size_t)row * 256 + t) = o4;
}

// ---------- fused masked attention: counted-vmcnt + depth-2 mask prefetch + XCD cluster ----------
#define ATTN_STEP(IT, CUR, MC) do{                                              \
  if ((IT) < 15) asm volatile("s_waitcnt vmcnt(4)" ::: "memory");               \
  else           asm volatile("s_waitcnt vmcnt(0)" ::: "memory");               \
  __builtin_amdgcn_s_barrier();                                                 \
  asm volatile("" ::: "memory");                                                \
  if ((IT) < 15) stage((CUR) ^ 1, ((IT) + 1) * 64);                             \
  asm volatile("" ::: "memory");                                                \
  const char* kt = (const char*)sK[(CUR)];                                      \
  f32x4 st[4];                                                                  \
  _Pragma("unroll")                                                             \
  for (int nf = 0; nf < 4; nf++){                                               \
    const char* kr = kt + (nf * 16 + c) * 128;                                  \
    bf16x8 ak0 = *(const bf16x8*)(kr + ((g * 16) ^ sw));                        \
    bf16x8 ak1 = *(const bf16x8*)(kr + ((64 + g * 16) ^ sw));                   \
    f32x4 z = (f32x4){0.f, 0.f, 0.f, 0.f};                                      \
    z = __builtin_amdgcn_mfma_f32_16x16x32_bf16(ak0, bq0, z, 0, 0, 0);          \
    z = __builtin_amdgcn_mfma_f32_16x16x32_bf16(ak1, bq1, z, 0, 0, 0);          \
    st[nf] = z;                                                                 \
  }                                                                             \
  float tmax = -INFINITY;                                                       \
  _Pragma("unroll")                                                             \
  for (int nf = 0; nf < 4; nf++)                                                \
    _Pragma("unroll")                                                           \
    for (int r = 0; r < 4; r++){                                                \
      float v = st[nf][r] * 0.03125f + MC[nf][r];                               \
      st[nf][r] = v; tmax = fmaxf(tmax, v);                                     \
    }                                                                           \
  if ((IT) < 14){                                                               \
    _Pragma("unroll")                                                           \
    for (int nf = 0; nf < 4; nf++)                                              \
      MC[nf] = *(const f32x4*)(mbase + ((IT) + 2) * 64 + nf * 16 + g * 4);      \
  }                                                                             \
  tmax = fmaxf(tmax, __shfl_xor(tmax, 16));                                     \
  tmax = fmaxf(tmax, __shfl_xor(tmax, 32));                                     \
  float mnew  = fmaxf(m, tmax);                                                 \
  float alpha = __expf(m - mnew);                                               \
  float rsum = 0.f;                                                             \
  bf16x4 pb[4];                                                                 \
  _Pragma("unroll")                                                             \
  for (int nf = 0; nf < 4; nf++)                                                \
    _Pragma("unroll")                                                           \
    for (int r = 0; r < 4; r++){                                                \
      float p = __expf(st[nf][r] - mnew);                                       \
      rsum += p;                                                                \
      pb[nf][r] = (short)f2b(p);                                                \
    }                                                                           \
  rsum += __shfl_xor(rsum, 16); rsum += __shfl_xor(rsum, 32);                   \
  lsum = lsum * alpha + rsum; m = mnew;                                         \
  _Pragma("unroll")                                                             \
  for (int f = 0; f < 4; f++){                                                  \
    acc[f][0] *= alpha; acc[f][1] *= alpha;                                     \
    acc[f][2] *= alpha; acc[f][3] *= alpha;                                     \
  }                                                                             \
  const char* vtc = (const char*)sV[(CUR)];                                     \
  __builtin_amdgcn_s_setprio(1);                                                \
  _Pragma("unroll")                                                             \
  for (int f = 0; f < 4; f++){                                                  \
    const char* vr = vtc + (f * 16 + c) * 128;                                  \
    _Pragma("unroll")                                                           \
    for (int nf = 0; nf < 4; nf++){                                             \
      bf16x4 av = *(const bf16x4*)(vr + ((nf * 32 + g * 8) ^ sw));              \
      acc[f] = __builtin_amdgcn_mfma_f32_16x16x16bf16_1k(av, pb[nf], acc[f], 0, 0, 0); \
    }                                                                           \
  }                                                                             \
  __builtin_amdgcn_s_setprio(0);                                                \
}while(0)

__global__ __launch_bounds__(256, 4) void attn_k(const u16* __restrict__ qb,
                                                 const u16* __restrict__ kb,
                                                 const u16* __restrict__ vt,
                                                 const float* __restrict__ mask,
                                                 u16* __restrict__ ob){
  __shared__ u16 sK[2][4096];   // [key][dh], row stride 128B, XOR-swizzled
  __shared__ u16 sV[2][4096];   // [dh][key], row stride 128B, XOR-swizzled

  const int t = threadIdx.x, w = t >> 6, l = t & 63;
  const int c = l & 15, g = l >> 4;
  const int lid  = blockIdx.x + (blockIdx.y << 4) + (blockIdx.z << 8);
  const int xcd  = lid & 7, slot = lid >> 3;
  const int grp  = xcd + ((slot >> 4) << 3);
  const int q0   = (slot & 15) * 64;
  const int h    = grp & 15, b = grp >> 4;
  const int qrow = q0 + w * 16 + c;
  const size_t qoff = ((size_t)(b * 1024 + qrow)) * 1024 + h * 64;
  const bf16x8 bq0 = *(const bf16x8*)(qb + qoff + g * 8);
  const bf16x8 bq1 = *(const bf16x8*)(qb + qoff + 32 + g * 8);
  const u16* kbase = kb + ((size_t)b * 1024) * 1024 + h * 64;
  const u16* vbase = vt + ((size_t)b << 20) + (size_t)(h * 64) * 1024;
  const float* mbase = mask + ((size_t)(h * 4 + b) * 1024 + qrow) * 1024;

  const int lr3 = l >> 3, lc3 = l & 7;
  const int ch0 = w * 2;

  auto stage = [&](int buf, int kv){
#pragma unroll
    for (int i = 0; i < 2; i++){
      int ch  = ch0 + i;
      int row = ch * 8 + lr3;
      int L   = (lc3 * 16) ^ ((row & 7) << 4);
      gld_lds16(kbase + (size_t)(kv + row) * 1024 + (L >> 1), &sK[buf][ch * 512]);
      gld_lds16(vbase + (size_t)row * 1024 + kv + (L >> 1),   &sV[buf][ch * 512]);
    }
  };

  float m = -INFINITY, lsum = 0.f;
  f32x4 acc[4];
#pragma unroll
  for (int f = 0; f < 4; f++) acc[f] = (f32x4){0.f, 0.f, 0.f, 0.f};

  stage(0, 0);
  asm volatile("" ::: "memory");
  f32x4 mA[4], mB[4];
#pragma unroll
  for (int nf = 0; nf < 4; nf++) mA[nf] = *(const f32x4*)(mbase + nf * 16 + g * 4);
  asm volatile("" ::: "memory");
#pragma unroll
  for (int nf = 0; nf < 4; nf++) mB[nf] = *(const f32x4*)(mbase + 64 + nf * 16 + g * 4);

  const int sw = (c & 7) << 4;
  for (int ii = 0; ii < 8; ++ii){
    ATTN_STEP(2 * ii,     0, mA);
    ATTN_STEP(2 * ii + 1, 1, mB);
  }

  // epilogue: O^T -> LDS (per-wave rows; final iter only read buf 1, sK[0] free)
  // then coalesced 16B row stores. Same-wave writes/reads only -> no barrier.
  const float inv = 1.f / lsum;
  u16* sO = &sK[0][0];                         // [qrow-local 64][dh 64]
#pragma unroll
  for (int f = 0; f < 4; f++){
    bf16x4 pk;
#pragma unroll
    for (int r = 0; r < 4; r++) pk[r] = (short)f2b(acc[f][r] * inv);
    *(bf16x4*)(sO + (w * 16 + c) * 64 + f * 16 + 4 * g) = pk;
  }
  asm volatile("s_waitcnt lgkmcnt(0)" ::: "memory");
  __builtin_amdgcn_sched_barrier(0);
  {
    int rl  = w * 16 + (l >> 2);               // own wave's rows only
    int d0  = (l & 3) * 16;                    // dh offset 0/16/32/48
    bf16x8 v0 = *(const bf16x8*)(sO + rl * 64 + d0);
    bf16x8 v1 = *(const bf16x8*)(sO + rl * 64 + d0 + 8);
    u16* dst = ob + ((size_t)(b * 1024 + q0 + rl)) * 1024 + h * 64 + d0;
    *(bf16x8*)(dst)     = v0;
    *(bf16x8*)(dst + 8) = v1;
  }
}

// ---------- launch ----------
extern "C" void kernel_launch(void* const* d_in, const int* in_sizes, int n_in,
                              void* d_out, int out_size, void* d_ws, size_t ws_size,
                              hipStream_t stream){
  const float* Q    = (const float*)d_in[0];
  const float* K    = (const float*)d_in[1];
  const float* mask = (const float*)d_in[2];
  const float* Wq   = (const float*)d_in[4];  const float* bq  = (const float*)d_in[5];
  const float* Wk   = (const float*)d_in[6];  const float* bk  = (const float*)d_in[7];
  const float* Wv   = (const float*)d_in[8];  const float* bv  = (const float*)d_in[9];
  const float* Wo0  = (const float*)d_in[10]; const float* bo0 = (const float*)d_in[11];
  const float* Wo   = (const float*)d_in[12]; const float* bo  = (const float*)d_in[13];
  const float* Wo2  = (const float*)d_in[14]; const float* bo2 = (const float*)d_in[15];
  const float* g0   = (const float*)d_in[16]; const float* be0 = (const float*)d_in[17];
  const float* g1   = (const float*)d_in[18]; const float* be1 = (const float*)d_in[19];

  uint8_t* W = (uint8_t*)d_ws;
  const size_t MB = 1024ull * 1024ull;
  u16* Wq_t  = (u16*)(W + 0);
  u16* Wk_t  = (u16*)(W + 2  * MB);
  u16* Wv_t  = (u16*)(W + 4  * MB);
  u16* Wo0_t = (u16*)(W + 6  * MB);
  u16* Wo_t  = (u16*)(W + 8  * MB);   // [4096][1024]
  u16* Wo2_t = (u16*)(W + 16 * MB);   // [1024][4096]
  u16* Qb    = (u16*)(W + 24 * MB);
  u16* Kb    = (u16*)(W + 32 * MB);
  u16* qb    = (u16*)(W + 40 * MB);
  u16* kbf   = (u16*)(W + 48 * MB);
  u16* vtb   = (u16*)(W + 56 * MB);
  u16* ob    = (u16*)(W + 24 * MB);   // reuse Qb
  u16* x1b   = (u16*)(W + 64 * MB);
  u16* hb    = (u16*)(W + 32 * MB);   // [4096][4096] bf16, spans dead Kb/qb/kbf/vtb
  float* pp  = (float*)(W + 72 * MB); // up to 4 x 16MB f32 partials (Wo0 uses 2, FF2 uses 4)

  prep<<<11264, 256, 0, stream>>>(Q, K, Qb, Kb, Wq, Wq_t, Wk, Wk_t, Wv, Wv_t,
                                  Wo0, Wo0_t, Wo, Wo_t, Wo2, Wo2_t);

  gemm8p_qkv<<<dim3(12, 16), 512, 0, stream>>>(Qb, Kb, Wq_t, Wk_t, Wv_t,
                                               bq, bk, bv, qb, kbf, vtb);

  attn_k<<<dim3(16, 16, 4), 256, 0, stream>>>(qb, kbf, vtb, mask, ob);

  gemm_sk2<<<dim3(8, 32, 2), 256, 0, stream>>>(ob, Wo0_t, pp);
  comb_ln0<<<4096, 256, 0, stream>>>(pp, bo0, qb, g0, be0, x1b);

  gemm8p<0><<<dim3(16, 16), 512, 0, stream>>>(x1b, Wo_t, bo, hb, 1024, 1024, 4096, 0, 16);
  gemm8p<1><<<dim3(4, 16, 4), 512, 0, stream>>>(hb, Wo2_t, nullptr, pp, 4096, 4096, 1024, 1024, 16);
  comb_ln1<<<4096, 256, 0, stream>>>(pp, bo2, x1b, g1, be1, (float*)d_out);
}

// Round 9
// 295.197 us; speedup vs baseline: 1.7534x; 1.0130x over previous
//
#include <hip/hip_runtime.h>
#include <hip/hip_bf16.h>

typedef unsigned short u16;
typedef __attribute__((ext_vector_type(4))) short bf16x4;
typedef __attribute__((ext_vector_type(8))) short bf16x8;
typedef __attribute__((ext_vector_type(4))) float f32x4;

// ---------- helpers ----------
static __device__ __forceinline__ u16 f2b(float f){
  union { float f; unsigned u; } v; v.f = f;
  unsigned r = v.u + 0x7fffu + ((v.u >> 16) & 1u);   // RNE
  return (u16)(r >> 16);
}
static __device__ __forceinline__ float b2f(u16 h){
  union { unsigned u; float f; } v; v.u = ((unsigned)h) << 16; return v.f;
}
static __device__ __forceinline__ void gld_lds16(const void* g, void* l){
  __builtin_amdgcn_global_load_lds((const __attribute__((address_space(1))) void*)g,
                                   (__attribute__((address_space(3))) void*)l, 16, 0, 0);
}

// ---------- fused prep: Q/K bf16 convert (compacted) + all 6 weight transposes ----------
__global__ __launch_bounds__(256) void prep(const float* __restrict__ Q,
                                            const float* __restrict__ K,
                                            u16* __restrict__ Qb, u16* __restrict__ Kb,
                                            const float* __restrict__ Wq, u16* __restrict__ Wq_t,
                                            const float* __restrict__ Wk, u16* __restrict__ Wk_t,
                                            const float* __restrict__ Wv, u16* __restrict__ Wv_t,
                                            const float* __restrict__ Wo0, u16* __restrict__ Wo0_t,
                                            const float* __restrict__ Wo, u16* __restrict__ Wo_t,
                                            const float* __restrict__ Wo2, u16* __restrict__ Wo2_t){
  __shared__ float tile[64][65];
  const int id = blockIdx.x, t = threadIdx.x;
  if (id < 8192){
    const float* src; u16* dst;
    if (id < 4096){
      src = Q + (size_t)id * 1024; dst = Qb + (size_t)id * 1024;
    } else {
      int r = id - 4096;
      size_t ir = (size_t)r + (size_t)(r >> 10) * 512;   // skip rows 1024..1535 per batch
      src = K + ir * 1024; dst = Kb + (size_t)r * 1024;
    }
    const float4 v = *(const float4*)(src + t * 4);
    bf16x4 o;
    o[0] = (short)f2b(v.x); o[1] = (short)f2b(v.y);
    o[2] = (short)f2b(v.z); o[3] = (short)f2b(v.w);
    *(bf16x4*)(dst + t * 4) = o;
    return;
  }
  int wid = id - 8192;
  const float* in; u16* out; int Kd, N, bx, by;
  if (wid < 1024){
    int sel = wid >> 8, local = wid & 255;
    bx = local & 15; by = local >> 4; Kd = 1024; N = 1024;
    in  = (sel == 0) ? Wq   : (sel == 1) ? Wk   : (sel == 2) ? Wv   : Wo0;
    out = (sel == 0) ? Wq_t : (sel == 1) ? Wk_t : (sel == 2) ? Wv_t : Wo0_t;
  } else if (wid < 2048){
    int local = wid - 1024; bx = local & 63; by = local >> 6; Kd = 1024; N = 4096;
    in = Wo; out = Wo_t;
  } else {
    int local = wid - 2048; bx = local & 15; by = local >> 4; Kd = 4096; N = 1024;
    in = Wo2; out = Wo2_t;
  }
  const int k0 = by * 64, n0 = bx * 64;
  const int tr = t >> 4, tc = t & 15;
#pragma unroll
  for (int i = 0; i < 4; i++){
    int r = tr + i * 16;
    float4 v = *(const float4*)(in + (size_t)(k0 + r) * N + n0 + tc * 4);
    tile[r][tc*4+0] = v.x; tile[r][tc*4+1] = v.y; tile[r][tc*4+2] = v.z; tile[r][tc*4+3] = v.w;
  }
  __syncthreads();
#pragma unroll
  for (int i = 0; i < 4; i++){
    int nr = tr + i * 16;
    bf16x4 pk;
#pragma unroll
    for (int j = 0; j < 4; j++) pk[j] = (short)f2b(tile[tc*4+j][nr]);
    *(bf16x4*)(out + (size_t)(n0 + nr) * Kd + k0 + tc * 4) = pk;
  }
}

// ---------- 256x256 8-phase main loop (T2+T3+T4+T5), BK=64, 8 waves ----------
static __device__ __forceinline__ void loop8p(const u16* __restrict__ A,
                                              const u16* __restrict__ Bt,
                                              int lda, int ldb, int kbeg, int NT,
                                              int m0, int n0,
                                              u16 (*sA)[2][8192], u16 (*sB)[2][8192],
                                              f32x4 acc[8][4]){
  const int t = threadIdx.x, w = t >> 6, l = t & 63;
  const int wr = w >> 2, wc = w & 3;
  const int c = l & 15, g = l >> 4;
  const int sr = t >> 3, scb = (t & 7) << 4;

  auto stA = [&](int d, int h, int T){
#pragma unroll
    for (int i = 0; i < 2; i++){
      int row = i * 64 + sr;
      int Lb  = scb ^ ((row & 7) << 4);
      gld_lds16(A + (size_t)(m0 + h * 128 + row) * lda + kbeg + T * 64 + (Lb >> 1),
                (char*)&sA[d][h][0] + i * 8192 + t * 16);
    }
  };
  auto stB = [&](int d, int h, int T){
#pragma unroll
    for (int i = 0; i < 2; i++){
      int row = i * 64 + sr;
      int Lb  = scb ^ ((row & 7) << 4);
      gld_lds16(Bt + (size_t)(n0 + h * 128 + row) * ldb + kbeg + T * 64 + (Lb >> 1),
                (char*)&sB[d][h][0] + i * 8192 + t * 16);
    }
  };

  // prologue: B0(0),B1(0),A0(0),A1(0),B0(1),B1(1)
  stB(0, 0, 0); stB(0, 1, 0); stA(0, 0, 0); stA(0, 1, 0);
  stB(1, 0, 1); stB(1, 1, 1);

  bf16x8 bfr[4][2];
  for (int T = 0; T < NT; ++T){
    const int d = T & 1;
    const char* pa = (const char*)&sA[d][wr][0];
    const char* pb = (const char*)&sB[d][wc >> 1][0];
#pragma unroll
    for (int q = 0; q < 4; ++q){
      if (q == 0){
        if (T + 1 < NT) asm volatile("s_waitcnt vmcnt(4)" ::: "memory");
        else            asm volatile("s_waitcnt vmcnt(0)" ::: "memory");
        asm volatile("" ::: "memory");
        __builtin_amdgcn_s_barrier();
        asm volatile("" ::: "memory");
#pragma unroll
        for (int nf = 0; nf < 4; ++nf){
          int lr = (wc & 1) * 64 + nf * 16 + c;
#pragma unroll
          for (int ks = 0; ks < 2; ++ks)
            bfr[nf][ks] = *(const bf16x8*)(pb + lr * 128 + ((ks * 64 + g * 16) ^ ((lr & 7) << 4)));
        }
      }
      bf16x8 af[2][2];
#pragma unroll
      for (int mi = 0; mi < 2; ++mi){
        int lr = (q * 2 + mi) * 16 + c;
#pragma unroll
        for (int ks = 0; ks < 2; ++ks)
          af[mi][ks] = *(const bf16x8*)(pa + lr * 128 + ((ks * 64 + g * 16) ^ ((lr & 7) << 4)));
      }
      if      (q == 0){ if (T + 1 < NT) stA(d ^ 1, 0, T + 1); }
      else if (q == 1){ if (T + 1 < NT) stA(d ^ 1, 1, T + 1); }
      else if (q == 2){ if (T + 2 < NT) stB(d, 0, T + 2); }
      else            { if (T + 2 < NT) stB(d, 1, T + 2); }
      __builtin_amdgcn_s_setprio(1);
#pragma unroll
      for (int mi = 0; mi < 2; ++mi)
#pragma unroll
        for (int nf = 0; nf < 4; ++nf)
#pragma unroll
          for (int ks = 0; ks < 2; ++ks)
            acc[q * 2 + mi][nf] =
              __builtin_amdgcn_mfma_f32_16x16x32_bf16(af[mi][ks], bfr[nf][ks], acc[q * 2 + mi][nf], 0, 0, 0);
      __builtin_amdgcn_s_setprio(0);
      asm volatile("" ::: "memory");
      __builtin_amdgcn_s_barrier();
      asm volatile("" ::: "memory");
    }
  }
}

// ---------- 8-phase GEMM with XCD-rect swizzle ----------
// EPI 0 (FF1, grid 16x16): bias+relu -> bf16. EPI 1 (grid 4x16x4): bf16 split-K partial.
template<int EPI>
__global__ __launch_bounds__(512, 2) void gemm8p(const u16* __restrict__ A,
                                                 const u16* __restrict__ Bt,
                                                 const float* __restrict__ bias,
                                                 void* __restrict__ outp,
                                                 int lda, int ldb, int ldout,
                                                 int ksz, int NT){
  __shared__ u16 sA[2][2][8192];
  __shared__ u16 sB[2][2][8192];
  const int t = threadIdx.x, w = t >> 6, l = t & 63;
  const int wr = w >> 2, wc = w & 3;
  const int c = l & 15, g = l >> 4;

  int m0, n0, zidx;
  if (EPI == 0){
    int lid = blockIdx.x + (blockIdx.y << 4);
    int xcd = lid & 7, slot = lid >> 3;
    int bx = ((xcd & 1) << 3) + (slot & 7);
    int by = ((xcd >> 1) << 2) + (slot >> 3);
    m0 = by * 256; n0 = bx * 256; zidx = 0;
  } else {
    int lid = blockIdx.x + (blockIdx.y << 2) + (blockIdx.z << 6);
    int xcd = lid & 7, slot = lid >> 3;
    int bx = slot & 3, rest = slot >> 2;
    int by = (xcd << 1) + (rest & 1);
    zidx = rest >> 1;
    m0 = by * 256; n0 = bx * 256;
  }

  f32x4 acc[8][4];
#pragma unroll
  for (int i = 0; i < 8; i++)
#pragma unroll
    for (int j = 0; j < 4; j++) acc[i][j] = (f32x4){0.f, 0.f, 0.f, 0.f};

  loop8p(A, Bt, lda, ldb, zidx * ksz, NT, m0, n0, sA, sB, acc);

  if (EPI == 0){
    u16* out = (u16*)outp;
#pragma unroll
    for (int nf = 0; nf < 4; ++nf){
      int n = n0 + wc * 64 + nf * 16 + c;
      float bv = bias[n];
#pragma unroll
      for (int mf = 0; mf < 8; ++mf){
        int row0 = m0 + wr * 128 + mf * 16 + 4 * g;
#pragma unroll
        for (int r = 0; r < 4; ++r)
          out[(size_t)(row0 + r) * ldout + n] = f2b(fmaxf(acc[mf][nf][r] + bv, 0.f));
      }
    }
  } else {
    u16* po = (u16*)outp + (size_t)zidx * (4096ull * 1024ull);   // bf16 partial slice
#pragma unroll
    for (int nf = 0; nf < 4; ++nf){
      int n = n0 + wc * 64 + nf * 16 + c;
#pragma unroll
      for (int mf = 0; mf < 8; ++mf){
        int row0 = m0 + wr * 128 + mf * 16 + 4 * g;
#pragma unroll
        for (int r = 0; r < 4; ++r)
          po[(size_t)(row0 + r) * 1024 + n] = f2b(acc[mf][nf][r]);
      }
    }
  }
}

// ---------- fused QKV (8-phase 256², grid 12x16, XCD 3x8 rect); V via LDS-transposed stores ----------
__global__ __launch_bounds__(512, 2) void gemm8p_qkv(const u16* __restrict__ Qb,
                                                     const u16* __restrict__ Kb,
                                                     const u16* __restrict__ Wq_t,
                                                     const u16* __restrict__ Wk_t,
                                                     const u16* __restrict__ Wv_t,
                                                     const float* __restrict__ bq,
                                                     const float* __restrict__ bk,
                                                     const float* __restrict__ bv,
                                                     u16* __restrict__ qb,
                                                     u16* __restrict__ kbf,
                                                     u16* __restrict__ vtb){
  __shared__ u16 sA[2][2][8192];
  __shared__ u16 sB[2][2][8192];
  int lid = blockIdx.x + blockIdx.y * 12;
  int xcd = lid & 7, slot = lid >> 3;
  int bx = (xcd & 3) * 3 + slot % 3;
  int by = ((xcd >> 2) << 3) + slot / 3;
  const int sel = bx >> 2;
  const u16* A    = sel ? Kb : Qb;
  const u16* Bt   = (sel == 0) ? Wq_t : (sel == 1) ? Wk_t : Wv_t;
  const float* bi = (sel == 0) ? bq   : (sel == 1) ? bk   : bv;
  const int t = threadIdx.x, w = t >> 6, l = t & 63;
  const int wr = w >> 2, wc = w & 3;
  const int c = l & 15, g = l >> 4;
  const int m0 = by * 256, n0 = (bx & 3) * 256;

  f32x4 acc[8][4];
#pragma unroll
  for (int i = 0; i < 8; i++)
#pragma unroll
    for (int j = 0; j < 4; j++) acc[i][j] = (f32x4){0.f, 0.f, 0.f, 0.f};

  loop8p(A, Bt, 1024, 1024, 0, 16, m0, n0, sA, sB, acc);

  if (sel == 2){
    // V: per-wave LDS transpose (sA/sB dead after final barrier), then coalesced stores
    u16* sl = (w < 4) ? (&sA[0][0][0] + w * 8192) : (&sB[0][0][0] + (w - 4) * 8192);
#pragma unroll
    for (int nf = 0; nf < 4; ++nf){
      int n = n0 + wc * 64 + nf * 16 + c;
      float bv_ = bi[n];
#pragma unroll
      for (int mf = 0; mf < 8; ++mf){
        bf16x4 pk;
#pragma unroll
        for (int r = 0; r < 4; ++r) pk[r] = (short)f2b(acc[mf][nf][r] + bv_);
        *(bf16x4*)(sl + (nf * 16 + c) * 128 + mf * 16 + 4 * g) = pk;
      }
    }
    asm volatile("s_waitcnt lgkmcnt(0)" ::: "memory");
    __builtin_amdgcn_sched_barrier(0);
    const int mg = m0 + wr * 128;
    const int bb = mg >> 10, kb0 = mg & 1023;
    u16* vbase = vtb + ((size_t)bb << 20) + kb0;
#pragma unroll
    for (int j = 0; j < 16; ++j){
      int nl  = (l >> 4) + j * 4;
      int kl  = (l & 15) * 8;
      bf16x8 v = *(const bf16x8*)(sl + nl * 128 + kl);
      *(bf16x8*)(vbase + (size_t)(n0 + wc * 64 + nl) * 1024 + kl) = v;
    }
  } else {
    u16* out = sel ? kbf : qb;
#pragma unroll
    for (int nf = 0; nf < 4; ++nf){
      int n = n0 + wc * 64 + nf * 16 + c;
      float bv_ = bi[n];
#pragma unroll
      for (int mf = 0; mf < 8; ++mf){
        int row0 = m0 + wr * 128 + mf * 16 + 4 * g;
#pragma unroll
        for (int r = 0; r < 4; ++r)
          out[(size_t)(row0 + r) * 1024 + n] = f2b(acc[mf][nf][r] + bv_);
      }
    }
  }
}

// ---------- combine NP bf16 partials + bias + residual, then LayerNorm ----------
template<int NP, int F32OUT>
__global__ __launch_bounds__(256) void comb_ln(const u16* __restrict__ pp,
                                               const float* __restrict__ bias,
                                               const u16* __restrict__ res,
                                               const float* __restrict__ gw,
                                               const float* __restrict__ bw,
                                               void* __restrict__ outp){
  const int row = blockIdx.x, t = threadIdx.x, w = t >> 6, l = t & 63;
  const size_t i4 = (size_t)row * 1024 + t * 4;
  bf16x4 rv = *(const bf16x4*)(res + i4);
  float xs[4];
#pragma unroll
  for (int j = 0; j < 4; j++) xs[j] = bias[t * 4 + j] + b2f((u16)rv[j]);
#pragma unroll
  for (int z = 0; z < NP; z++){
    bf16x4 p = *(const bf16x4*)(pp + (size_t)z * (4096ull * 1024ull) + i4);
#pragma unroll
    for (int j = 0; j < 4; j++) xs[j] += b2f((u16)p[j]);
  }
  float s = 0.f, sq = 0.f;
#pragma unroll
  for (int j = 0; j < 4; j++){ s += xs[j]; sq += xs[j] * xs[j]; }
#pragma unroll
  for (int o = 32; o; o >>= 1){ s += __shfl_xor(s, o); sq += __shfl_xor(sq, o); }
  __shared__ float rs[4], rq[4];
  if (l == 0){ rs[w] = s; rq[w] = sq; }
  __syncthreads();
  s  = rs[0] + rs[1] + rs[2] + rs[3];
  sq = rq[0] + rq[1] + rq[2] + rq[3];
  const float mu   = s * (1.f / 1024.f);
  const float var  = sq * (1.f / 1024.f) - mu * mu;
  const float rstd = rsqrtf(var + 1e-5f);
  if (F32OUT){
    float4 o4;
    o4.x = (xs[0]-mu)*rstd*gw[t*4+0] + bw[t*4+0];
    o4.y = (xs[1]-mu)*rstd*gw[t*4+1] + bw[t*4+1];
    o4.z = (xs[2]-mu)*rstd*gw[t*4+2] + bw[t*4+2];
    o4.w = (xs[3]-mu)*rstd*gw[t*4+3] + bw[t*4+3];
    *((float4*)outp + (size_t)row * 256 + t) = o4;
  } else {
    bf16x4 o;
#pragma unroll
    for (int j = 0; j < 4; j++) o[j] = (short)f2b((xs[j]-mu)*rstd*gw[t*4+j] + bw[t*4+j]);
    *((bf16x4*)outp + (size_t)row * 256 + t) = o;
  }
}

// ---------- fused masked attention: counted-vmcnt + depth-2 mask prefetch + XCD cluster ----------
#define ATTN_STEP(IT, CUR, MC) do{                                              \
  if ((IT) < 15) asm volatile("s_waitcnt vmcnt(4)" ::: "memory");               \
  else           asm volatile("s_waitcnt vmcnt(0)" ::: "memory");               \
  __builtin_amdgcn_s_barrier();                                                 \
  asm volatile("" ::: "memory");                                                \
  if ((IT) < 15) stage((CUR) ^ 1, ((IT) + 1) * 64);                             \
  asm volatile("" ::: "memory");                                                \
  const char* kt = (const char*)sK[(CUR)];                                      \
  f32x4 st[4];                                                                  \
  _Pragma("unroll")                                                             \
  for (int nf = 0; nf < 4; nf++){                                               \
    const char* kr = kt + (nf * 16 + c) * 128;                                  \
    bf16x8 ak0 = *(const bf16x8*)(kr + ((g * 16) ^ sw));                        \
    bf16x8 ak1 = *(const bf16x8*)(kr + ((64 + g * 16) ^ sw));                   \
    f32x4 z = (f32x4){0.f, 0.f, 0.f, 0.f};                                      \
    z = __builtin_amdgcn_mfma_f32_16x16x32_bf16(ak0, bq0, z, 0, 0, 0);          \
    z = __builtin_amdgcn_mfma_f32_16x16x32_bf16(ak1, bq1, z, 0, 0, 0);          \
    st[nf] = z;                                                                 \
  }                                                                             \
  float tmax = -INFINITY;                                                       \
  _Pragma("unroll")                                                             \
  for (int nf = 0; nf < 4; nf++)                                                \
    _Pragma("unroll")                                                           \
    for (int r = 0; r < 4; r++){                                                \
      float v = st[nf][r] * 0.03125f + MC[nf][r];                               \
      st[nf][r] = v; tmax = fmaxf(tmax, v);                                     \
    }                                                                           \
  if ((IT) < 14){                                                               \
    _Pragma("unroll")                                                           \
    for (int nf = 0; nf < 4; nf++)                                              \
      MC[nf] = *(const f32x4*)(mbase + ((IT) + 2) * 64 + nf * 16 + g * 4);      \
  }                                                                             \
  tmax = fmaxf(tmax, __shfl_xor(tmax, 16));                                     \
  tmax = fmaxf(tmax, __shfl_xor(tmax, 32));                                     \
  float mnew  = fmaxf(m, tmax);                                                 \
  float alpha = __expf(m - mnew);                                               \
  float rsum = 0.f;                                                             \
  bf16x4 pb[4];                                                                 \
  _Pragma("unroll")                                                             \
  for (int nf = 0; nf < 4; nf++)                                                \
    _Pragma("unroll")                                                           \
    for (int r = 0; r < 4; r++){                                                \
      float p = __expf(st[nf][r] - mnew);                                       \
      rsum += p;                                                                \
      pb[nf][r] = (short)f2b(p);                                                \
    }                                                                           \
  rsum += __shfl_xor(rsum, 16); rsum += __shfl_xor(rsum, 32);                   \
  lsum = lsum * alpha + rsum; m = mnew;                                         \
  _Pragma("unroll")                                                             \
  for (int f = 0; f < 4; f++){                                                  \
    acc[f][0] *= alpha; acc[f][1] *= alpha;                                     \
    acc[f][2] *= alpha; acc[f][3] *= alpha;                                     \
  }                                                                             \
  const char* vtc = (const char*)sV[(CUR)];                                     \
  __builtin_amdgcn_s_setprio(1);                                                \
  _Pragma("unroll")                                                             \
  for (int f = 0; f < 4; f++){                                                  \
    const char* vr = vtc + (f * 16 + c) * 128;                                  \
    _Pragma("unroll")                                                           \
    for (int nf = 0; nf < 4; nf++){                                             \
      bf16x4 av = *(const bf16x4*)(vr + ((nf * 32 + g * 8) ^ sw));              \
      acc[f] = __builtin_amdgcn_mfma_f32_16x16x16bf16_1k(av, pb[nf], acc[f], 0, 0, 0); \
    }                                                                           \
  }                                                                             \
  __builtin_amdgcn_s_setprio(0);                                                \
}while(0)

__global__ __launch_bounds__(256, 4) void attn_k(const u16* __restrict__ qb,
                                                 const u16* __restrict__ kb,
                                                 const u16* __restrict__ vt,
                                                 const float* __restrict__ mask,
                                                 u16* __restrict__ ob){
  __shared__ u16 sK[2][4096];   // [key][dh], row stride 128B, XOR-swizzled
  __shared__ u16 sV[2][4096];   // [dh][key], row stride 128B, XOR-swizzled

  const int t = threadIdx.x, w = t >> 6, l = t & 63;
  const int c = l & 15, g = l >> 4;
  const int lid  = blockIdx.x + (blockIdx.y << 4) + (blockIdx.z << 8);
  const int xcd  = lid & 7, slot = lid >> 3;
  const int grp  = xcd + ((slot >> 4) << 3);
  const int q0   = (slot & 15) * 64;
  const int h    = grp & 15, b = grp >> 4;
  const int qrow = q0 + w * 16 + c;
  const size_t qoff = ((size_t)(b * 1024 + qrow)) * 1024 + h * 64;
  const bf16x8 bq0 = *(const bf16x8*)(qb + qoff + g * 8);
  const bf16x8 bq1 = *(const bf16x8*)(qb + qoff + 32 + g * 8);
  const u16* kbase = kb + ((size_t)b * 1024) * 1024 + h * 64;
  const u16* vbase = vt + ((size_t)b << 20) + (size_t)(h * 64) * 1024;
  const float* mbase = mask + ((size_t)(h * 4 + b) * 1024 + qrow) * 1024;

  const int lr3 = l >> 3, lc3 = l & 7;
  const int ch0 = w * 2;

  auto stage = [&](int buf, int kv){
#pragma unroll
    for (int i = 0; i < 2; i++){
      int ch  = ch0 + i;
      int row = ch * 8 + lr3;
      int L   = (lc3 * 16) ^ ((row & 7) << 4);
      gld_lds16(kbase + (size_t)(kv + row) * 1024 + (L >> 1), &sK[buf][ch * 512]);
      gld_lds16(vbase + (size_t)row * 1024 + kv + (L >> 1),   &sV[buf][ch * 512]);
    }
  };

  float m = -INFINITY, lsum = 0.f;
  f32x4 acc[4];
#pragma unroll
  for (int f = 0; f < 4; f++) acc[f] = (f32x4){0.f, 0.f, 0.f, 0.f};

  stage(0, 0);
  asm volatile("" ::: "memory");
  f32x4 mA[4], mB[4];
#pragma unroll
  for (int nf = 0; nf < 4; nf++) mA[nf] = *(const f32x4*)(mbase + nf * 16 + g * 4);
  asm volatile("" ::: "memory");
#pragma unroll
  for (int nf = 0; nf < 4; nf++) mB[nf] = *(const f32x4*)(mbase + 64 + nf * 16 + g * 4);

  const int sw = (c & 7) << 4;
  for (int ii = 0; ii < 8; ++ii){
    ATTN_STEP(2 * ii,     0, mA);
    ATTN_STEP(2 * ii + 1, 1, mB);
  }

  // epilogue: O^T -> LDS (per-wave rows), then coalesced 16B row stores
  const float inv = 1.f / lsum;
  u16* sO = &sK[0][0];
#pragma unroll
  for (int f = 0; f < 4; f++){
    bf16x4 pk;
#pragma unroll
    for (int r = 0; r < 4; r++) pk[r] = (short)f2b(acc[f][r] * inv);
    *(bf16x4*)(sO + (w * 16 + c) * 64 + f * 16 + 4 * g) = pk;
  }
  asm volatile("s_waitcnt lgkmcnt(0)" ::: "memory");
  __builtin_amdgcn_sched_barrier(0);
  {
    int rl  = w * 16 + (l >> 2);
    int d0  = (l & 3) * 16;
    bf16x8 v0 = *(const bf16x8*)(sO + rl * 64 + d0);
    bf16x8 v1 = *(const bf16x8*)(sO + rl * 64 + d0 + 8);
    u16* dst = ob + ((size_t)(b * 1024 + q0 + rl)) * 1024 + h * 64 + d0;
    *(bf16x8*)(dst)     = v0;
    *(bf16x8*)(dst + 8) = v1;
  }
}

// ---------- launch ----------
extern "C" void kernel_launch(void* const* d_in, const int* in_sizes, int n_in,
                              void* d_out, int out_size, void* d_ws, size_t ws_size,
                              hipStream_t stream){
  const float* Q    = (const float*)d_in[0];
  const float* K    = (const float*)d_in[1];
  const float* mask = (const float*)d_in[2];
  const float* Wq   = (const float*)d_in[4];  const float* bq  = (const float*)d_in[5];
  const float* Wk   = (const float*)d_in[6];  const float* bk  = (const float*)d_in[7];
  const float* Wv   = (const float*)d_in[8];  const float* bv  = (const float*)d_in[9];
  const float* Wo0  = (const float*)d_in[10]; const float* bo0 = (const float*)d_in[11];
  const float* Wo   = (const float*)d_in[12]; const float* bo  = (const float*)d_in[13];
  const float* Wo2  = (const float*)d_in[14]; const float* bo2 = (const float*)d_in[15];
  const float* g0   = (const float*)d_in[16]; const float* be0 = (const float*)d_in[17];
  const float* g1   = (const float*)d_in[18]; const float* be1 = (const float*)d_in[19];

  uint8_t* W = (uint8_t*)d_ws;
  const size_t MB = 1024ull * 1024ull;
  u16* Wq_t  = (u16*)(W + 0);
  u16* Wk_t  = (u16*)(W + 2  * MB);
  u16* Wv_t  = (u16*)(W + 4  * MB);
  u16* Wo0_t = (u16*)(W + 6  * MB);
  u16* Wo_t  = (u16*)(W + 8  * MB);   // [4096][1024]
  u16* Wo2_t = (u16*)(W + 16 * MB);   // [1024][4096]
  u16* Qb    = (u16*)(W + 24 * MB);
  u16* Kb    = (u16*)(W + 32 * MB);
  u16* qb    = (u16*)(W + 40 * MB);
  u16* kbf   = (u16*)(W + 48 * MB);
  u16* vtb   = (u16*)(W + 56 * MB);
  u16* ob    = (u16*)(W + 24 * MB);   // reuse Qb
  u16* x1b   = (u16*)(W + 64 * MB);
  u16* hb    = (u16*)(W + 32 * MB);   // [4096][4096] bf16, spans dead Kb/qb/kbf/vtb
  u16* ppb   = (u16*)(W + 72 * MB);   // 4 x 8MB bf16 split-K partials

  prep<<<11264, 256, 0, stream>>>(Q, K, Qb, Kb, Wq, Wq_t, Wk, Wk_t, Wv, Wv_t,
                                  Wo0, Wo0_t, Wo, Wo_t, Wo2, Wo2_t);

  gemm8p_qkv<<<dim3(12, 16), 512, 0, stream>>>(Qb, Kb, Wq_t, Wk_t, Wv_t,
                                               bq, bk, bv, qb, kbf, vtb);

  attn_k<<<dim3(16, 16, 4), 256, 0, stream>>>(qb, kbf, vtb, mask, ob);

  // output proj: 8-phase split-K=4 (NT=4), bf16 partials -> fused combine+LN0
  gemm8p<1><<<dim3(4, 16, 4), 512, 0, stream>>>(ob, Wo0_t, nullptr, ppb, 1024, 1024, 1024, 256, 4);
  comb_ln<4, 0><<<4096, 256, 0, stream>>>(ppb, bo0, qb, g0, be0, x1b);

  // FFN: FF1 (8-phase, relu) -> FF2 (8-phase, split-K=4, bf16 partials) -> combine+LN1
  gemm8p<0><<<dim3(16, 16), 512, 0, stream>>>(x1b, Wo_t, bo, hb, 1024, 1024, 4096, 0, 16);
  gemm8p<1><<<dim3(4, 16, 4), 512, 0, stream>>>(hb, Wo2_t, nullptr, ppb, 4096, 4096, 1024, 1024, 16);
  comb_ln<4, 1><<<4096, 256, 0, stream>>>(ppb, bo2, x1b, g1, be1, d_out);
}

// Round 10
// 291.496 us; speedup vs baseline: 1.7757x; 1.0127x over previous
//
#include <hip/hip_runtime.h>
#include <hip/hip_bf16.h>

typedef unsigned short u16;
typedef __attribute__((ext_vector_type(4))) short bf16x4;
typedef __attribute__((ext_vector_type(8))) short bf16x8;
typedef __attribute__((ext_vector_type(4))) float f32x4;

// ---------- helpers ----------
static __device__ __forceinline__ u16 f2b(float f){
  union { float f; unsigned u; } v; v.f = f;
  unsigned r = v.u + 0x7fffu + ((v.u >> 16) & 1u);   // RNE
  return (u16)(r >> 16);
}
static __device__ __forceinline__ float b2f(u16 h){
  union { unsigned u; float f; } v; v.u = ((unsigned)h) << 16; return v.f;
}
static __device__ __forceinline__ void gld_lds16(const void* g, void* l){
  __builtin_amdgcn_global_load_lds((const __attribute__((address_space(1))) void*)g,
                                   (__attribute__((address_space(3))) void*)l, 16, 0, 0);
}

// ---------- fused prep: Q/K bf16 convert (compacted) + all 6 weight transposes ----------
__global__ __launch_bounds__(256) void prep(const float* __restrict__ Q,
                                            const float* __restrict__ K,
                                            u16* __restrict__ Qb, u16* __restrict__ Kb,
                                            const float* __restrict__ Wq, u16* __restrict__ Wq_t,
                                            const float* __restrict__ Wk, u16* __restrict__ Wk_t,
                                            const float* __restrict__ Wv, u16* __restrict__ Wv_t,
                                            const float* __restrict__ Wo0, u16* __restrict__ Wo0_t,
                                            const float* __restrict__ Wo, u16* __restrict__ Wo_t,
                                            const float* __restrict__ Wo2, u16* __restrict__ Wo2_t){
  __shared__ float tile[64][65];
  const int id = blockIdx.x, t = threadIdx.x;
  if (id < 8192){
    const float* src; u16* dst;
    if (id < 4096){
      src = Q + (size_t)id * 1024; dst = Qb + (size_t)id * 1024;
    } else {
      int r = id - 4096;
      size_t ir = (size_t)r + (size_t)(r >> 10) * 512;   // skip rows 1024..1535 per batch
      src = K + ir * 1024; dst = Kb + (size_t)r * 1024;
    }
    const float4 v = *(const float4*)(src + t * 4);
    bf16x4 o;
    o[0] = (short)f2b(v.x); o[1] = (short)f2b(v.y);
    o[2] = (short)f2b(v.z); o[3] = (short)f2b(v.w);
    *(bf16x4*)(dst + t * 4) = o;
    return;
  }
  int wid = id - 8192;
  const float* in; u16* out; int Kd, N, bx, by;
  if (wid < 1024){
    int sel = wid >> 8, local = wid & 255;
    bx = local & 15; by = local >> 4; Kd = 1024; N = 1024;
    in  = (sel == 0) ? Wq   : (sel == 1) ? Wk   : (sel == 2) ? Wv   : Wo0;
    out = (sel == 0) ? Wq_t : (sel == 1) ? Wk_t : (sel == 2) ? Wv_t : Wo0_t;
  } else if (wid < 2048){
    int local = wid - 1024; bx = local & 63; by = local >> 6; Kd = 1024; N = 4096;
    in = Wo; out = Wo_t;
  } else {
    int local = wid - 2048; bx = local & 15; by = local >> 4; Kd = 4096; N = 1024;
    in = Wo2; out = Wo2_t;
  }
  const int k0 = by * 64, n0 = bx * 64;
  const int tr = t >> 4, tc = t & 15;
#pragma unroll
  for (int i = 0; i < 4; i++){
    int r = tr + i * 16;
    float4 v = *(const float4*)(in + (size_t)(k0 + r) * N + n0 + tc * 4);
    tile[r][tc*4+0] = v.x; tile[r][tc*4+1] = v.y; tile[r][tc*4+2] = v.z; tile[r][tc*4+3] = v.w;
  }
  __syncthreads();
#pragma unroll
  for (int i = 0; i < 4; i++){
    int nr = tr + i * 16;
    bf16x4 pk;
#pragma unroll
    for (int j = 0; j < 4; j++) pk[j] = (short)f2b(tile[tc*4+j][nr]);
    *(bf16x4*)(out + (size_t)(n0 + nr) * Kd + k0 + tc * 4) = pk;
  }
}

// ---------- 256x256 8-phase main loop (T2+T3+T4+T5), BK=64, 8 waves ----------
static __device__ __forceinline__ void loop8p(const u16* __restrict__ A,
                                              const u16* __restrict__ Bt,
                                              int lda, int ldb, int kbeg, int NT,
                                              int m0, int n0,
                                              u16 (*sA)[2][8192], u16 (*sB)[2][8192],
                                              f32x4 acc[8][4]){
  const int t = threadIdx.x, w = t >> 6, l = t & 63;
  const int wr = w >> 2, wc = w & 3;
  const int c = l & 15, g = l >> 4;
  const int sr = t >> 3, scb = (t & 7) << 4;

  auto stA = [&](int d, int h, int T){
#pragma unroll
    for (int i = 0; i < 2; i++){
      int row = i * 64 + sr;
      int Lb  = scb ^ ((row & 7) << 4);
      gld_lds16(A + (size_t)(m0 + h * 128 + row) * lda + kbeg + T * 64 + (Lb >> 1),
                (char*)&sA[d][h][0] + i * 8192 + t * 16);
    }
  };
  auto stB = [&](int d, int h, int T){
#pragma unroll
    for (int i = 0; i < 2; i++){
      int row = i * 64 + sr;
      int Lb  = scb ^ ((row & 7) << 4);
      gld_lds16(Bt + (size_t)(n0 + h * 128 + row) * ldb + kbeg + T * 64 + (Lb >> 1),
                (char*)&sB[d][h][0] + i * 8192 + t * 16);
    }
  };

  // prologue: B0(0),B1(0),A0(0),A1(0),B0(1),B1(1)
  stB(0, 0, 0); stB(0, 1, 0); stA(0, 0, 0); stA(0, 1, 0);
  stB(1, 0, 1); stB(1, 1, 1);

  bf16x8 bfr[4][2];
  for (int T = 0; T < NT; ++T){
    const int d = T & 1;
    const char* pa = (const char*)&sA[d][wr][0];
    const char* pb = (const char*)&sB[d][wc >> 1][0];
#pragma unroll
    for (int q = 0; q < 4; ++q){
      if (q == 0){
        if (T + 1 < NT) asm volatile("s_waitcnt vmcnt(4)" ::: "memory");
        else            asm volatile("s_waitcnt vmcnt(0)" ::: "memory");
        asm volatile("" ::: "memory");
        __builtin_amdgcn_s_barrier();
        asm volatile("" ::: "memory");
#pragma unroll
        for (int nf = 0; nf < 4; ++nf){
          int lr = (wc & 1) * 64 + nf * 16 + c;
#pragma unroll
          for (int ks = 0; ks < 2; ++ks)
            bfr[nf][ks] = *(const bf16x8*)(pb + lr * 128 + ((ks * 64 + g * 16) ^ ((lr & 7) << 4)));
        }
      }
      bf16x8 af[2][2];
#pragma unroll
      for (int mi = 0; mi < 2; ++mi){
        int lr = (q * 2 + mi) * 16 + c;
#pragma unroll
        for (int ks = 0; ks < 2; ++ks)
          af[mi][ks] = *(const bf16x8*)(pa + lr * 128 + ((ks * 64 + g * 16) ^ ((lr & 7) << 4)));
      }
      if      (q == 0){ if (T + 1 < NT) stA(d ^ 1, 0, T + 1); }
      else if (q == 1){ if (T + 1 < NT) stA(d ^ 1, 1, T + 1); }
      else if (q == 2){ if (T + 2 < NT) stB(d, 0, T + 2); }
      else            { if (T + 2 < NT) stB(d, 1, T + 2); }
      __builtin_amdgcn_s_setprio(1);
#pragma unroll
      for (int mi = 0; mi < 2; ++mi)
#pragma unroll
        for (int nf = 0; nf < 4; ++nf)
#pragma unroll
          for (int ks = 0; ks < 2; ++ks)
            acc[q * 2 + mi][nf] =
              __builtin_amdgcn_mfma_f32_16x16x32_bf16(af[mi][ks], bfr[nf][ks], acc[q * 2 + mi][nf], 0, 0, 0);
      __builtin_amdgcn_s_setprio(0);
      asm volatile("" ::: "memory");
      __builtin_amdgcn_s_barrier();
      asm volatile("" ::: "memory");
    }
  }
}

// ---------- 8-phase GEMM with XCD-rect swizzle ----------
// EPI 0 (FF1, grid 16x16): bias+relu -> bf16. EPI 1 (grid 4x16x4): bf16 split-K partial.
template<int EPI>
__global__ __launch_bounds__(512, 2) void gemm8p(const u16* __restrict__ A,
                                                 const u16* __restrict__ Bt,
                                                 const float* __restrict__ bias,
                                                 void* __restrict__ outp,
                                                 int lda, int ldb, int ldout,
                                                 int ksz, int NT){
  __shared__ u16 sA[2][2][8192];
  __shared__ u16 sB[2][2][8192];
  const int t = threadIdx.x, w = t >> 6, l = t & 63;
  const int wr = w >> 2, wc = w & 3;
  const int c = l & 15, g = l >> 4;

  int m0, n0, zidx;
  if (EPI == 0){
    int lid = blockIdx.x + (blockIdx.y << 4);
    int xcd = lid & 7, slot = lid >> 3;
    int bx = ((xcd & 1) << 3) + (slot & 7);
    int by = ((xcd >> 1) << 2) + (slot >> 3);
    m0 = by * 256; n0 = bx * 256; zidx = 0;
  } else {
    int lid = blockIdx.x + (blockIdx.y << 2) + (blockIdx.z << 6);
    int xcd = lid & 7, slot = lid >> 3;
    int bx = slot & 3, rest = slot >> 2;
    int by = (xcd << 1) + (rest & 1);
    zidx = rest >> 1;
    m0 = by * 256; n0 = bx * 256;
  }

  f32x4 acc[8][4];
#pragma unroll
  for (int i = 0; i < 8; i++)
#pragma unroll
    for (int j = 0; j < 4; j++) acc[i][j] = (f32x4){0.f, 0.f, 0.f, 0.f};

  loop8p(A, Bt, lda, ldb, zidx * ksz, NT, m0, n0, sA, sB, acc);

  if (EPI == 0){
    u16* out = (u16*)outp;
#pragma unroll
    for (int nf = 0; nf < 4; ++nf){
      int n = n0 + wc * 64 + nf * 16 + c;
      float bv = bias[n];
#pragma unroll
      for (int mf = 0; mf < 8; ++mf){
        int row0 = m0 + wr * 128 + mf * 16 + 4 * g;
#pragma unroll
        for (int r = 0; r < 4; ++r)
          out[(size_t)(row0 + r) * ldout + n] = f2b(fmaxf(acc[mf][nf][r] + bv, 0.f));
      }
    }
  } else {
    u16* po = (u16*)outp + (size_t)zidx * (4096ull * 1024ull);   // bf16 partial slice
#pragma unroll
    for (int nf = 0; nf < 4; ++nf){
      int n = n0 + wc * 64 + nf * 16 + c;
#pragma unroll
      for (int mf = 0; mf < 8; ++mf){
        int row0 = m0 + wr * 128 + mf * 16 + 4 * g;
#pragma unroll
        for (int r = 0; r < 4; ++r)
          po[(size_t)(row0 + r) * 1024 + n] = f2b(acc[mf][nf][r]);
      }
    }
  }
}

// ---------- fused QKV (8-phase 256², grid 12x16, XCD 3x8 rect); V via LDS-transposed stores ----------
__global__ __launch_bounds__(512, 2) void gemm8p_qkv(const u16* __restrict__ Qb,
                                                     const u16* __restrict__ Kb,
                                                     const u16* __restrict__ Wq_t,
                                                     const u16* __restrict__ Wk_t,
                                                     const u16* __restrict__ Wv_t,
                                                     const float* __restrict__ bq,
                                                     const float* __restrict__ bk,
                                                     const float* __restrict__ bv,
                                                     u16* __restrict__ qb,
                                                     u16* __restrict__ kbf,
                                                     u16* __restrict__ vtb){
  __shared__ u16 sA[2][2][8192];
  __shared__ u16 sB[2][2][8192];
  int lid = blockIdx.x + blockIdx.y * 12;
  int xcd = lid & 7, slot = lid >> 3;
  int bx = (xcd & 3) * 3 + slot % 3;
  int by = ((xcd >> 2) << 3) + slot / 3;
  const int sel = bx >> 2;
  const u16* A    = sel ? Kb : Qb;
  const u16* Bt   = (sel == 0) ? Wq_t : (sel == 1) ? Wk_t : Wv_t;
  const float* bi = (sel == 0) ? bq   : (sel == 1) ? bk   : bv;
  const int t = threadIdx.x, w = t >> 6, l = t & 63;
  const int wr = w >> 2, wc = w & 3;
  const int c = l & 15, g = l >> 4;
  const int m0 = by * 256, n0 = (bx & 3) * 256;

  f32x4 acc[8][4];
#pragma unroll
  for (int i = 0; i < 8; i++)
#pragma unroll
    for (int j = 0; j < 4; j++) acc[i][j] = (f32x4){0.f, 0.f, 0.f, 0.f};

  loop8p(A, Bt, 1024, 1024, 0, 16, m0, n0, sA, sB, acc);

  if (sel == 2){
    // V: per-wave LDS transpose (sA/sB dead after final barrier), then coalesced stores
    u16* sl = (w < 4) ? (&sA[0][0][0] + w * 8192) : (&sB[0][0][0] + (w - 4) * 8192);
#pragma unroll
    for (int nf = 0; nf < 4; ++nf){
      int n = n0 + wc * 64 + nf * 16 + c;
      float bv_ = bi[n];
#pragma unroll
      for (int mf = 0; mf < 8; ++mf){
        bf16x4 pk;
#pragma unroll
        for (int r = 0; r < 4; ++r) pk[r] = (short)f2b(acc[mf][nf][r] + bv_);
        *(bf16x4*)(sl + (nf * 16 + c) * 128 + mf * 16 + 4 * g) = pk;
      }
    }
    asm volatile("s_waitcnt lgkmcnt(0)" ::: "memory");
    __builtin_amdgcn_sched_barrier(0);
    const int mg = m0 + wr * 128;
    const int bb = mg >> 10, kb0 = mg & 1023;
    u16* vbase = vtb + ((size_t)bb << 20) + kb0;
#pragma unroll
    for (int j = 0; j < 16; ++j){
      int nl  = (l >> 4) + j * 4;
      int kl  = (l & 15) * 8;
      bf16x8 v = *(const bf16x8*)(sl + nl * 128 + kl);
      *(bf16x8*)(vbase + (size_t)(n0 + wc * 64 + nl) * 1024 + kl) = v;
    }
  } else {
    u16* out = sel ? kbf : qb;
#pragma unroll
    for (int nf = 0; nf < 4; ++nf){
      int n = n0 + wc * 64 + nf * 16 + c;
      float bv_ = bi[n];
#pragma unroll
      for (int mf = 0; mf < 8; ++mf){
        int row0 = m0 + wr * 128 + mf * 16 + 4 * g;
#pragma unroll
        for (int r = 0; r < 4; ++r)
          out[(size_t)(row0 + r) * 1024 + n] = f2b(acc[mf][nf][r] + bv_);
      }
    }
  }
}

// ---------- combine NP bf16 partials + bias + residual, then LayerNorm ----------
// 2 rows per block; 128 threads per row; 8 cols/thread (16B loads, G13).
template<int NP, int F32OUT>
__global__ __launch_bounds__(256) void comb_ln(const u16* __restrict__ pp,
                                               const float* __restrict__ bias,
                                               const u16* __restrict__ res,
                                               const float* __restrict__ gw,
                                               const float* __restrict__ bw,
                                               void* __restrict__ outp){
  const int t = threadIdx.x, w = t >> 6;
  const int row = blockIdx.x * 2 + (t >> 7);
  const int u = t & 127;
  const size_t i8 = (size_t)row * 1024 + u * 8;
  bf16x8 rv = *(const bf16x8*)(res + i8);
  float4 b0 = *(const float4*)(bias + u * 8);
  float4 b1 = *(const float4*)(bias + u * 8 + 4);
  float xs[8] = {b0.x, b0.y, b0.z, b0.w, b1.x, b1.y, b1.z, b1.w};
#pragma unroll
  for (int j = 0; j < 8; j++) xs[j] += b2f((u16)rv[j]);
#pragma unroll
  for (int z = 0; z < NP; z++){
    bf16x8 p = *(const bf16x8*)(pp + (size_t)z * (4096ull * 1024ull) + i8);
#pragma unroll
    for (int j = 0; j < 8; j++) xs[j] += b2f((u16)p[j]);
  }
  float s = 0.f, sq = 0.f;
#pragma unroll
  for (int j = 0; j < 8; j++){ s += xs[j]; sq += xs[j] * xs[j]; }
#pragma unroll
  for (int o = 32; o; o >>= 1){ s += __shfl_xor(s, o); sq += __shfl_xor(sq, o); }
  __shared__ float rs[4], rq[4];
  if ((t & 63) == 0){ rs[w] = s; rq[w] = sq; }
  __syncthreads();
  const int wb = (t >> 7) * 2;                 // row0 -> waves 0,1 ; row1 -> waves 2,3
  s  = rs[wb] + rs[wb + 1];
  sq = rq[wb] + rq[wb + 1];
  const float mu   = s * (1.f / 1024.f);
  const float var  = sq * (1.f / 1024.f) - mu * mu;
  const float rstd = rsqrtf(var + 1e-5f);
  float4 g0 = *(const float4*)(gw + u * 8);
  float4 g1 = *(const float4*)(gw + u * 8 + 4);
  float4 w0 = *(const float4*)(bw + u * 8);
  float4 w1 = *(const float4*)(bw + u * 8 + 4);
  float gv[8] = {g0.x, g0.y, g0.z, g0.w, g1.x, g1.y, g1.z, g1.w};
  float wv[8] = {w0.x, w0.y, w0.z, w0.w, w1.x, w1.y, w1.z, w1.w};
  if (F32OUT){
    float4 o0, o1;
    o0.x = (xs[0]-mu)*rstd*gv[0] + wv[0]; o0.y = (xs[1]-mu)*rstd*gv[1] + wv[1];
    o0.z = (xs[2]-mu)*rstd*gv[2] + wv[2]; o0.w = (xs[3]-mu)*rstd*gv[3] + wv[3];
    o1.x = (xs[4]-mu)*rstd*gv[4] + wv[4]; o1.y = (xs[5]-mu)*rstd*gv[5] + wv[5];
    o1.z = (xs[6]-mu)*rstd*gv[6] + wv[6]; o1.w = (xs[7]-mu)*rstd*gv[7] + wv[7];
    *(float4*)((float*)outp + i8)     = o0;
    *(float4*)((float*)outp + i8 + 4) = o1;
  } else {
    bf16x8 o;
#pragma unroll
    for (int j = 0; j < 8; j++) o[j] = (short)f2b((xs[j]-mu)*rstd*gv[j] + wv[j]);
    *(bf16x8*)((u16*)outp + i8) = o;
  }
}

// ---------- fused masked attention: fixed-max softmax (exact: logits < 6.5 << 8) ----------
#define ATTN_STEP(IT, CUR, MC) do{                                              \
  if ((IT) < 15) asm volatile("s_waitcnt vmcnt(4)" ::: "memory");               \
  else           asm volatile("s_waitcnt vmcnt(0)" ::: "memory");               \
  __builtin_amdgcn_s_barrier();                                                 \
  asm volatile("" ::: "memory");                                                \
  if ((IT) < 15) stage((CUR) ^ 1, ((IT) + 1) * 64);                             \
  asm volatile("" ::: "memory");                                                \
  const char* kt = (const char*)sK[(CUR)];                                      \
  f32x4 st[4];                                                                  \
  _Pragma("unroll")                                                             \
  for (int nf = 0; nf < 4; nf++){                                               \
    const char* kr = kt + (nf * 16 + c) * 128;                                  \
    bf16x8 ak0 = *(const bf16x8*)(kr + ((g * 16) ^ sw));                        \
    bf16x8 ak1 = *(const bf16x8*)(kr + ((64 + g * 16) ^ sw));                   \
    f32x4 z = (f32x4){0.f, 0.f, 0.f, 0.f};                                      \
    z = __builtin_amdgcn_mfma_f32_16x16x32_bf16(ak0, bq0, z, 0, 0, 0);          \
    z = __builtin_amdgcn_mfma_f32_16x16x32_bf16(ak1, bq1, z, 0, 0, 0);          \
    st[nf] = z;                                                                 \
  }                                                                             \
  float rsum = 0.f;                                                             \
  bf16x4 pb[4];                                                                 \
  _Pragma("unroll")                                                             \
  for (int nf = 0; nf < 4; nf++)                                                \
    _Pragma("unroll")                                                           \
    for (int r = 0; r < 4; r++){                                                \
      float p = __expf(fmaf(st[nf][r], 0.03125f, MC[nf][r]) - 8.f);             \
      rsum += p;                                                                \
      pb[nf][r] = (short)f2b(p);                                                \
    }                                                                           \
  if ((IT) < 14){                                                               \
    _Pragma("unroll")                                                           \
    for (int nf = 0; nf < 4; nf++)                                              \
      MC[nf] = *(const f32x4*)(mbase + ((IT) + 2) * 64 + nf * 16 + g * 4);      \
  }                                                                             \
  rsum += __shfl_xor(rsum, 16); rsum += __shfl_xor(rsum, 32);                   \
  lsum += rsum;                                                                 \
  const char* vtc = (const char*)sV[(CUR)];                                     \
  __builtin_amdgcn_s_setprio(1);                                                \
  _Pragma("unroll")                                                             \
  for (int f = 0; f < 4; f++){                                                  \
    const char* vr = vtc + (f * 16 + c) * 128;                                  \
    _Pragma("unroll")                                                           \
    for (int nf = 0; nf < 4; nf++){                                             \
      bf16x4 av = *(const bf16x4*)(vr + ((nf * 32 + g * 8) ^ sw));              \
      acc[f] = __builtin_amdgcn_mfma_f32_16x16x16bf16_1k(av, pb[nf], acc[f], 0, 0, 0); \
    }                                                                           \
  }                                                                             \
  __builtin_amdgcn_s_setprio(0);                                                \
}while(0)

__global__ __launch_bounds__(256, 4) void attn_k(const u16* __restrict__ qb,
                                                 const u16* __restrict__ kb,
                                                 const u16* __restrict__ vt,
                                                 const float* __restrict__ mask,
                                                 u16* __restrict__ ob){
  __shared__ u16 sK[2][4096];   // [key][dh], row stride 128B, XOR-swizzled
  __shared__ u16 sV[2][4096];   // [dh][key], row stride 128B, XOR-swizzled

  const int t = threadIdx.x, w = t >> 6, l = t & 63;
  const int c = l & 15, g = l >> 4;
  const int lid  = blockIdx.x + (blockIdx.y << 4) + (blockIdx.z << 8);
  const int xcd  = lid & 7, slot = lid >> 3;
  const int grp  = xcd + ((slot >> 4) << 3);
  const int q0   = (slot & 15) * 64;
  const int h    = grp & 15, b = grp >> 4;
  const int qrow = q0 + w * 16 + c;
  const size_t qoff = ((size_t)(b * 1024 + qrow)) * 1024 + h * 64;
  const bf16x8 bq0 = *(const bf16x8*)(qb + qoff + g * 8);
  const bf16x8 bq1 = *(const bf16x8*)(qb + qoff + 32 + g * 8);
  const u16* kbase = kb + ((size_t)b * 1024) * 1024 + h * 64;
  const u16* vbase = vt + ((size_t)b << 20) + (size_t)(h * 64) * 1024;
  const float* mbase = mask + ((size_t)(h * 4 + b) * 1024 + qrow) * 1024;

  const int lr3 = l >> 3, lc3 = l & 7;
  const int ch0 = w * 2;

  auto stage = [&](int buf, int kv){
#pragma unroll
    for (int i = 0; i < 2; i++){
      int ch  = ch0 + i;
      int row = ch * 8 + lr3;
      int L   = (lc3 * 16) ^ ((row & 7) << 4);
      gld_lds16(kbase + (size_t)(kv + row) * 1024 + (L >> 1), &sK[buf][ch * 512]);
      gld_lds16(vbase + (size_t)row * 1024 + kv + (L >> 1),   &sV[buf][ch * 512]);
    }
  };

  float lsum = 0.f;
  f32x4 acc[4];
#pragma unroll
  for (int f = 0; f < 4; f++) acc[f] = (f32x4){0.f, 0.f, 0.f, 0.f};

  stage(0, 0);
  asm volatile("" ::: "memory");
  f32x4 mA[4], mB[4];
#pragma unroll
  for (int nf = 0; nf < 4; nf++) mA[nf] = *(const f32x4*)(mbase + nf * 16 + g * 4);
  asm volatile("" ::: "memory");
#pragma unroll
  for (int nf = 0; nf < 4; nf++) mB[nf] = *(const f32x4*)(mbase + 64 + nf * 16 + g * 4);

  const int sw = (c & 7) << 4;
  for (int ii = 0; ii < 8; ++ii){
    ATTN_STEP(2 * ii,     0, mA);
    ATTN_STEP(2 * ii + 1, 1, mB);
  }

  // epilogue: O^T -> LDS (per-wave rows), then coalesced 16B row stores
  const float inv = 1.f / lsum;
  u16* sO = &sK[0][0];
#pragma unroll
  for (int f = 0; f < 4; f++){
    bf16x4 pk;
#pragma unroll
    for (int r = 0; r < 4; r++) pk[r] = (short)f2b(acc[f][r] * inv);
    *(bf16x4*)(sO + (w * 16 + c) * 64 + f * 16 + 4 * g) = pk;
  }
  asm volatile("s_waitcnt lgkmcnt(0)" ::: "memory");
  __builtin_amdgcn_sched_barrier(0);
  {
    int rl  = w * 16 + (l >> 2);
    int d0  = (l & 3) * 16;
    bf16x8 v0 = *(const bf16x8*)(sO + rl * 64 + d0);
    bf16x8 v1 = *(const bf16x8*)(sO + rl * 64 + d0 + 8);
    u16* dst = ob + ((size_t)(b * 1024 + q0 + rl)) * 1024 + h * 64 + d0;
    *(bf16x8*)(dst)     = v0;
    *(bf16x8*)(dst + 8) = v1;
  }
}

// ---------- launch ----------
extern "C" void kernel_launch(void* const* d_in, const int* in_sizes, int n_in,
                              void* d_out, int out_size, void* d_ws, size_t ws_size,
                              hipStream_t stream){
  const float* Q    = (const float*)d_in[0];
  const float* K    = (const float*)d_in[1];
  const float* mask = (const float*)d_in[2];
  const float* Wq   = (const float*)d_in[4];  const float* bq  = (const float*)d_in[5];
  const float* Wk   = (const float*)d_in[6];  const float* bk  = (const float*)d_in[7];
  const float* Wv   = (const float*)d_in[8];  const float* bv  = (const float*)d_in[9];
  const float* Wo0  = (const float*)d_in[10]; const float* bo0 = (const float*)d_in[11];
  const float* Wo   = (const float*)d_in[12]; const float* bo  = (const float*)d_in[13];
  const float* Wo2  = (const float*)d_in[14]; const float* bo2 = (const float*)d_in[15];
  const float* g0   = (const float*)d_in[16]; const float* be0 = (const float*)d_in[17];
  const float* g1   = (const float*)d_in[18]; const float* be1 = (const float*)d_in[19];

  uint8_t* W = (uint8_t*)d_ws;
  const size_t MB = 1024ull * 1024ull;
  u16* Wq_t  = (u16*)(W + 0);
  u16* Wk_t  = (u16*)(W + 2  * MB);
  u16* Wv_t  = (u16*)(W + 4  * MB);
  u16* Wo0_t = (u16*)(W + 6  * MB);
  u16* Wo_t  = (u16*)(W + 8  * MB);   // [4096][1024]
  u16* Wo2_t = (u16*)(W + 16 * MB);   // [1024][4096]
  u16* Qb    = (u16*)(W + 24 * MB);
  u16* Kb    = (u16*)(W + 32 * MB);
  u16* qb    = (u16*)(W + 40 * MB);
  u16* kbf   = (u16*)(W + 48 * MB);
  u16* vtb   = (u16*)(W + 56 * MB);
  u16* ob    = (u16*)(W + 24 * MB);   // reuse Qb
  u16* x1b   = (u16*)(W + 64 * MB);
  u16* hb    = (u16*)(W + 32 * MB);   // [4096][4096] bf16, spans dead Kb/qb/kbf/vtb
  u16* ppb   = (u16*)(W + 72 * MB);   // 4 x 8MB bf16 split-K partials

  prep<<<11264, 256, 0, stream>>>(Q, K, Qb, Kb, Wq, Wq_t, Wk, Wk_t, Wv, Wv_t,
                                  Wo0, Wo0_t, Wo, Wo_t, Wo2, Wo2_t);

  gemm8p_qkv<<<dim3(12, 16), 512, 0, stream>>>(Qb, Kb, Wq_t, Wk_t, Wv_t,
                                               bq, bk, bv, qb, kbf, vtb);

  attn_k<<<dim3(16, 16, 4), 256, 0, stream>>>(qb, kbf, vtb, mask, ob);

  // output proj: 8-phase split-K=4 (NT=4), bf16 partials -> fused combine+LN0
  gemm8p<1><<<dim3(4, 16, 4), 512, 0, stream>>>(ob, Wo0_t, nullptr, ppb, 1024, 1024, 1024, 256, 4);
  comb_ln<4, 0><<<2048, 256, 0, stream>>>(ppb, bo0, qb, g0, be0, x1b);

  // FFN: FF1 (8-phase, relu) -> FF2 (8-phase, split-K=4, bf16 partials) -> combine+LN1
  gemm8p<0><<<dim3(16, 16), 512, 0, stream>>>(x1b, Wo_t, bo, hb, 1024, 1024, 4096, 0, 16);
  gemm8p<1><<<dim3(4, 16, 4), 512, 0, stream>>>(hb, Wo2_t, nullptr, ppb, 4096, 4096, 1024, 1024, 16);
  comb_ln<4, 1><<<2048, 256, 0, stream>>>(ppb, bo2, x1b, g1, be1, d_out);
}

// Round 11
// 290.050 us; speedup vs baseline: 1.7845x; 1.0050x over previous
//
#include <hip/hip_runtime.h>
#include <hip/hip_bf16.h>

typedef unsigned short u16;
typedef __attribute__((ext_vector_type(4))) short bf16x4;
typedef __attribute__((ext_vector_type(8))) short bf16x8;
typedef __attribute__((ext_vector_type(4))) float f32x4;

// ---------- helpers ----------
static __device__ __forceinline__ u16 f2b(float f){
  union { float f; unsigned u; } v; v.f = f;
  unsigned r = v.u + 0x7fffu + ((v.u >> 16) & 1u);   // RNE
  return (u16)(r >> 16);
}
static __device__ __forceinline__ float b2f(u16 h){
  union { unsigned u; float f; } v; v.u = ((unsigned)h) << 16; return v.f;
}
static __device__ __forceinline__ void gld_lds16(const void* g, void* l){
  __builtin_amdgcn_global_load_lds((const __attribute__((address_space(1))) void*)g,
                                   (__attribute__((address_space(3))) void*)l, 16, 0, 0);
}

// ---------- prep: Q/K bf16 convert (compacted) + Wq/Wk/Wv transposes ----------
__global__ __launch_bounds__(256) void prep(const float* __restrict__ Q,
                                            const float* __restrict__ K,
                                            u16* __restrict__ Qb, u16* __restrict__ Kb,
                                            const float* __restrict__ Wq, u16* __restrict__ Wq_t,
                                            const float* __restrict__ Wk, u16* __restrict__ Wk_t,
                                            const float* __restrict__ Wv, u16* __restrict__ Wv_t){
  __shared__ float tile[64][65];
  const int id = blockIdx.x, t = threadIdx.x;
  if (id < 8192){
    const float* src; u16* dst;
    if (id < 4096){
      src = Q + (size_t)id * 1024; dst = Qb + (size_t)id * 1024;
    } else {
      int r = id - 4096;
      size_t ir = (size_t)r + (size_t)(r >> 10) * 512;   // skip rows 1024..1535 per batch
      src = K + ir * 1024; dst = Kb + (size_t)r * 1024;
    }
    const float4 v = *(const float4*)(src + t * 4);
    bf16x4 o;
    o[0] = (short)f2b(v.x); o[1] = (short)f2b(v.y);
    o[2] = (short)f2b(v.z); o[3] = (short)f2b(v.w);
    *(bf16x4*)(dst + t * 4) = o;
    return;
  }
  int wid = id - 8192;               // 0..767 : 3 x 256 tiles (Wq, Wk, Wv)
  int sel = wid >> 8, local = wid & 255;
  int bx = local & 15, by = local >> 4;
  const float* in  = (sel == 0) ? Wq   : (sel == 1) ? Wk   : Wv;
  u16*         out = (sel == 0) ? Wq_t : (sel == 1) ? Wk_t : Wv_t;
  const int k0 = by * 64, n0 = bx * 64;
  const int tr = t >> 4, tc = t & 15;
#pragma unroll
  for (int i = 0; i < 4; i++){
    int r = tr + i * 16;
    float4 v = *(const float4*)(in + (size_t)(k0 + r) * 1024 + n0 + tc * 4);
    tile[r][tc*4+0] = v.x; tile[r][tc*4+1] = v.y; tile[r][tc*4+2] = v.z; tile[r][tc*4+3] = v.w;
  }
  __syncthreads();
#pragma unroll
  for (int i = 0; i < 4; i++){
    int nr = tr + i * 16;
    bf16x4 pk;
#pragma unroll
    for (int j = 0; j < 4; j++) pk[j] = (short)f2b(tile[tc*4+j][nr]);
    *(bf16x4*)(out + (size_t)(n0 + nr) * 1024 + k0 + tc * 4) = pk;
  }
}

// ---------- 256x256 8-phase main loop (T2+T3+T4+T5), BK=64, 8 waves ----------
static __device__ __forceinline__ void loop8p(const u16* __restrict__ A,
                                              const u16* __restrict__ Bt,
                                              int lda, int ldb, int kbeg, int NT,
                                              int m0, int n0,
                                              u16 (*sA)[2][8192], u16 (*sB)[2][8192],
                                              f32x4 acc[8][4]){
  const int t = threadIdx.x, w = t >> 6, l = t & 63;
  const int wr = w >> 2, wc = w & 3;
  const int c = l & 15, g = l >> 4;
  const int sr = t >> 3, scb = (t & 7) << 4;

  auto stA = [&](int d, int h, int T){
#pragma unroll
    for (int i = 0; i < 2; i++){
      int row = i * 64 + sr;
      int Lb  = scb ^ ((row & 7) << 4);
      gld_lds16(A + (size_t)(m0 + h * 128 + row) * lda + kbeg + T * 64 + (Lb >> 1),
                (char*)&sA[d][h][0] + i * 8192 + t * 16);
    }
  };
  auto stB = [&](int d, int h, int T){
#pragma unroll
    for (int i = 0; i < 2; i++){
      int row = i * 64 + sr;
      int Lb  = scb ^ ((row & 7) << 4);
      gld_lds16(Bt + (size_t)(n0 + h * 128 + row) * ldb + kbeg + T * 64 + (Lb >> 1),
                (char*)&sB[d][h][0] + i * 8192 + t * 16);
    }
  };

  // prologue: B0(0),B1(0),A0(0),A1(0),B0(1),B1(1)
  stB(0, 0, 0); stB(0, 1, 0); stA(0, 0, 0); stA(0, 1, 0);
  stB(1, 0, 1); stB(1, 1, 1);

  bf16x8 bfr[4][2];
  for (int T = 0; T < NT; ++T){
    const int d = T & 1;
    const char* pa = (const char*)&sA[d][wr][0];
    const char* pb = (const char*)&sB[d][wc >> 1][0];
#pragma unroll
    for (int q = 0; q < 4; ++q){
      if (q == 0){
        if (T + 1 < NT) asm volatile("s_waitcnt vmcnt(4)" ::: "memory");
        else            asm volatile("s_waitcnt vmcnt(0)" ::: "memory");
        asm volatile("" ::: "memory");
        __builtin_amdgcn_s_barrier();
        asm volatile("" ::: "memory");
#pragma unroll
        for (int nf = 0; nf < 4; ++nf){
          int lr = (wc & 1) * 64 + nf * 16 + c;
#pragma unroll
          for (int ks = 0; ks < 2; ++ks)
            bfr[nf][ks] = *(const bf16x8*)(pb + lr * 128 + ((ks * 64 + g * 16) ^ ((lr & 7) << 4)));
        }
      }
      bf16x8 af[2][2];
#pragma unroll
      for (int mi = 0; mi < 2; ++mi){
        int lr = (q * 2 + mi) * 16 + c;
#pragma unroll
        for (int ks = 0; ks < 2; ++ks)
          af[mi][ks] = *(const bf16x8*)(pa + lr * 128 + ((ks * 64 + g * 16) ^ ((lr & 7) << 4)));
      }
      if      (q == 0){ if (T + 1 < NT) stA(d ^ 1, 0, T + 1); }
      else if (q == 1){ if (T + 1 < NT) stA(d ^ 1, 1, T + 1); }
      else if (q == 2){ if (T + 2 < NT) stB(d, 0, T + 2); }
      else            { if (T + 2 < NT) stB(d, 1, T + 2); }
      __builtin_amdgcn_s_setprio(1);
#pragma unroll
      for (int mi = 0; mi < 2; ++mi)
#pragma unroll
        for (int nf = 0; nf < 4; ++nf)
#pragma unroll
          for (int ks = 0; ks < 2; ++ks)
            acc[q * 2 + mi][nf] =
              __builtin_amdgcn_mfma_f32_16x16x32_bf16(af[mi][ks], bfr[nf][ks], acc[q * 2 + mi][nf], 0, 0, 0);
      __builtin_amdgcn_s_setprio(0);
      asm volatile("" ::: "memory");
      __builtin_amdgcn_s_barrier();
      asm volatile("" ::: "memory");
    }
  }
}

// ---------- 8-phase GEMM with XCD-rect swizzle ----------
// EPI 0 (FF1, grid 16x16): bias+relu -> bf16. EPI 1 (grid 4x16x4): bf16 split-K partial.
template<int EPI>
__global__ __launch_bounds__(512, 2) void gemm8p(const u16* __restrict__ A,
                                                 const u16* __restrict__ Bt,
                                                 const float* __restrict__ bias,
                                                 void* __restrict__ outp,
                                                 int lda, int ldb, int ldout,
                                                 int ksz, int NT){
  __shared__ u16 sA[2][2][8192];
  __shared__ u16 sB[2][2][8192];
  const int t = threadIdx.x, w = t >> 6, l = t & 63;
  const int wr = w >> 2, wc = w & 3;
  const int c = l & 15, g = l >> 4;

  int m0, n0, zidx;
  if (EPI == 0){
    int lid = blockIdx.x + (blockIdx.y << 4);
    int xcd = lid & 7, slot = lid >> 3;
    int bx = ((xcd & 1) << 3) + (slot & 7);
    int by = ((xcd >> 1) << 2) + (slot >> 3);
    m0 = by * 256; n0 = bx * 256; zidx = 0;
  } else {
    int lid = blockIdx.x + (blockIdx.y << 2) + (blockIdx.z << 6);
    int xcd = lid & 7, slot = lid >> 3;
    int bx = slot & 3, rest = slot >> 2;
    int by = (xcd << 1) + (rest & 1);
    zidx = rest >> 1;
    m0 = by * 256; n0 = bx * 256;
  }

  f32x4 acc[8][4];
#pragma unroll
  for (int i = 0; i < 8; i++)
#pragma unroll
    for (int j = 0; j < 4; j++) acc[i][j] = (f32x4){0.f, 0.f, 0.f, 0.f};

  loop8p(A, Bt, lda, ldb, zidx * ksz, NT, m0, n0, sA, sB, acc);

  if (EPI == 0){
    u16* out = (u16*)outp;
#pragma unroll
    for (int nf = 0; nf < 4; ++nf){
      int n = n0 + wc * 64 + nf * 16 + c;
      float bv = bias[n];
#pragma unroll
      for (int mf = 0; mf < 8; ++mf){
        int row0 = m0 + wr * 128 + mf * 16 + 4 * g;
#pragma unroll
        for (int r = 0; r < 4; ++r)
          out[(size_t)(row0 + r) * ldout + n] = f2b(fmaxf(acc[mf][nf][r] + bv, 0.f));
      }
    }
  } else {
    u16* po = (u16*)outp + (size_t)zidx * (4096ull * 1024ull);   // bf16 partial slice
#pragma unroll
    for (int nf = 0; nf < 4; ++nf){
      int n = n0 + wc * 64 + nf * 16 + c;
#pragma unroll
      for (int mf = 0; mf < 8; ++mf){
        int row0 = m0 + wr * 128 + mf * 16 + 4 * g;
#pragma unroll
        for (int r = 0; r < 4; ++r)
          po[(size_t)(row0 + r) * 1024 + n] = f2b(acc[mf][nf][r]);
      }
    }
  }
}

// ---------- fused QKV (8-phase 256², grid 12x16, XCD 3x8 rect); V via LDS-transposed stores ----------
__global__ __launch_bounds__(512, 2) void gemm8p_qkv(const u16* __restrict__ Qb,
                                                     const u16* __restrict__ Kb,
                                                     const u16* __restrict__ Wq_t,
                                                     const u16* __restrict__ Wk_t,
                                                     const u16* __restrict__ Wv_t,
                                                     const float* __restrict__ bq,
                                                     const float* __restrict__ bk,
                                                     const float* __restrict__ bv,
                                                     u16* __restrict__ qb,
                                                     u16* __restrict__ kbf,
                                                     u16* __restrict__ vtb){
  __shared__ u16 sA[2][2][8192];
  __shared__ u16 sB[2][2][8192];
  int lid = blockIdx.x + blockIdx.y * 12;
  int xcd = lid & 7, slot = lid >> 3;
  int bx = (xcd & 3) * 3 + slot % 3;
  int by = ((xcd >> 2) << 3) + slot / 3;
  const int sel = bx >> 2;
  const u16* A    = sel ? Kb : Qb;
  const u16* Bt   = (sel == 0) ? Wq_t : (sel == 1) ? Wk_t : Wv_t;
  const float* bi = (sel == 0) ? bq   : (sel == 1) ? bk   : bv;
  const int t = threadIdx.x, w = t >> 6, l = t & 63;
  const int wr = w >> 2, wc = w & 3;
  const int c = l & 15, g = l >> 4;
  const int m0 = by * 256, n0 = (bx & 3) * 256;

  f32x4 acc[8][4];
#pragma unroll
  for (int i = 0; i < 8; i++)
#pragma unroll
    for (int j = 0; j < 4; j++) acc[i][j] = (f32x4){0.f, 0.f, 0.f, 0.f};

  loop8p(A, Bt, 1024, 1024, 0, 16, m0, n0, sA, sB, acc);

  if (sel == 2){
    // V: per-wave LDS transpose (sA/sB dead after final barrier), then coalesced stores
    u16* sl = (w < 4) ? (&sA[0][0][0] + w * 8192) : (&sB[0][0][0] + (w - 4) * 8192);
#pragma unroll
    for (int nf = 0; nf < 4; ++nf){
      int n = n0 + wc * 64 + nf * 16 + c;
      float bv_ = bi[n];
#pragma unroll
      for (int mf = 0; mf < 8; ++mf){
        bf16x4 pk;
#pragma unroll
        for (int r = 0; r < 4; ++r) pk[r] = (short)f2b(acc[mf][nf][r] + bv_);
        *(bf16x4*)(sl + (nf * 16 + c) * 128 + mf * 16 + 4 * g) = pk;
      }
    }
    asm volatile("s_waitcnt lgkmcnt(0)" ::: "memory");
    __builtin_amdgcn_sched_barrier(0);
    const int mg = m0 + wr * 128;
    const int bb = mg >> 10, kb0 = mg & 1023;
    u16* vbase = vtb + ((size_t)bb << 20) + kb0;
#pragma unroll
    for (int j = 0; j < 16; ++j){
      int nl  = (l >> 4) + j * 4;
      int kl  = (l & 15) * 8;
      bf16x8 v = *(const bf16x8*)(sl + nl * 128 + kl);
      *(bf16x8*)(vbase + (size_t)(n0 + wc * 64 + nl) * 1024 + kl) = v;
    }
  } else {
    u16* out = sel ? kbf : qb;
#pragma unroll
    for (int nf = 0; nf < 4; ++nf){
      int n = n0 + wc * 64 + nf * 16 + c;
      float bv_ = bi[n];
#pragma unroll
      for (int mf = 0; mf < 8; ++mf){
        int row0 = m0 + wr * 128 + mf * 16 + 4 * g;
#pragma unroll
        for (int r = 0; r < 4; ++r)
          out[(size_t)(row0 + r) * 1024 + n] = f2b(acc[mf][nf][r] + bv_);
      }
    }
  }
}

// ---------- combine NP bf16 partials + bias + residual, then LayerNorm ----------
// 2 rows per block; 128 threads per row; 8 cols/thread (16B loads, G13).
template<int NP, int F32OUT>
__global__ __launch_bounds__(256) void comb_ln(const u16* __restrict__ pp,
                                               const float* __restrict__ bias,
                                               const u16* __restrict__ res,
                                               const float* __restrict__ gw,
                                               const float* __restrict__ bw,
                                               void* __restrict__ outp){
  const int t = threadIdx.x, w = t >> 6;
  const int row = blockIdx.x * 2 + (t >> 7);
  const int u = t & 127;
  const size_t i8 = (size_t)row * 1024 + u * 8;
  bf16x8 rv = *(const bf16x8*)(res + i8);
  float4 b0 = *(const float4*)(bias + u * 8);
  float4 b1 = *(const float4*)(bias + u * 8 + 4);
  float xs[8] = {b0.x, b0.y, b0.z, b0.w, b1.x, b1.y, b1.z, b1.w};
#pragma unroll
  for (int j = 0; j < 8; j++) xs[j] += b2f((u16)rv[j]);
#pragma unroll
  for (int z = 0; z < NP; z++){
    bf16x8 p = *(const bf16x8*)(pp + (size_t)z * (4096ull * 1024ull) + i8);
#pragma unroll
    for (int j = 0; j < 8; j++) xs[j] += b2f((u16)p[j]);
  }
  float s = 0.f, sq = 0.f;
#pragma unroll
  for (int j = 0; j < 8; j++){ s += xs[j]; sq += xs[j] * xs[j]; }
#pragma unroll
  for (int o = 32; o; o >>= 1){ s += __shfl_xor(s, o); sq += __shfl_xor(sq, o); }
  __shared__ float rs[4], rq[4];
  if ((t & 63) == 0){ rs[w] = s; rq[w] = sq; }
  __syncthreads();
  const int wb = (t >> 7) * 2;                 // row0 -> waves 0,1 ; row1 -> waves 2,3
  s  = rs[wb] + rs[wb + 1];
  sq = rq[wb] + rq[wb + 1];
  const float mu   = s * (1.f / 1024.f);
  const float var  = sq * (1.f / 1024.f) - mu * mu;
  const float rstd = rsqrtf(var + 1e-5f);
  float4 g0 = *(const float4*)(gw + u * 8);
  float4 g1 = *(const float4*)(gw + u * 8 + 4);
  float4 w0 = *(const float4*)(bw + u * 8);
  float4 w1 = *(const float4*)(bw + u * 8 + 4);
  float gv[8] = {g0.x, g0.y, g0.z, g0.w, g1.x, g1.y, g1.z, g1.w};
  float wv[8] = {w0.x, w0.y, w0.z, w0.w, w1.x, w1.y, w1.z, w1.w};
  if (F32OUT){
    float4 o0, o1;
    o0.x = (xs[0]-mu)*rstd*gv[0] + wv[0]; o0.y = (xs[1]-mu)*rstd*gv[1] + wv[1];
    o0.z = (xs[2]-mu)*rstd*gv[2] + wv[2]; o0.w = (xs[3]-mu)*rstd*gv[3] + wv[3];
    o1.x = (xs[4]-mu)*rstd*gv[4] + wv[4]; o1.y = (xs[5]-mu)*rstd*gv[5] + wv[5];
    o1.z = (xs[6]-mu)*rstd*gv[6] + wv[6]; o1.w = (xs[7]-mu)*rstd*gv[7] + wv[7];
    *(float4*)((float*)outp + i8)     = o0;
    *(float4*)((float*)outp + i8 + 4) = o1;
  } else {
    bf16x8 o;
#pragma unroll
    for (int j = 0; j < 8; j++) o[j] = (short)f2b((xs[j]-mu)*rstd*gv[j] + wv[j]);
    *(bf16x8*)((u16*)outp + i8) = o;
  }
}

// ---------- fused masked attention (128 q-rows/block, 8 waves) + folded transposes ----------
// Per-thread stage = 2 loads (K,V); mask = 4; queue at iter top = 6 -> vmcnt(4) drains stage.
#define ATTN_STEP(IT, CUR, MC) do{                                              \
  if ((IT) < 15) asm volatile("s_waitcnt vmcnt(4)" ::: "memory");               \
  else           asm volatile("s_waitcnt vmcnt(0)" ::: "memory");               \
  __builtin_amdgcn_s_barrier();                                                 \
  asm volatile("" ::: "memory");                                                \
  if ((IT) < 15) stage((CUR) ^ 1, ((IT) + 1) * 64);                             \
  asm volatile("" ::: "memory");                                                \
  const char* kt = (const char*)sK[(CUR)];                                      \
  f32x4 st[4];                                                                  \
  _Pragma("unroll")                                                             \
  for (int nf = 0; nf < 4; nf++){                                               \
    const char* kr = kt + (nf * 16 + c) * 128;                                  \
    bf16x8 ak0 = *(const bf16x8*)(kr + ((g * 16) ^ sw));                        \
    bf16x8 ak1 = *(const bf16x8*)(kr + ((64 + g * 16) ^ sw));                   \
    f32x4 z = (f32x4){0.f, 0.f, 0.f, 0.f};                                      \
    z = __builtin_amdgcn_mfma_f32_16x16x32_bf16(ak0, bq0, z, 0, 0, 0);          \
    z = __builtin_amdgcn_mfma_f32_16x16x32_bf16(ak1, bq1, z, 0, 0, 0);          \
    st[nf] = z;                                                                 \
  }                                                                             \
  float rsum = 0.f;                                                             \
  bf16x4 pb[4];                                                                 \
  _Pragma("unroll")                                                             \
  for (int nf = 0; nf < 4; nf++)                                                \
    _Pragma("unroll")                                                           \
    for (int r = 0; r < 4; r++){                                                \
      float p = __expf(fmaf(st[nf][r], 0.03125f, MC[nf][r]) - 8.f);             \
      rsum += p;                                                                \
      pb[nf][r] = (short)f2b(p);                                                \
    }                                                                           \
  if ((IT) < 14){                                                               \
    _Pragma("unroll")                                                           \
    for (int nf = 0; nf < 4; nf++)                                              \
      MC[nf] = *(const f32x4*)(mbase + ((IT) + 2) * 64 + nf * 16 + g * 4);      \
  }                                                                             \
  rsum += __shfl_xor(rsum, 16); rsum += __shfl_xor(rsum, 32);                   \
  lsum += rsum;                                                                 \
  const char* vtc = (const char*)sV[(CUR)];                                     \
  __builtin_amdgcn_s_setprio(1);                                                \
  _Pragma("unroll")                                                             \
  for (int f = 0; f < 4; f++){                                                  \
    const char* vr = vtc + (f * 16 + c) * 128;                                  \
    _Pragma("unroll")                                                           \
    for (int nf = 0; nf < 4; nf++){                                             \
      bf16x4 av = *(const bf16x4*)(vr + ((nf * 32 + g * 8) ^ sw));              \
      acc[f] = __builtin_amdgcn_mfma_f32_16x16x16bf16_1k(av, pb[nf], acc[f], 0, 0, 0); \
    }                                                                           \
  }                                                                             \
  __builtin_amdgcn_s_setprio(0);                                                \
}while(0)

__global__ __launch_bounds__(512, 4) void attn_k(const u16* __restrict__ qb,
                                                 const u16* __restrict__ kb,
                                                 const u16* __restrict__ vt,
                                                 const float* __restrict__ mask,
                                                 u16* __restrict__ ob,
                                                 const float* __restrict__ Wo0, u16* __restrict__ Wo0_t,
                                                 const float* __restrict__ Wo,  u16* __restrict__ Wo_t,
                                                 const float* __restrict__ Wo2, u16* __restrict__ Wo2_t){
  __shared__ u16 sK[2][4096];   // [key 64][dh 64], row stride 128B, XOR-swizzled
  __shared__ u16 sV[2][4096];   // [dh 64][key 64], row stride 128B, XOR-swizzled

  const int id = blockIdx.x, t = threadIdx.x;

  if (id < 1152){
    // ---- folded weight transposes (2 x 64x64 tiles per 512-thread block) ----
    const int half = t >> 8, tt = t & 255;
    const int tileid = id * 2 + half;
    const float* in; u16* out; int Kd, N, bx, by;
    if (tileid < 256){
      bx = tileid & 15; by = tileid >> 4; Kd = 1024; N = 1024; in = Wo0; out = Wo0_t;
    } else if (tileid < 1280){
      int lo = tileid - 256; bx = lo & 63; by = lo >> 6; Kd = 1024; N = 4096; in = Wo; out = Wo_t;
    } else {
      int lo = tileid - 1280; bx = lo & 15; by = lo >> 4; Kd = 4096; N = 1024; in = Wo2; out = Wo2_t;
    }
    u16* tl = half ? &sV[0][0] : &sK[0][0];          // 64x65 u16 tile (fits 8KB+spill in own array)
    const int k0 = by * 64, n0 = bx * 64;
    const int tr = tt >> 4, tc = tt & 15;
#pragma unroll
    for (int i = 0; i < 4; i++){
      int r = tr + i * 16;
      float4 v = *(const float4*)(in + (size_t)(k0 + r) * N + n0 + tc * 4);
      tl[r * 65 + tc * 4 + 0] = f2b(v.x); tl[r * 65 + tc * 4 + 1] = f2b(v.y);
      tl[r * 65 + tc * 4 + 2] = f2b(v.z); tl[r * 65 + tc * 4 + 3] = f2b(v.w);
    }
    __syncthreads();
#pragma unroll
    for (int i = 0; i < 4; i++){
      int nr = tr + i * 16;
      bf16x4 pk;
#pragma unroll
      for (int j = 0; j < 4; j++) pk[j] = (short)tl[(tc * 4 + j) * 65 + nr];
      *(bf16x4*)(out + (size_t)(n0 + nr) * Kd + k0 + tc * 4) = pk;
    }
    return;
  }

  // ---- attention: 128 q-rows per block, K/V staged once for 8 waves ----
  const int aid = id - 1152;                        // 0..511
  const int w = t >> 6, l = t & 63;
  const int c = l & 15, g = l >> 4;
  const int q0 = (aid & 7) * 128;
  const int h  = (aid >> 3) & 15, b = aid >> 7;
  const int qrow = q0 + w * 16 + c;                 // w in 0..7 -> 128 rows
  const size_t qoff = ((size_t)(b * 1024 + qrow)) * 1024 + h * 64;
  const bf16x8 bq0 = *(const bf16x8*)(qb + qoff + g * 8);
  const bf16x8 bq1 = *(const bf16x8*)(qb + qoff + 32 + g * 8);
  const u16* kbase = kb + ((size_t)b * 1024) * 1024 + h * 64;
  const u16* vbase = vt + ((size_t)b << 20) + (size_t)(h * 64) * 1024;
  const float* mbase = mask + ((size_t)(h * 4 + b) * 1024 + qrow) * 1024;

  const int srow = t >> 3, slc = t & 7;             // 512 threads cover 64 rows x 128B

  auto stage = [&](int buf, int kv){
    int L = (slc * 16) ^ ((srow & 7) << 4);
    gld_lds16(kbase + (size_t)(kv + srow) * 1024 + (L >> 1), &sK[buf][t * 8]);
    gld_lds16(vbase + (size_t)srow * 1024 + kv + (L >> 1),   &sV[buf][t * 8]);
  };

  float lsum = 0.f;
  f32x4 acc[4];
#pragma unroll
  for (int f = 0; f < 4; f++) acc[f] = (f32x4){0.f, 0.f, 0.f, 0.f};

  stage(0, 0);
  asm volatile("" ::: "memory");
  f32x4 mA[4], mB[4];
#pragma unroll
  for (int nf = 0; nf < 4; nf++) mA[nf] = *(const f32x4*)(mbase + nf * 16 + g * 4);
  asm volatile("" ::: "memory");
#pragma unroll
  for (int nf = 0; nf < 4; nf++) mB[nf] = *(const f32x4*)(mbase + 64 + nf * 16 + g * 4);

  const int sw = (c & 7) << 4;
  for (int ii = 0; ii < 8; ++ii){
    ATTN_STEP(2 * ii,     0, mA);
    ATTN_STEP(2 * ii + 1, 1, mB);
  }

  // epilogue: barrier (other waves still reading buf1), O^T -> LDS, coalesced stores
  __syncthreads();
  const float inv = 1.f / lsum;
  u16* sO = &sK[0][0];                               // [128 rows][64 dh] = 16KB = all of sK
#pragma unroll
  for (int f = 0; f < 4; f++){
    bf16x4 pk;
#pragma unroll
    for (int r = 0; r < 4; r++) pk[r] = (short)f2b(acc[f][r] * inv);
    *(bf16x4*)(sO + (w * 16 + c) * 64 + f * 16 + 4 * g) = pk;
  }
  asm volatile("s_waitcnt lgkmcnt(0)" ::: "memory");
  __builtin_amdgcn_sched_barrier(0);
  {
    int rl  = w * 16 + (l >> 2);                     // own wave's rows only
    int d0  = (l & 3) * 16;
    bf16x8 v0 = *(const bf16x8*)(sO + rl * 64 + d0);
    bf16x8 v1 = *(const bf16x8*)(sO + rl * 64 + d0 + 8);
    u16* dst = ob + ((size_t)(b * 1024 + q0 + rl)) * 1024 + h * 64 + d0;
    *(bf16x8*)(dst)     = v0;
    *(bf16x8*)(dst + 8) = v1;
  }
}

// ---------- launch ----------
extern "C" void kernel_launch(void* const* d_in, const int* in_sizes, int n_in,
                              void* d_out, int out_size, void* d_ws, size_t ws_size,
                              hipStream_t stream){
  const float* Q    = (const float*)d_in[0];
  const float* K    = (const float*)d_in[1];
  const float* mask = (const float*)d_in[2];
  const float* Wq   = (const float*)d_in[4];  const float* bq  = (const float*)d_in[5];
  const float* Wk   = (const float*)d_in[6];  const float* bk  = (const float*)d_in[7];
  const float* Wv   = (const float*)d_in[8];  const float* bv  = (const float*)d_in[9];
  const float* Wo0  = (const float*)d_in[10]; const float* bo0 = (const float*)d_in[11];
  const float* Wo   = (const float*)d_in[12]; const float* bo  = (const float*)d_in[13];
  const float* Wo2  = (const float*)d_in[14]; const float* bo2 = (const float*)d_in[15];
  const float* g0   = (const float*)d_in[16]; const float* be0 = (const float*)d_in[17];
  const float* g1   = (const float*)d_in[18]; const float* be1 = (const float*)d_in[19];

  uint8_t* W = (uint8_t*)d_ws;
  const size_t MB = 1024ull * 1024ull;
  u16* Wq_t  = (u16*)(W + 0);
  u16* Wk_t  = (u16*)(W + 2  * MB);
  u16* Wv_t  = (u16*)(W + 4  * MB);
  u16* Wo0_t = (u16*)(W + 6  * MB);
  u16* Wo_t  = (u16*)(W + 8  * MB);   // [4096][1024]
  u16* Wo2_t = (u16*)(W + 16 * MB);   // [1024][4096]
  u16* Qb    = (u16*)(W + 24 * MB);
  u16* Kb    = (u16*)(W + 32 * MB);
  u16* qb    = (u16*)(W + 40 * MB);
  u16* kbf   = (u16*)(W + 48 * MB);
  u16* vtb   = (u16*)(W + 56 * MB);
  u16* ob    = (u16*)(W + 24 * MB);   // reuse Qb
  u16* x1b   = (u16*)(W + 64 * MB);
  u16* hb    = (u16*)(W + 32 * MB);   // [4096][4096] bf16, spans dead Kb/qb/kbf/vtb
  u16* ppb   = (u16*)(W + 72 * MB);   // 4 x 8MB bf16 split-K partials

  // Q/K convert + QKV weight transposes
  prep<<<8960, 256, 0, stream>>>(Q, K, Qb, Kb, Wq, Wq_t, Wk, Wk_t, Wv, Wv_t);

  // fused QKV projections (8-phase 256²)
  gemm8p_qkv<<<dim3(12, 16), 512, 0, stream>>>(Qb, Kb, Wq_t, Wk_t, Wv_t,
                                               bq, bk, bv, qb, kbf, vtb);

  // attention (128-q blocks) + folded Wo0/Wo/Wo2 transposes (blocks 0..1151)
  attn_k<<<1664, 512, 0, stream>>>(qb, kbf, vtb, mask, ob,
                                   Wo0, Wo0_t, Wo, Wo_t, Wo2, Wo2_t);

  // output proj: 8-phase split-K=4 (NT=4), bf16 partials -> fused combine+LN0
  gemm8p<1><<<dim3(4, 16, 4), 512, 0, stream>>>(ob, Wo0_t, nullptr, ppb, 1024, 1024, 1024, 256, 4);
  comb_ln<4, 0><<<2048, 256, 0, stream>>>(ppb, bo0, qb, g0, be0, x1b);

  // FFN: FF1 (8-phase, relu) -> FF2 (8-phase, split-K=4, bf16 partials) -> combine+LN1
  gemm8p<0><<<dim3(16, 16), 512, 0, stream>>>(x1b, Wo_t, bo, hb, 1024, 1024, 4096, 0, 16);
  gemm8p<1><<<dim3(4, 16, 4), 512, 0, stream>>>(hb, Wo2_t, nullptr, ppb, 4096, 4096, 1024, 1024, 16);
  comb_ln<4, 1><<<2048, 256, 0, stream>>>(ppb, bo2, x1b, g1, be1, d_out);
}

// Round 12
// 269.962 us; speedup vs baseline: 1.9173x; 1.0744x over previous
//
#include <hip/hip_runtime.h>
#include <hip/hip_bf16.h>

typedef unsigned short u16;
typedef __attribute__((ext_vector_type(4))) short bf16x4;
typedef __attribute__((ext_vector_type(8))) short bf16x8;
typedef __attribute__((ext_vector_type(4))) float f32x4;

// ---------- helpers ----------
static __device__ __forceinline__ u16 f2b(float f){
  union { float f; unsigned u; } v; v.f = f;
  unsigned r = v.u + 0x7fffu + ((v.u >> 16) & 1u);   // RNE
  return (u16)(r >> 16);
}
static __device__ __forceinline__ float b2f(u16 h){
  union { unsigned u; float f; } v; v.u = ((unsigned)h) << 16; return v.f;
}
static __device__ __forceinline__ void gld_lds16(const void* g, void* l){
  __builtin_amdgcn_global_load_lds((const __attribute__((address_space(1))) void*)g,
                                   (__attribute__((address_space(3))) void*)l, 16, 0, 0);
}

// ---------- prep: Q/K bf16 convert (compacted) + Wq/Wk/Wv transposes ----------
__global__ __launch_bounds__(256) void prep(const float* __restrict__ Q,
                                            const float* __restrict__ K,
                                            u16* __restrict__ Qb, u16* __restrict__ Kb,
                                            const float* __restrict__ Wq, u16* __restrict__ Wq_t,
                                            const float* __restrict__ Wk, u16* __restrict__ Wk_t,
                                            const float* __restrict__ Wv, u16* __restrict__ Wv_t){
  __shared__ float tile[64][65];
  const int id = blockIdx.x, t = threadIdx.x;
  if (id < 8192){
    const float* src; u16* dst;
    if (id < 4096){
      src = Q + (size_t)id * 1024; dst = Qb + (size_t)id * 1024;
    } else {
      int r = id - 4096;
      size_t ir = (size_t)r + (size_t)(r >> 10) * 512;   // skip rows 1024..1535 per batch
      src = K + ir * 1024; dst = Kb + (size_t)r * 1024;
    }
    const float4 v = *(const float4*)(src + t * 4);
    bf16x4 o;
    o[0] = (short)f2b(v.x); o[1] = (short)f2b(v.y);
    o[2] = (short)f2b(v.z); o[3] = (short)f2b(v.w);
    *(bf16x4*)(dst + t * 4) = o;
    return;
  }
  int wid = id - 8192;               // 0..767 : 3 x 256 tiles (Wq, Wk, Wv)
  int sel = wid >> 8, local = wid & 255;
  int bx = local & 15, by = local >> 4;
  const float* in  = (sel == 0) ? Wq   : (sel == 1) ? Wk   : Wv;
  u16*         out = (sel == 0) ? Wq_t : (sel == 1) ? Wk_t : Wv_t;
  const int k0 = by * 64, n0 = bx * 64;
  const int tr = t >> 4, tc = t & 15;
#pragma unroll
  for (int i = 0; i < 4; i++){
    int r = tr + i * 16;
    float4 v = *(const float4*)(in + (size_t)(k0 + r) * 1024 + n0 + tc * 4);
    tile[r][tc*4+0] = v.x; tile[r][tc*4+1] = v.y; tile[r][tc*4+2] = v.z; tile[r][tc*4+3] = v.w;
  }
  __syncthreads();
#pragma unroll
  for (int i = 0; i < 4; i++){
    int nr = tr + i * 16;
    bf16x4 pk;
#pragma unroll
    for (int j = 0; j < 4; j++) pk[j] = (short)f2b(tile[tc*4+j][nr]);
    *(bf16x4*)(out + (size_t)(n0 + nr) * 1024 + k0 + tc * 4) = pk;
  }
}

// ---------- 256x256 8-phase main loop (T2+T3+T4+T5), BK=64, 8 waves ----------
static __device__ __forceinline__ void loop8p(const u16* __restrict__ A,
                                              const u16* __restrict__ Bt,
                                              int lda, int ldb, int kbeg, int NT,
                                              int m0, int n0,
                                              u16 (*sA)[2][8192], u16 (*sB)[2][8192],
                                              f32x4 acc[8][4]){
  const int t = threadIdx.x, w = t >> 6, l = t & 63;
  const int wr = w >> 2, wc = w & 3;
  const int c = l & 15, g = l >> 4;
  const int sr = t >> 3, scb = (t & 7) << 4;

  auto stA = [&](int d, int h, int T){
#pragma unroll
    for (int i = 0; i < 2; i++){
      int row = i * 64 + sr;
      int Lb  = scb ^ ((row & 7) << 4);
      gld_lds16(A + (size_t)(m0 + h * 128 + row) * lda + kbeg + T * 64 + (Lb >> 1),
                (char*)&sA[d][h][0] + i * 8192 + t * 16);
    }
  };
  auto stB = [&](int d, int h, int T){
#pragma unroll
    for (int i = 0; i < 2; i++){
      int row = i * 64 + sr;
      int Lb  = scb ^ ((row & 7) << 4);
      gld_lds16(Bt + (size_t)(n0 + h * 128 + row) * ldb + kbeg + T * 64 + (Lb >> 1),
                (char*)&sB[d][h][0] + i * 8192 + t * 16);
    }
  };

  // prologue: B0(0),B1(0),A0(0),A1(0),B0(1),B1(1)
  stB(0, 0, 0); stB(0, 1, 0); stA(0, 0, 0); stA(0, 1, 0);
  stB(1, 0, 1); stB(1, 1, 1);

  bf16x8 bfr[4][2];
  for (int T = 0; T < NT; ++T){
    const int d = T & 1;
    const char* pa = (const char*)&sA[d][wr][0];
    const char* pb = (const char*)&sB[d][wc >> 1][0];
#pragma unroll
    for (int q = 0; q < 4; ++q){
      if (q == 0){
        if (T + 1 < NT) asm volatile("s_waitcnt vmcnt(4)" ::: "memory");
        else            asm volatile("s_waitcnt vmcnt(0)" ::: "memory");
        asm volatile("" ::: "memory");
        __builtin_amdgcn_s_barrier();
        asm volatile("" ::: "memory");
#pragma unroll
        for (int nf = 0; nf < 4; ++nf){
          int lr = (wc & 1) * 64 + nf * 16 + c;
#pragma unroll
          for (int ks = 0; ks < 2; ++ks)
            bfr[nf][ks] = *(const bf16x8*)(pb + lr * 128 + ((ks * 64 + g * 16) ^ ((lr & 7) << 4)));
        }
      }
      bf16x8 af[2][2];
#pragma unroll
      for (int mi = 0; mi < 2; ++mi){
        int lr = (q * 2 + mi) * 16 + c;
#pragma unroll
        for (int ks = 0; ks < 2; ++ks)
          af[mi][ks] = *(const bf16x8*)(pa + lr * 128 + ((ks * 64 + g * 16) ^ ((lr & 7) << 4)));
      }
      if      (q == 0){ if (T + 1 < NT) stA(d ^ 1, 0, T + 1); }
      else if (q == 1){ if (T + 1 < NT) stA(d ^ 1, 1, T + 1); }
      else if (q == 2){ if (T + 2 < NT) stB(d, 0, T + 2); }
      else            { if (T + 2 < NT) stB(d, 1, T + 2); }
      __builtin_amdgcn_s_setprio(1);
#pragma unroll
      for (int mi = 0; mi < 2; ++mi)
#pragma unroll
        for (int nf = 0; nf < 4; ++nf)
#pragma unroll
          for (int ks = 0; ks < 2; ++ks)
            acc[q * 2 + mi][nf] =
              __builtin_amdgcn_mfma_f32_16x16x32_bf16(af[mi][ks], bfr[nf][ks], acc[q * 2 + mi][nf], 0, 0, 0);
      __builtin_amdgcn_s_setprio(0);
      asm volatile("" ::: "memory");
      __builtin_amdgcn_s_barrier();
      asm volatile("" ::: "memory");
    }
  }
}

// ---------- LDS-staged coalesced epilogue: wave's C[128x64] -> 16B row stores ----------
// sl: 8KB per-wave LDS slice (sA/sB dead after loop8p's final barrier).
// Rows XOR-swizzled (G4); lgkmcnt+sched_barrier per rule 18; DS pipe in-order
// covers the pass-1-write-after-pass-0-read WAR.
template<typename F>
static __device__ __forceinline__ void epi_store(char* sl, u16* gbase, int ld,
                                                 int l, F val){
  const int c = l & 15, g = l >> 4;
#pragma unroll
  for (int p = 0; p < 2; ++p){
#pragma unroll
    for (int mi = 0; mi < 4; ++mi){
#pragma unroll
      for (int nf = 0; nf < 4; ++nf){
        int col2 = (nf * 16 + c) * 2;
#pragma unroll
        for (int r = 0; r < 4; ++r){
          int row = mi * 16 + 4 * g + r;
          *(u16*)(sl + row * 128 + (col2 ^ ((row & 7) << 4))) = f2b(val(p * 4 + mi, nf, r));
        }
      }
    }
    asm volatile("s_waitcnt lgkmcnt(0)" ::: "memory");
    __builtin_amdgcn_sched_barrier(0);
#pragma unroll
    for (int j = 0; j < 8; ++j){
      int row = (l >> 3) + j * 8;
      int ch  = (l & 7) * 16;
      bf16x8 v = *(const bf16x8*)(sl + row * 128 + (ch ^ ((row & 7) << 4)));
      *(bf16x8*)(gbase + (size_t)(p * 64 + row) * ld + (l & 7) * 8) = v;
    }
    __builtin_amdgcn_sched_barrier(0);
  }
}

// ---------- 8-phase GEMM with XCD-rect swizzle ----------
// EPI 0 (FF1, grid 16x16): bias+relu -> bf16. EPI 1 (grid 4x16x4): bf16 split-K partial.
template<int EPI>
__global__ __launch_bounds__(512, 2) void gemm8p(const u16* __restrict__ A,
                                                 const u16* __restrict__ Bt,
                                                 const float* __restrict__ bias,
                                                 void* __restrict__ outp,
                                                 int lda, int ldb, int ldout,
                                                 int ksz, int NT){
  __shared__ u16 sA[2][2][8192];
  __shared__ u16 sB[2][2][8192];
  const int t = threadIdx.x, w = t >> 6, l = t & 63;
  const int wr = w >> 2, wc = w & 3;
  const int c = l & 15;

  int m0, n0, zidx;
  if (EPI == 0){
    int lid = blockIdx.x + (blockIdx.y << 4);
    int xcd = lid & 7, slot = lid >> 3;
    int bx = ((xcd & 1) << 3) + (slot & 7);
    int by = ((xcd >> 1) << 2) + (slot >> 3);
    m0 = by * 256; n0 = bx * 256; zidx = 0;
  } else {
    int lid = blockIdx.x + (blockIdx.y << 2) + (blockIdx.z << 6);
    int xcd = lid & 7, slot = lid >> 3;
    int bx = slot & 3, rest = slot >> 2;
    int by = (xcd << 1) + (rest & 1);
    zidx = rest >> 1;
    m0 = by * 256; n0 = bx * 256;
  }

  f32x4 acc[8][4];
#pragma unroll
  for (int i = 0; i < 8; i++)
#pragma unroll
    for (int j = 0; j < 4; j++) acc[i][j] = (f32x4){0.f, 0.f, 0.f, 0.f};

  loop8p(A, Bt, lda, ldb, zidx * ksz, NT, m0, n0, sA, sB, acc);

  char* slw = (char*)&sA[0][0][0] + w * 8192;        // 8KB per-wave slice
  if (EPI == 0){
    float bv[4];
#pragma unroll
    for (int nf = 0; nf < 4; ++nf) bv[nf] = bias[n0 + wc * 64 + nf * 16 + c];
    u16* gb = (u16*)outp + (size_t)(m0 + wr * 128) * ldout + n0 + wc * 64;
    epi_store(slw, gb, ldout, l,
              [&](int mf, int nf, int r){ return fmaxf(acc[mf][nf][r] + bv[nf], 0.f); });
  } else {
    u16* gb = (u16*)outp + (size_t)zidx * (4096ull * 1024ull)
              + (size_t)(m0 + wr * 128) * 1024 + n0 + wc * 64;
    epi_store(slw, gb, 1024, l,
              [&](int mf, int nf, int r){ return acc[mf][nf][r]; });
  }
}

// ---------- fused QKV (8-phase 256², grid 12x16, XCD 3x8 rect); all outputs via LDS ----------
__global__ __launch_bounds__(512, 2) void gemm8p_qkv(const u16* __restrict__ Qb,
                                                     const u16* __restrict__ Kb,
                                                     const u16* __restrict__ Wq_t,
                                                     const u16* __restrict__ Wk_t,
                                                     const u16* __restrict__ Wv_t,
                                                     const float* __restrict__ bq,
                                                     const float* __restrict__ bk,
                                                     const float* __restrict__ bv,
                                                     u16* __restrict__ qb,
                                                     u16* __restrict__ kbf,
                                                     u16* __restrict__ vtb){
  __shared__ u16 sA[2][2][8192];
  __shared__ u16 sB[2][2][8192];
  int lid = blockIdx.x + blockIdx.y * 12;
  int xcd = lid & 7, slot = lid >> 3;
  int bx = (xcd & 3) * 3 + slot % 3;
  int by = ((xcd >> 2) << 3) + slot / 3;
  const int sel = bx >> 2;
  const u16* A    = sel ? Kb : Qb;
  const u16* Bt   = (sel == 0) ? Wq_t : (sel == 1) ? Wk_t : Wv_t;
  const float* bi = (sel == 0) ? bq   : (sel == 1) ? bk   : bv;
  const int t = threadIdx.x, w = t >> 6, l = t & 63;
  const int wr = w >> 2, wc = w & 3;
  const int c = l & 15, g = l >> 4;
  const int m0 = by * 256, n0 = (bx & 3) * 256;

  f32x4 acc[8][4];
#pragma unroll
  for (int i = 0; i < 8; i++)
#pragma unroll
    for (int j = 0; j < 4; j++) acc[i][j] = (f32x4){0.f, 0.f, 0.f, 0.f};

  loop8p(A, Bt, 1024, 1024, 0, 16, m0, n0, sA, sB, acc);

  if (sel == 2){
    // V: per-wave LDS transpose (16KB slices), then coalesced vt row stores
    u16* sl = (w < 4) ? (&sA[0][0][0] + w * 8192) : (&sB[0][0][0] + (w - 4) * 8192);
#pragma unroll
    for (int nf = 0; nf < 4; ++nf){
      int n = n0 + wc * 64 + nf * 16 + c;
      float bv_ = bi[n];
#pragma unroll
      for (int mf = 0; mf < 8; ++mf){
        bf16x4 pk;
#pragma unroll
        for (int r = 0; r < 4; ++r) pk[r] = (short)f2b(acc[mf][nf][r] + bv_);
        *(bf16x4*)(sl + (nf * 16 + c) * 128 + mf * 16 + 4 * g) = pk;
      }
    }
    asm volatile("s_waitcnt lgkmcnt(0)" ::: "memory");
    __builtin_amdgcn_sched_barrier(0);
    const int mg = m0 + wr * 128;
    const int bb = mg >> 10, kb0 = mg & 1023;
    u16* vbase = vtb + ((size_t)bb << 20) + kb0;
#pragma unroll
    for (int j = 0; j < 16; ++j){
      int nl  = (l >> 4) + j * 4;
      int kl  = (l & 15) * 8;
      bf16x8 v = *(const bf16x8*)(sl + nl * 128 + kl);
      *(bf16x8*)(vbase + (size_t)(n0 + wc * 64 + nl) * 1024 + kl) = v;
    }
  } else {
    char* slw = (char*)&sA[0][0][0] + w * 8192;
    float bv[4];
#pragma unroll
    for (int nf = 0; nf < 4; ++nf) bv[nf] = bi[n0 + wc * 64 + nf * 16 + c];
    u16* out = sel ? kbf : qb;
    u16* gb  = out + (size_t)(m0 + wr * 128) * 1024 + n0 + wc * 64;
    epi_store(slw, gb, 1024, l,
              [&](int mf, int nf, int r){ return acc[mf][nf][r] + bv[nf]; });
  }
}

// ---------- combine NP bf16 partials + bias + residual, then LayerNorm ----------
// 2 rows per block; 128 threads per row; 8 cols/thread (16B loads, G13).
template<int NP, int F32OUT>
__global__ __launch_bounds__(256) void comb_ln(const u16* __restrict__ pp,
                                               const float* __restrict__ bias,
                                               const u16* __restrict__ res,
                                               const float* __restrict__ gw,
                                               const float* __restrict__ bw,
                                               void* __restrict__ outp){
  const int t = threadIdx.x, w = t >> 6;
  const int row = blockIdx.x * 2 + (t >> 7);
  const int u = t & 127;
  const size_t i8 = (size_t)row * 1024 + u * 8;
  bf16x8 rv = *(const bf16x8*)(res + i8);
  float4 b0 = *(const float4*)(bias + u * 8);
  float4 b1 = *(const float4*)(bias + u * 8 + 4);
  float xs[8] = {b0.x, b0.y, b0.z, b0.w, b1.x, b1.y, b1.z, b1.w};
#pragma unroll
  for (int j = 0; j < 8; j++) xs[j] += b2f((u16)rv[j]);
#pragma unroll
  for (int z = 0; z < NP; z++){
    bf16x8 p = *(const bf16x8*)(pp + (size_t)z * (4096ull * 1024ull) + i8);
#pragma unroll
    for (int j = 0; j < 8; j++) xs[j] += b2f((u16)p[j]);
  }
  float s = 0.f, sq = 0.f;
#pragma unroll
  for (int j = 0; j < 8; j++){ s += xs[j]; sq += xs[j] * xs[j]; }
#pragma unroll
  for (int o = 32; o; o >>= 1){ s += __shfl_xor(s, o); sq += __shfl_xor(sq, o); }
  __shared__ float rs[4], rq[4];
  if ((t & 63) == 0){ rs[w] = s; rq[w] = sq; }
  __syncthreads();
  const int wb = (t >> 7) * 2;                 // row0 -> waves 0,1 ; row1 -> waves 2,3
  s  = rs[wb] + rs[wb + 1];
  sq = rq[wb] + rq[wb + 1];
  const float mu   = s * (1.f / 1024.f);
  const float var  = sq * (1.f / 1024.f) - mu * mu;
  const float rstd = rsqrtf(var + 1e-5f);
  float4 g0 = *(const float4*)(gw + u * 8);
  float4 g1 = *(const float4*)(gw + u * 8 + 4);
  float4 w0 = *(const float4*)(bw + u * 8);
  float4 w1 = *(const float4*)(bw + u * 8 + 4);
  float gv[8] = {g0.x, g0.y, g0.z, g0.w, g1.x, g1.y, g1.z, g1.w};
  float wv[8] = {w0.x, w0.y, w0.z, w0.w, w1.x, w1.y, w1.z, w1.w};
  if (F32OUT){
    float4 o0, o1;
    o0.x = (xs[0]-mu)*rstd*gv[0] + wv[0]; o0.y = (xs[1]-mu)*rstd*gv[1] + wv[1];
    o0.z = (xs[2]-mu)*rstd*gv[2] + wv[2]; o0.w = (xs[3]-mu)*rstd*gv[3] + wv[3];
    o1.x = (xs[4]-mu)*rstd*gv[4] + wv[4]; o1.y = (xs[5]-mu)*rstd*gv[5] + wv[5];
    o1.z = (xs[6]-mu)*rstd*gv[6] + wv[6]; o1.w = (xs[7]-mu)*rstd*gv[7] + wv[7];
    *(float4*)((float*)outp + i8)     = o0;
    *(float4*)((float*)outp + i8 + 4) = o1;
  } else {
    bf16x8 o;
#pragma unroll
    for (int j = 0; j < 8; j++) o[j] = (short)f2b((xs[j]-mu)*rstd*gv[j] + wv[j]);
    *(bf16x8*)((u16*)outp + i8) = o;
  }
}

// ---------- fused masked attention (128 q-rows/block, 8 waves) + folded transposes ----------
#define ATTN_STEP(IT, CUR, MC) do{                                              \
  if ((IT) < 15) asm volatile("s_waitcnt vmcnt(4)" ::: "memory");               \
  else           asm volatile("s_waitcnt vmcnt(0)" ::: "memory");               \
  __builtin_amdgcn_s_barrier();                                                 \
  asm volatile("" ::: "memory");                                                \
  if ((IT) < 15) stage((CUR) ^ 1, ((IT) + 1) * 64);                             \
  asm volatile("" ::: "memory");                                                \
  const char* kt = (const char*)sK[(CUR)];                                      \
  f32x4 st[4];                                                                  \
  _Pragma("unroll")                                                             \
  for (int nf = 0; nf < 4; nf++){                                               \
    const char* kr = kt + (nf * 16 + c) * 128;                                  \
    bf16x8 ak0 = *(const bf16x8*)(kr + ((g * 16) ^ sw));                        \
    bf16x8 ak1 = *(const bf16x8*)(kr + ((64 + g * 16) ^ sw));                   \
    f32x4 z = (f32x4){0.f, 0.f, 0.f, 0.f};                                      \
    z = __builtin_amdgcn_mfma_f32_16x16x32_bf16(ak0, bq0, z, 0, 0, 0);          \
    z = __builtin_amdgcn_mfma_f32_16x16x32_bf16(ak1, bq1, z, 0, 0, 0);          \
    st[nf] = z;                                                                 \
  }                                                                             \
  float rsum = 0.f;                                                             \
  bf16x4 pb[4];                                                                 \
  _Pragma("unroll")                                                             \
  for (int nf = 0; nf < 4; nf++)                                                \
    _Pragma("unroll")                                                           \
    for (int r = 0; r < 4; r++){                                                \
      float p = __expf(fmaf(st[nf][r], 0.03125f, MC[nf][r]) - 8.f);             \
      rsum += p;                                                                \
      pb[nf][r] = (short)f2b(p);                                                \
    }                                                                           \
  if ((IT) < 14){                                                               \
    _Pragma("unroll")                                                           \
    for (int nf = 0; nf < 4; nf++)                                              \
      MC[nf] = *(const f32x4*)(mbase + ((IT) + 2) * 64 + nf * 16 + g * 4);      \
  }                                                                             \
  rsum += __shfl_xor(rsum, 16); rsum += __shfl_xor(rsum, 32);                   \
  lsum += rsum;                                                                 \
  const char* vtc = (const char*)sV[(CUR)];                                     \
  __builtin_amdgcn_s_setprio(1);                                                \
  _Pragma("unroll")                                                             \
  for (int f = 0; f < 4; f++){                                                  \
    const char* vr = vtc + (f * 16 + c) * 128;                                  \
    _Pragma("unroll")                                                           \
    for (int nf = 0; nf < 4; nf++){                                             \
      bf16x4 av = *(const bf16x4*)(vr + ((nf * 32 + g * 8) ^ sw));              \
      acc[f] = __builtin_amdgcn_mfma_f32_16x16x16bf16_1k(av, pb[nf], acc[f], 0, 0, 0); \
    }                                                                           \
  }                                                                             \
  __builtin_amdgcn_s_setprio(0);                                                \
}while(0)

__global__ __launch_bounds__(512, 4) void attn_k(const u16* __restrict__ qb,
                                                 const u16* __restrict__ kb,
                                                 const u16* __restrict__ vt,
                                                 const float* __restrict__ mask,
                                                 u16* __restrict__ ob,
                                                 const float* __restrict__ Wo0, u16* __restrict__ Wo0_t,
                                                 const float* __restrict__ Wo,  u16* __restrict__ Wo_t,
                                                 const float* __restrict__ Wo2, u16* __restrict__ Wo2_t){
  __shared__ u16 sK[2][4096];   // [key 64][dh 64], row stride 128B, XOR-swizzled
  __shared__ u16 sV[2][4096];   // [dh 64][key 64], row stride 128B, XOR-swizzled

  const int id = blockIdx.x, t = threadIdx.x;

  if (id < 1152){
    // ---- folded weight transposes (2 x 64x64 tiles per 512-thread block) ----
    const int half = t >> 8, tt = t & 255;
    const int tileid = id * 2 + half;
    const float* in; u16* out; int Kd, N, bx, by;
    if (tileid < 256){
      bx = tileid & 15; by = tileid >> 4; Kd = 1024; N = 1024; in = Wo0; out = Wo0_t;
    } else if (tileid < 1280){
      int lo = tileid - 256; bx = lo & 63; by = lo >> 6; Kd = 1024; N = 4096; in = Wo; out = Wo_t;
    } else {
      int lo = tileid - 1280; bx = lo & 15; by = lo >> 4; Kd = 4096; N = 1024; in = Wo2; out = Wo2_t;
    }
    u16* tl = half ? &sV[0][0] : &sK[0][0];
    const int k0 = by * 64, n0 = bx * 64;
    const int tr = tt >> 4, tc = tt & 15;
#pragma unroll
    for (int i = 0; i < 4; i++){
      int r = tr + i * 16;
      float4 v = *(const float4*)(in + (size_t)(k0 + r) * N + n0 + tc * 4);
      tl[r * 65 + tc * 4 + 0] = f2b(v.x); tl[r * 65 + tc * 4 + 1] = f2b(v.y);
      tl[r * 65 + tc * 4 + 2] = f2b(v.z); tl[r * 65 + tc * 4 + 3] = f2b(v.w);
    }
    __syncthreads();
#pragma unroll
    for (int i = 0; i < 4; i++){
      int nr = tr + i * 16;
      bf16x4 pk;
#pragma unroll
      for (int j = 0; j < 4; j++) pk[j] = (short)tl[(tc * 4 + j) * 65 + nr];
      *(bf16x4*)(out + (size_t)(n0 + nr) * Kd + k0 + tc * 4) = pk;
    }
    return;
  }

  // ---- attention: 128 q-rows per block, K/V staged once for 8 waves ----
  const int aid = id - 1152;                        // 0..511
  const int w = t >> 6, l = t & 63;
  const int c = l & 15, g = l >> 4;
  const int q0 = (aid & 7) * 128;
  const int h  = (aid >> 3) & 15, b = aid >> 7;
  const int qrow = q0 + w * 16 + c;
  const size_t qoff = ((size_t)(b * 1024 + qrow)) * 1024 + h * 64;
  const bf16x8 bq0 = *(const bf16x8*)(qb + qoff + g * 8);
  const bf16x8 bq1 = *(const bf16x8*)(qb + qoff + 32 + g * 8);
  const u16* kbase = kb + ((size_t)b * 1024) * 1024 + h * 64;
  const u16* vbase = vt + ((size_t)b << 20) + (size_t)(h * 64) * 1024;
  const float* mbase = mask + ((size_t)(h * 4 + b) * 1024 + qrow) * 1024;

  const int srow = t >> 3, slc = t & 7;             // 512 threads cover 64 rows x 128B

  auto stage = [&](int buf, int kv){
    int L = (slc * 16) ^ ((srow & 7) << 4);
    gld_lds16(kbase + (size_t)(kv + srow) * 1024 + (L >> 1), &sK[buf][t * 8]);
    gld_lds16(vbase + (size_t)srow * 1024 + kv + (L >> 1),   &sV[buf][t * 8]);
  };

  float lsum = 0.f;
  f32x4 acc[4];
#pragma unroll
  for (int f = 0; f < 4; f++) acc[f] = (f32x4){0.f, 0.f, 0.f, 0.f};

  stage(0, 0);
  asm volatile("" ::: "memory");
  f32x4 mA[4], mB[4];
#pragma unroll
  for (int nf = 0; nf < 4; nf++) mA[nf] = *(const f32x4*)(mbase + nf * 16 + g * 4);
  asm volatile("" ::: "memory");
#pragma unroll
  for (int nf = 0; nf < 4; nf++) mB[nf] = *(const f32x4*)(mbase + 64 + nf * 16 + g * 4);

  const int sw = (c & 7) << 4;
  for (int ii = 0; ii < 8; ++ii){
    ATTN_STEP(2 * ii,     0, mA);
    ATTN_STEP(2 * ii + 1, 1, mB);
  }

  // epilogue: barrier, O^T -> LDS, coalesced stores
  __syncthreads();
  const float inv = 1.f / lsum;
  u16* sO = &sK[0][0];                               // [128 rows][64 dh] = 16KB = all of sK
#pragma unroll
  for (int f = 0; f < 4; f++){
    bf16x4 pk;
#pragma unroll
    for (int r = 0; r < 4; r++) pk[r] = (short)f2b(acc[f][r] * inv);
    *(bf16x4*)(sO + (w * 16 + c) * 64 + f * 16 + 4 * g) = pk;
  }
  asm volatile("s_waitcnt lgkmcnt(0)" ::: "memory");
  __builtin_amdgcn_sched_barrier(0);
  {
    int rl  = w * 16 + (l >> 2);
    int d0  = (l & 3) * 16;
    bf16x8 v0 = *(const bf16x8*)(sO + rl * 64 + d0);
    bf16x8 v1 = *(const bf16x8*)(sO + rl * 64 + d0 + 8);
    u16* dst = ob + ((size_t)(b * 1024 + q0 + rl)) * 1024 + h * 64 + d0;
    *(bf16x8*)(dst)     = v0;
    *(bf16x8*)(dst + 8) = v1;
  }
}

// ---------- launch ----------
extern "C" void kernel_launch(void* const* d_in, const int* in_sizes, int n_in,
                              void* d_out, int out_size, void* d_ws, size_t ws_size,
                              hipStream_t stream){
  const float* Q    = (const float*)d_in[0];
  const float* K    = (const float*)d_in[1];
  const float* mask = (const float*)d_in[2];
  const float* Wq   = (const float*)d_in[4];  const float* bq  = (const float*)d_in[5];
  const float* Wk   = (const float*)d_in[6];  const float* bk  = (const float*)d_in[7];
  const float* Wv   = (const float*)d_in[8];  const float* bv  = (const float*)d_in[9];
  const float* Wo0  = (const float*)d_in[10]; const float* bo0 = (const float*)d_in[11];
  const float* Wo   = (const float*)d_in[12]; const float* bo  = (const float*)d_in[13];
  const float* Wo2  = (const float*)d_in[14]; const float* bo2 = (const float*)d_in[15];
  const float* g0   = (const float*)d_in[16]; const float* be0 = (const float*)d_in[17];
  const float* g1   = (const float*)d_in[18]; const float* be1 = (const float*)d_in[19];

  uint8_t* W = (uint8_t*)d_ws;
  const size_t MB = 1024ull * 1024ull;
  u16* Wq_t  = (u16*)(W + 0);
  u16* Wk_t  = (u16*)(W + 2  * MB);
  u16* Wv_t  = (u16*)(W + 4  * MB);
  u16* Wo0_t = (u16*)(W + 6  * MB);
  u16* Wo_t  = (u16*)(W + 8  * MB);   // [4096][1024]
  u16* Wo2_t = (u16*)(W + 16 * MB);   // [1024][4096]
  u16* Qb    = (u16*)(W + 24 * MB);
  u16* Kb    = (u16*)(W + 32 * MB);
  u16* qb    = (u16*)(W + 40 * MB);
  u16* kbf   = (u16*)(W + 48 * MB);
  u16* vtb   = (u16*)(W + 56 * MB);
  u16* ob    = (u16*)(W + 24 * MB);   // reuse Qb
  u16* x1b   = (u16*)(W + 64 * MB);
  u16* hb    = (u16*)(W + 32 * MB);   // [4096][4096] bf16, spans dead Kb/qb/kbf/vtb
  u16* ppb   = (u16*)(W + 72 * MB);   // 4 x 8MB bf16 split-K partials

  // Q/K convert + QKV weight transposes
  prep<<<8960, 256, 0, stream>>>(Q, K, Qb, Kb, Wq, Wq_t, Wk, Wk_t, Wv, Wv_t);

  // fused QKV projections (8-phase 256²)
  gemm8p_qkv<<<dim3(12, 16), 512, 0, stream>>>(Qb, Kb, Wq_t, Wk_t, Wv_t,
                                               bq, bk, bv, qb, kbf, vtb);

  // attention (128-q blocks) + folded Wo0/Wo/Wo2 transposes (blocks 0..1151)
  attn_k<<<1664, 512, 0, stream>>>(qb, kbf, vtb, mask, ob,
                                   Wo0, Wo0_t, Wo, Wo_t, Wo2, Wo2_t);

  // output proj: 8-phase split-K=4 (NT=4), bf16 partials -> fused combine+LN0
  gemm8p<1><<<dim3(4, 16, 4), 512, 0, stream>>>(ob, Wo0_t, nullptr, ppb, 1024, 1024, 1024, 256, 4);
  comb_ln<4, 0><<<2048, 256, 0, stream>>>(ppb, bo0, qb, g0, be0, x1b);

  // FFN: FF1 (8-phase, relu) -> FF2 (8-phase, split-K=4, bf16 partials) -> combine+LN1
  gemm8p<0><<<dim3(16, 16), 512, 0, stream>>>(x1b, Wo_t, bo, hb, 1024, 1024, 4096, 0, 16);
  gemm8p<1><<<dim3(4, 16, 4), 512, 0, stream>>>(hb, Wo2_t, nullptr, ppb, 4096, 4096, 1024, 1024, 16);
  comb_ln<4, 1><<<2048, 256, 0, stream>>>(ppb, bo2, x1b, g1, be1, d_out);
}

// Round 14
// 260.447 us; speedup vs baseline: 1.9874x; 1.0365x over previous
//
#include <hip/hip_runtime.h>
#include <hip/hip_bf16.h>

typedef unsigned short u16;
typedef __attribute__((ext_vector_type(4))) short bf16x4;
typedef __attribute__((ext_vector_type(8))) short bf16x8;
typedef __attribute__((ext_vector_type(4))) float f32x4;

// ---------- helpers ----------
static __device__ __forceinline__ u16 f2b(float f){
  union { float f; unsigned u; } v; v.f = f;
  unsigned r = v.u + 0x7fffu + ((v.u >> 16) & 1u);   // RNE
  return (u16)(r >> 16);
}
static __device__ __forceinline__ float b2f(u16 h){
  union { unsigned u; float f; } v; v.u = ((unsigned)h) << 16; return v.f;
}
static __device__ __forceinline__ void gld_lds16(const void* g, void* l){
  __builtin_amdgcn_global_load_lds((const __attribute__((address_space(1))) void*)g,
                                   (__attribute__((address_space(3))) void*)l, 16, 0, 0);
}

// ---------- prep: Q/K bf16 convert (compacted) + Wq/Wk/Wv transposes ----------
__global__ __launch_bounds__(256) void prep(const float* __restrict__ Q,
                                            const float* __restrict__ K,
                                            u16* __restrict__ Qb, u16* __restrict__ Kb,
                                            const float* __restrict__ Wq, u16* __restrict__ Wq_t,
                                            const float* __restrict__ Wk, u16* __restrict__ Wk_t,
                                            const float* __restrict__ Wv, u16* __restrict__ Wv_t){
  __shared__ float tile[64][65];
  const int id = blockIdx.x, t = threadIdx.x;
  if (id < 8192){
    const float* src; u16* dst;
    if (id < 4096){
      src = Q + (size_t)id * 1024; dst = Qb + (size_t)id * 1024;
    } else {
      int r = id - 4096;
      size_t ir = (size_t)r + (size_t)(r >> 10) * 512;   // skip rows 1024..1535 per batch
      src = K + ir * 1024; dst = Kb + (size_t)r * 1024;
    }
    const float4 v = *(const float4*)(src + t * 4);
    bf16x4 o;
    o[0] = (short)f2b(v.x); o[1] = (short)f2b(v.y);
    o[2] = (short)f2b(v.z); o[3] = (short)f2b(v.w);
    *(bf16x4*)(dst + t * 4) = o;
    return;
  }
  int wid = id - 8192;               // 0..767 : 3 x 256 tiles (Wq, Wk, Wv)
  int sel = wid >> 8, local = wid & 255;
  int bx = local & 15, by = local >> 4;
  const float* in  = (sel == 0) ? Wq   : (sel == 1) ? Wk   : Wv;
  u16*         out = (sel == 0) ? Wq_t : (sel == 1) ? Wk_t : Wv_t;
  const int k0 = by * 64, n0 = bx * 64;
  const int tr = t >> 4, tc = t & 15;
#pragma unroll
  for (int i = 0; i < 4; i++){
    int r = tr + i * 16;
    float4 v = *(const float4*)(in + (size_t)(k0 + r) * 1024 + n0 + tc * 4);
    tile[r][tc*4+0] = v.x; tile[r][tc*4+1] = v.y; tile[r][tc*4+2] = v.z; tile[r][tc*4+3] = v.w;
  }
  __syncthreads();
#pragma unroll
  for (int i = 0; i < 4; i++){
    int nr = tr + i * 16;
    bf16x4 pk;
#pragma unroll
    for (int j = 0; j < 4; j++) pk[j] = (short)f2b(tile[tc*4+j][nr]);
    *(bf16x4*)(out + (size_t)(n0 + nr) * 1024 + k0 + tc * 4) = pk;
  }
}

// ---------- 256x256 8-phase main loop (T2+T3+T4+T5), BK=64, 8 waves ----------
static __device__ __forceinline__ void loop8p(const u16* __restrict__ A,
                                              const u16* __restrict__ Bt,
                                              int lda, int ldb, int kbeg, int NT,
                                              int m0, int n0,
                                              u16 (*sA)[2][8192], u16 (*sB)[2][8192],
                                              f32x4 acc[8][4]){
  const int t = threadIdx.x, w = t >> 6, l = t & 63;
  const int wr = w >> 2, wc = w & 3;
  const int c = l & 15, g = l >> 4;
  const int sr = t >> 3, scb = (t & 7) << 4;

  auto stA = [&](int d, int h, int T){
#pragma unroll
    for (int i = 0; i < 2; i++){
      int row = i * 64 + sr;
      int Lb  = scb ^ ((row & 7) << 4);
      gld_lds16(A + (size_t)(m0 + h * 128 + row) * lda + kbeg + T * 64 + (Lb >> 1),
                (char*)&sA[d][h][0] + i * 8192 + t * 16);
    }
  };
  auto stB = [&](int d, int h, int T){
#pragma unroll
    for (int i = 0; i < 2; i++){
      int row = i * 64 + sr;
      int Lb  = scb ^ ((row & 7) << 4);
      gld_lds16(Bt + (size_t)(n0 + h * 128 + row) * ldb + kbeg + T * 64 + (Lb >> 1),
                (char*)&sB[d][h][0] + i * 8192 + t * 16);
    }
  };

  // prologue: B0(0),B1(0),A0(0),A1(0),B0(1),B1(1)
  stB(0, 0, 0); stB(0, 1, 0); stA(0, 0, 0); stA(0, 1, 0);
  stB(1, 0, 1); stB(1, 1, 1);

  bf16x8 bfr[4][2];
  for (int T = 0; T < NT; ++T){
    const int d = T & 1;
    const char* pa = (const char*)&sA[d][wr][0];
    const char* pb = (const char*)&sB[d][wc >> 1][0];
#pragma unroll
    for (int q = 0; q < 4; ++q){
      if (q == 0){
        if (T + 1 < NT) asm volatile("s_waitcnt vmcnt(4)" ::: "memory");
        else            asm volatile("s_waitcnt vmcnt(0)" ::: "memory");
        asm volatile("" ::: "memory");
        __builtin_amdgcn_s_barrier();
        asm volatile("" ::: "memory");
#pragma unroll
        for (int nf = 0; nf < 4; ++nf){
          int lr = (wc & 1) * 64 + nf * 16 + c;
#pragma unroll
          for (int ks = 0; ks < 2; ++ks)
            bfr[nf][ks] = *(const bf16x8*)(pb + lr * 128 + ((ks * 64 + g * 16) ^ ((lr & 7) << 4)));
        }
      }
      bf16x8 af[2][2];
#pragma unroll
      for (int mi = 0; mi < 2; ++mi){
        int lr = (q * 2 + mi) * 16 + c;
#pragma unroll
        for (int ks = 0; ks < 2; ++ks)
          af[mi][ks] = *(const bf16x8*)(pa + lr * 128 + ((ks * 64 + g * 16) ^ ((lr & 7) << 4)));
      }
      if      (q == 0){ if (T + 1 < NT) stA(d ^ 1, 0, T + 1); }
      else if (q == 1){ if (T + 1 < NT) stA(d ^ 1, 1, T + 1); }
      else if (q == 2){ if (T + 2 < NT) stB(d, 0, T + 2); }
      else            { if (T + 2 < NT) stB(d, 1, T + 2); }
      __builtin_amdgcn_s_setprio(1);
#pragma unroll
      for (int mi = 0; mi < 2; ++mi)
#pragma unroll
        for (int nf = 0; nf < 4; ++nf)
#pragma unroll
          for (int ks = 0; ks < 2; ++ks)
            acc[q * 2 + mi][nf] =
              __builtin_amdgcn_mfma_f32_16x16x32_bf16(af[mi][ks], bfr[nf][ks], acc[q * 2 + mi][nf], 0, 0, 0);
      __builtin_amdgcn_s_setprio(0);
      asm volatile("" ::: "memory");
      __builtin_amdgcn_s_barrier();
      asm volatile("" ::: "memory");
    }
  }
}

// ---------- LDS-staged coalesced epilogue: wave's C[128x64] -> 16B row stores ----------
template<typename F>
static __device__ __forceinline__ void epi_store(char* sl, u16* gbase, int ld,
                                                 int l, F val){
  const int c = l & 15, g = l >> 4;
#pragma unroll
  for (int p = 0; p < 2; ++p){
#pragma unroll
    for (int mi = 0; mi < 4; ++mi){
#pragma unroll
      for (int nf = 0; nf < 4; ++nf){
        int col2 = (nf * 16 + c) * 2;
#pragma unroll
        for (int r = 0; r < 4; ++r){
          int row = mi * 16 + 4 * g + r;
          *(u16*)(sl + row * 128 + (col2 ^ ((row & 7) << 4))) = f2b(val(p * 4 + mi, nf, r));
        }
      }
    }
    asm volatile("s_waitcnt lgkmcnt(0)" ::: "memory");
    __builtin_amdgcn_sched_barrier(0);
#pragma unroll
    for (int j = 0; j < 8; ++j){
      int row = (l >> 3) + j * 8;
      int ch  = (l & 7) * 16;
      bf16x8 v = *(const bf16x8*)(sl + row * 128 + (ch ^ ((row & 7) << 4)));
      *(bf16x8*)(gbase + (size_t)(p * 64 + row) * ld + (l & 7) * 8) = v;
    }
    __builtin_amdgcn_sched_barrier(0);
  }
}

// ---------- 8-phase GEMM with XCD-rect swizzle ----------
// EPI 0 (FF1, grid 16x16): bias+relu -> bf16. EPI 1 (grid 4x16x4): bf16 split-K partial.
template<int EPI>
__global__ __launch_bounds__(512, 2) void gemm8p(const u16* __restrict__ A,
                                                 const u16* __restrict__ Bt,
                                                 const float* __restrict__ bias,
                                                 void* __restrict__ outp,
                                                 int lda, int ldb, int ldout,
                                                 int ksz, int NT){
  __shared__ u16 sA[2][2][8192];
  __shared__ u16 sB[2][2][8192];
  const int t = threadIdx.x, w = t >> 6, l = t & 63;
  const int wr = w >> 2, wc = w & 3;
  const int c = l & 15;

  int m0, n0, zidx;
  if (EPI == 0){
    int lid = blockIdx.x + (blockIdx.y << 4);
    int xcd = lid & 7, slot = lid >> 3;
    int bx = ((xcd & 1) << 3) + (slot & 7);
    int by = ((xcd >> 1) << 2) + (slot >> 3);
    m0 = by * 256; n0 = bx * 256; zidx = 0;
  } else {
    int lid = blockIdx.x + (blockIdx.y << 2) + (blockIdx.z << 6);
    int xcd = lid & 7, slot = lid >> 3;
    int bx = slot & 3, rest = slot >> 2;
    int by = (xcd << 1) + (rest & 1);
    zidx = rest >> 1;
    m0 = by * 256; n0 = bx * 256;
  }

  f32x4 acc[8][4];
#pragma unroll
  for (int i = 0; i < 8; i++)
#pragma unroll
    for (int j = 0; j < 4; j++) acc[i][j] = (f32x4){0.f, 0.f, 0.f, 0.f};

  loop8p(A, Bt, lda, ldb, zidx * ksz, NT, m0, n0, sA, sB, acc);

  char* slw = (char*)&sA[0][0][0] + w * 8192;        // 8KB per-wave slice
  if (EPI == 0){
    float bv[4];
#pragma unroll
    for (int nf = 0; nf < 4; ++nf) bv[nf] = bias[n0 + wc * 64 + nf * 16 + c];
    u16* gb = (u16*)outp + (size_t)(m0 + wr * 128) * ldout + n0 + wc * 64;
    epi_store(slw, gb, ldout, l,
              [&](int mf, int nf, int r){ return fmaxf(acc[mf][nf][r] + bv[nf], 0.f); });
  } else {
    u16* gb = (u16*)outp + (size_t)zidx * (4096ull * 1024ull)
              + (size_t)(m0 + wr * 128) * 1024 + n0 + wc * 64;
    epi_store(slw, gb, 1024, l,
              [&](int mf, int nf, int r){ return acc[mf][nf][r]; });
  }
}

// ---------- fused QKV (blocks 0..191: 8-phase 256² GEMM; 192..1343: Wo0/Wo/Wo2 transposes) ----------
__global__ __launch_bounds__(512, 2) void gemm8p_qkv(const u16* __restrict__ Qb,
                                                     const u16* __restrict__ Kb,
                                                     const u16* __restrict__ Wq_t,
                                                     const u16* __restrict__ Wk_t,
                                                     const u16* __restrict__ Wv_t,
                                                     const float* __restrict__ bq,
                                                     const float* __restrict__ bk,
                                                     const float* __restrict__ bv,
                                                     u16* __restrict__ qb,
                                                     u16* __restrict__ kbf,
                                                     u16* __restrict__ vtb,
                                                     const float* __restrict__ Wo0, u16* __restrict__ Wo0_t,
                                                     const float* __restrict__ Wo,  u16* __restrict__ Wo_t,
                                                     const float* __restrict__ Wo2, u16* __restrict__ Wo2_t){
  __shared__ u16 sA[2][2][8192];
  __shared__ u16 sB[2][2][8192];
  const int id = blockIdx.x, t = threadIdx.x;

  if (id >= 192){
    // ---- folded weight transposes: 2 x 64x64 tiles per 512-thread block,
    // 1152 blocks -> 2304 tiles = Wo0(256) + Wo(1024) + Wo2(1024). ----
    const int half = t >> 8, tt = t & 255;
    const int tileid = (id - 192) * 2 + half;          // 0..2303
    const float* in; u16* out; int Kd, N, bx, by;
    if (tileid < 256){
      bx = tileid & 15; by = tileid >> 4; Kd = 1024; N = 1024; in = Wo0; out = Wo0_t;
    } else if (tileid < 1280){
      int lo = tileid - 256; bx = lo & 63; by = lo >> 6; Kd = 1024; N = 4096; in = Wo; out = Wo_t;
    } else {
      int lo = tileid - 1280; bx = lo & 15; by = lo >> 4; Kd = 4096; N = 1024; in = Wo2; out = Wo2_t;
    }
    u16* tl = (u16*)&sA[0][0][0] + half * 4160;        // 64x65 u16 per half
    const int k0 = by * 64, n0 = bx * 64;
    const int tr = tt >> 4, tc = tt & 15;
#pragma unroll
    for (int i = 0; i < 4; i++){
      int r = tr + i * 16;
      float4 v = *(const float4*)(in + (size_t)(k0 + r) * N + n0 + tc * 4);
      tl[r * 65 + tc * 4 + 0] = f2b(v.x); tl[r * 65 + tc * 4 + 1] = f2b(v.y);
      tl[r * 65 + tc * 4 + 2] = f2b(v.z); tl[r * 65 + tc * 4 + 3] = f2b(v.w);
    }
    __syncthreads();
#pragma unroll
    for (int i = 0; i < 4; i++){
      int nr = tr + i * 16;
      bf16x4 pk;
#pragma unroll
      for (int j = 0; j < 4; j++) pk[j] = (short)tl[(tc * 4 + j) * 65 + nr];
      *(bf16x4*)(out + (size_t)(n0 + nr) * Kd + k0 + tc * 4) = pk;
    }
    return;
  }

  int lid = id;
  int xcd = lid & 7, slot = lid >> 3;
  int bx = (xcd & 3) * 3 + slot % 3;
  int by = ((xcd >> 2) << 3) + slot / 3;
  const int sel = bx >> 2;
  const u16* A    = sel ? Kb : Qb;
  const u16* Bt   = (sel == 0) ? Wq_t : (sel == 1) ? Wk_t : Wv_t;
  const float* bi = (sel == 0) ? bq   : (sel == 1) ? bk   : bv;
  const int w = t >> 6, l = t & 63;
  const int wr = w >> 2, wc = w & 3;
  const int c = l & 15, g = l >> 4;
  const int m0 = by * 256, n0 = (bx & 3) * 256;

  f32x4 acc[8][4];
#pragma unroll
  for (int i = 0; i < 8; i++)
#pragma unroll
    for (int j = 0; j < 4; j++) acc[i][j] = (f32x4){0.f, 0.f, 0.f, 0.f};

  loop8p(A, Bt, 1024, 1024, 0, 16, m0, n0, sA, sB, acc);

  if (sel == 2){
    // V: per-wave LDS transpose (16KB slices), then coalesced vt row stores
    u16* sl = (w < 4) ? (&sA[0][0][0] + w * 8192) : (&sB[0][0][0] + (w - 4) * 8192);
#pragma unroll
    for (int nf = 0; nf < 4; ++nf){
      int n = n0 + wc * 64 + nf * 16 + c;
      float bv_ = bi[n];
#pragma unroll
      for (int mf = 0; mf < 8; ++mf){
        bf16x4 pk;
#pragma unroll
        for (int r = 0; r < 4; ++r) pk[r] = (short)f2b(acc[mf][nf][r] + bv_);
        *(bf16x4*)(sl + (nf * 16 + c) * 128 + mf * 16 + 4 * g) = pk;
      }
    }
    asm volatile("s_waitcnt lgkmcnt(0)" ::: "memory");
    __builtin_amdgcn_sched_barrier(0);
    const int mg = m0 + wr * 128;
    const int bb = mg >> 10, kb0 = mg & 1023;
    u16* vbase = vtb + ((size_t)bb << 20) + kb0;
#pragma unroll
    for (int j = 0; j < 16; ++j){
      int nl  = (l >> 4) + j * 4;
      int kl  = (l & 15) * 8;
      bf16x8 v = *(const bf16x8*)(sl + nl * 128 + kl);
      *(bf16x8*)(vbase + (size_t)(n0 + wc * 64 + nl) * 1024 + kl) = v;
    }
  } else {
    char* slw = (char*)&sA[0][0][0] + w * 8192;
    float bv[4];
#pragma unroll
    for (int nf = 0; nf < 4; ++nf) bv[nf] = bi[n0 + wc * 64 + nf * 16 + c];
    u16* out = sel ? kbf : qb;
    u16* gb  = out + (size_t)(m0 + wr * 128) * 1024 + n0 + wc * 64;
    epi_store(slw, gb, 1024, l,
              [&](int mf, int nf, int r){ return acc[mf][nf][r] + bv[nf]; });
  }
}

// ---------- combine NP bf16 partials + bias + residual, then LayerNorm ----------
template<int NP, int F32OUT>
__global__ __launch_bounds__(256) void comb_ln(const u16* __restrict__ pp,
                                               const float* __restrict__ bias,
                                               const u16* __restrict__ res,
                                               const float* __restrict__ gw,
                                               const float* __restrict__ bw,
                                               void* __restrict__ outp){
  const int t = threadIdx.x, w = t >> 6;
  const int row = blockIdx.x * 2 + (t >> 7);
  const int u = t & 127;
  const size_t i8 = (size_t)row * 1024 + u * 8;
  bf16x8 rv = *(const bf16x8*)(res + i8);
  float4 b0 = *(const float4*)(bias + u * 8);
  float4 b1 = *(const float4*)(bias + u * 8 + 4);
  float xs[8] = {b0.x, b0.y, b0.z, b0.w, b1.x, b1.y, b1.z, b1.w};
#pragma unroll
  for (int j = 0; j < 8; j++) xs[j] += b2f((u16)rv[j]);
#pragma unroll
  for (int z = 0; z < NP; z++){
    bf16x8 p = *(const bf16x8*)(pp + (size_t)z * (4096ull * 1024ull) + i8);
#pragma unroll
    for (int j = 0; j < 8; j++) xs[j] += b2f((u16)p[j]);
  }
  float s = 0.f, sq = 0.f;
#pragma unroll
  for (int j = 0; j < 8; j++){ s += xs[j]; sq += xs[j] * xs[j]; }
#pragma unroll
  for (int o = 32; o; o >>= 1){ s += __shfl_xor(s, o); sq += __shfl_xor(sq, o); }
  __shared__ float rs[4], rq[4];
  if ((t & 63) == 0){ rs[w] = s; rq[w] = sq; }
  __syncthreads();
  const int wb = (t >> 7) * 2;
  s  = rs[wb] + rs[wb + 1];
  sq = rq[wb] + rq[wb + 1];
  const float mu   = s * (1.f / 1024.f);
  const float var  = sq * (1.f / 1024.f) - mu * mu;
  const float rstd = rsqrtf(var + 1e-5f);
  float4 g0 = *(const float4*)(gw + u * 8);
  float4 g1 = *(const float4*)(gw + u * 8 + 4);
  float4 w0 = *(const float4*)(bw + u * 8);
  float4 w1 = *(const float4*)(bw + u * 8 + 4);
  float gv[8] = {g0.x, g0.y, g0.z, g0.w, g1.x, g1.y, g1.z, g1.w};
  float wv[8] = {w0.x, w0.y, w0.z, w0.w, w1.x, w1.y, w1.z, w1.w};
  if (F32OUT){
    float4 o0, o1;
    o0.x = (xs[0]-mu)*rstd*gv[0] + wv[0]; o0.y = (xs[1]-mu)*rstd*gv[1] + wv[1];
    o0.z = (xs[2]-mu)*rstd*gv[2] + wv[2]; o0.w = (xs[3]-mu)*rstd*gv[3] + wv[3];
    o1.x = (xs[4]-mu)*rstd*gv[4] + wv[4]; o1.y = (xs[5]-mu)*rstd*gv[5] + wv[5];
    o1.z = (xs[6]-mu)*rstd*gv[6] + wv[6]; o1.w = (xs[7]-mu)*rstd*gv[7] + wv[7];
    *(float4*)((float*)outp + i8)     = o0;
    *(float4*)((float*)outp + i8 + 4) = o1;
  } else {
    bf16x8 o;
#pragma unroll
    for (int j = 0; j < 8; j++) o[j] = (short)f2b((xs[j]-mu)*rstd*gv[j] + wv[j]);
    *(bf16x8*)((u16*)outp + i8) = o;
  }
}

// ---------- fused masked attention (128 q-rows/block, 8 waves) ----------
#define ATTN_STEP(IT, CUR, MC) do{                                              \
  if ((IT) < 15) asm volatile("s_waitcnt vmcnt(4)" ::: "memory");               \
  else           asm volatile("s_waitcnt vmcnt(0)" ::: "memory");               \
  __builtin_amdgcn_s_barrier();                                                 \
  asm volatile("" ::: "memory");                                                \
  if ((IT) < 15) stage((CUR) ^ 1, ((IT) + 1) * 64);                             \
  asm volatile("" ::: "memory");                                                \
  const char* kt = (const char*)sK[(CUR)];                                      \
  f32x4 st[4];                                                                  \
  _Pragma("unroll")                                                             \
  for (int nf = 0; nf < 4; nf++){                                               \
    const char* kr = kt + (nf * 16 + c) * 128;                                  \
    bf16x8 ak0 = *(const bf16x8*)(kr + ((g * 16) ^ sw));                        \
    bf16x8 ak1 = *(const bf16x8*)(kr + ((64 + g * 16) ^ sw));                   \
    f32x4 z = (f32x4){0.f, 0.f, 0.f, 0.f};                                      \
    z = __builtin_amdgcn_mfma_f32_16x16x32_bf16(ak0, bq0, z, 0, 0, 0);          \
    z = __builtin_amdgcn_mfma_f32_16x16x32_bf16(ak1, bq1, z, 0, 0, 0);          \
    st[nf] = z;                                                                 \
  }                                                                             \
  float rsum = 0.f;                                                             \
  bf16x4 pb[4];                                                                 \
  _Pragma("unroll")                                                             \
  for (int nf = 0; nf < 4; nf++)                                                \
    _Pragma("unroll")                                                           \
    for (int r = 0; r < 4; r++){                                                \
      float p = __expf(fmaf(st[nf][r], 0.03125f, MC[nf][r]) - 8.f);             \
      rsum += p;                                                                \
      pb[nf][r] = (short)f2b(p);                                                \
    }                                                                           \
  if ((IT) < 14){                                                               \
    _Pragma("unroll")                                                           \
    for (int nf = 0; nf < 4; nf++)                                              \
      MC[nf] = *(const f32x4*)(mbase + ((IT) + 2) * 64 + nf * 16 + g * 4);      \
  }                                                                             \
  rsum += __shfl_xor(rsum, 16); rsum += __shfl_xor(rsum, 32);                   \
  lsum += rsum;                                                                 \
  const char* vtc = (const char*)sV[(CUR)];                                     \
  __builtin_amdgcn_s_setprio(1);                                                \
  _Pragma("unroll")                                                             \
  for (int f = 0; f < 4; f++){                                                  \
    const char* vr = vtc + (f * 16 + c) * 128;                                  \
    _Pragma("unroll")                                                           \
    for (int nf = 0; nf < 4; nf++){                                             \
      bf16x4 av = *(const bf16x4*)(vr + ((nf * 32 + g * 8) ^ sw));              \
      acc[f] = __builtin_amdgcn_mfma_f32_16x16x16bf16_1k(av, pb[nf], acc[f], 0, 0, 0); \
    }                                                                           \
  }                                                                             \
  __builtin_amdgcn_s_setprio(0);                                                \
}while(0)

__global__ __launch_bounds__(512, 4) void attn_k(const u16* __restrict__ qb,
                                                 const u16* __restrict__ kb,
                                                 const u16* __restrict__ vt,
                                                 const float* __restrict__ mask,
                                                 u16* __restrict__ ob){
  __shared__ u16 sK[2][4096];   // [key 64][dh 64], row stride 128B, XOR-swizzled
  __shared__ u16 sV[2][4096];   // [dh 64][key 64], row stride 128B, XOR-swizzled

  const int aid = blockIdx.x, t = threadIdx.x;
  const int w = t >> 6, l = t & 63;
  const int c = l & 15, g = l >> 4;
  const int q0 = (aid & 7) * 128;
  const int h  = (aid >> 3) & 15, b = aid >> 7;
  const int qrow = q0 + w * 16 + c;
  const size_t qoff = ((size_t)(b * 1024 + qrow)) * 1024 + h * 64;
  const bf16x8 bq0 = *(const bf16x8*)(qb + qoff + g * 8);
  const bf16x8 bq1 = *(const bf16x8*)(qb + qoff + 32 + g * 8);
  const u16* kbase = kb + ((size_t)b * 1024) * 1024 + h * 64;
  const u16* vbase = vt + ((size_t)b << 20) + (size_t)(h * 64) * 1024;
  const float* mbase = mask + ((size_t)(h * 4 + b) * 1024 + qrow) * 1024;

  const int srow = t >> 3, slc = t & 7;             // 512 threads cover 64 rows x 128B

  auto stage = [&](int buf, int kv){
    int L = (slc * 16) ^ ((srow & 7) << 4);
    gld_lds16(kbase + (size_t)(kv + srow) * 1024 + (L >> 1), &sK[buf][t * 8]);
    gld_lds16(vbase + (size_t)srow * 1024 + kv + (L >> 1),   &sV[buf][t * 8]);
  };

  float lsum = 0.f;
  f32x4 acc[4];
#pragma unroll
  for (int f = 0; f < 4; f++) acc[f] = (f32x4){0.f, 0.f, 0.f, 0.f};

  stage(0, 0);
  asm volatile("" ::: "memory");
  f32x4 mA[4], mB[4];
#pragma unroll
  for (int nf = 0; nf < 4; nf++) mA[nf] = *(const f32x4*)(mbase + nf * 16 + g * 4);
  asm volatile("" ::: "memory");
#pragma unroll
  for (int nf = 0; nf < 4; nf++) mB[nf] = *(const f32x4*)(mbase + 64 + nf * 16 + g * 4);

  const int sw = (c & 7) << 4;
  for (int ii = 0; ii < 8; ++ii){
    ATTN_STEP(2 * ii,     0, mA);
    ATTN_STEP(2 * ii + 1, 1, mB);
  }

  // epilogue: barrier, O^T -> LDS, coalesced stores
  __syncthreads();
  const float inv = 1.f / lsum;
  u16* sO = &sK[0][0];                               // [128 rows][64 dh] = 16KB = all of sK
#pragma unroll
  for (int f = 0; f < 4; f++){
    bf16x4 pk;
#pragma unroll
    for (int r = 0; r < 4; r++) pk[r] = (short)f2b(acc[f][r] * inv);
    *(bf16x4*)(sO + (w * 16 + c) * 64 + f * 16 + 4 * g) = pk;
  }
  asm volatile("s_waitcnt lgkmcnt(0)" ::: "memory");
  __builtin_amdgcn_sched_barrier(0);
  {
    int rl  = w * 16 + (l >> 2);
    int d0  = (l & 3) * 16;
    bf16x8 v0 = *(const bf16x8*)(sO + rl * 64 + d0);
    bf16x8 v1 = *(const bf16x8*)(sO + rl * 64 + d0 + 8);
    u16* dst = ob + ((size_t)(b * 1024 + q0 + rl)) * 1024 + h * 64 + d0;
    *(bf16x8*)(dst)     = v0;
    *(bf16x8*)(dst + 8) = v1;
  }
}

// ---------- launch ----------
extern "C" void kernel_launch(void* const* d_in, const int* in_sizes, int n_in,
                              void* d_out, int out_size, void* d_ws, size_t ws_size,
                              hipStream_t stream){
  const float* Q    = (const float*)d_in[0];
  const float* K    = (const float*)d_in[1];
  const float* mask = (const float*)d_in[2];
  const float* Wq   = (const float*)d_in[4];  const float* bq  = (const float*)d_in[5];
  const float* Wk   = (const float*)d_in[6];  const float* bk  = (const float*)d_in[7];
  const float* Wv   = (const float*)d_in[8];  const float* bv  = (const float*)d_in[9];
  const float* Wo0  = (const float*)d_in[10]; const float* bo0 = (const float*)d_in[11];
  const float* Wo   = (const float*)d_in[12]; const float* bo  = (const float*)d_in[13];
  const float* Wo2  = (const float*)d_in[14]; const float* bo2 = (const float*)d_in[15];
  const float* g0   = (const float*)d_in[16]; const float* be0 = (const float*)d_in[17];
  const float* g1   = (const float*)d_in[18]; const float* be1 = (const float*)d_in[19];

  uint8_t* W = (uint8_t*)d_ws;
  const size_t MB = 1024ull * 1024ull;
  u16* Wq_t  = (u16*)(W + 0);
  u16* Wk_t  = (u16*)(W + 2  * MB);
  u16* Wv_t  = (u16*)(W + 4  * MB);
  u16* Wo0_t = (u16*)(W + 6  * MB);
  u16* Wo_t  = (u16*)(W + 8  * MB);   // [4096][1024]
  u16* Wo2_t = (u16*)(W + 16 * MB);   // [1024][4096]
  u16* Qb    = (u16*)(W + 24 * MB);
  u16* Kb    = (u16*)(W + 32 * MB);
  u16* qb    = (u16*)(W + 40 * MB);
  u16* kbf   = (u16*)(W + 48 * MB);
  u16* vtb   = (u16*)(W + 56 * MB);
  u16* ob    = (u16*)(W + 24 * MB);   // reuse Qb
  u16* x1b   = (u16*)(W + 64 * MB);
  u16* hb    = (u16*)(W + 32 * MB);   // [4096][4096] bf16, spans dead Kb/qb/kbf/vtb
  u16* ppb   = (u16*)(W + 72 * MB);   // 4 x 8MB bf16 split-K partials

  // Q/K convert + QKV weight transposes
  prep<<<8960, 256, 0, stream>>>(Q, K, Qb, Kb, Wq, Wq_t, Wk, Wk_t, Wv, Wv_t);

  // fused QKV projections (192 GEMM blocks) + 1152 transpose blocks (2304 tiles)
  gemm8p_qkv<<<1344, 512, 0, stream>>>(Qb, Kb, Wq_t, Wk_t, Wv_t,
                                       bq, bk, bv, qb, kbf, vtb,
                                       Wo0, Wo0_t, Wo, Wo_t, Wo2, Wo2_t);

  // attention (pure; 512 blocks x 512 threads)
  attn_k<<<512, 512, 0, stream>>>(qb, kbf, vtb, mask, ob);

  // output proj: 8-phase split-K=4 (NT=4), bf16 partials -> fused combine+LN0
  gemm8p<1><<<dim3(4, 16, 4), 512, 0, stream>>>(ob, Wo0_t, nullptr, ppb, 1024, 1024, 1024, 256, 4);
  comb_ln<4, 0><<<2048, 256, 0, stream>>>(ppb, bo0, qb, g0, be0, x1b);

  // FFN: FF1 (8-phase, relu) -> FF2 (8-phase, split-K=4, bf16 partials) -> combine+LN1
  gemm8p<0><<<dim3(16, 16), 512, 0, stream>>>(x1b, Wo_t, bo, hb, 1024, 1024, 4096, 0, 16);
  gemm8p<1><<<dim3(4, 16, 4), 512, 0, stream>>>(hb, Wo2_t, nullptr, ppb, 4096, 4096, 1024, 1024, 16);
  comb_ln<4, 1><<<2048, 256, 0, stream>>>(ppb, bo2, x1b, g1, be1, d_out);
}